// Round 3
// baseline (1174.896 us; speedup 1.0000x reference)
//
#include <hip/hip_runtime.h>

// out = 0.5*ve[batch] + 0.5 * softmax((lang[batch]@W) @ keyᵀ) @ ve
// (bias b cancels in softmax). bf16 MFMA 16x16x32, f32 accumulate.
// Main GEMMs use a 256x256 deep-pipelined 8-wave schedule (counted vmcnt,
// XOR-swizzled LDS, setprio) per the m201/HK template. Vocab chunked.

#define DIM   1024
#define VOCAB 32000
#define NTOK  4096
#define KSPLIT 2

typedef unsigned short u16;
typedef __attribute__((ext_vector_type(8))) __bf16 bf16x8;
typedef __attribute__((ext_vector_type(4))) float  f32x4;
typedef __attribute__((ext_vector_type(8))) u16    u16x8;
typedef __attribute__((ext_vector_type(4))) u16    u16x4;

__device__ __forceinline__ u16 f2bf(float f) {  // round-to-nearest-even
  unsigned u = __float_as_uint(f);
  u += 0x7FFFu + ((u >> 16) & 1u);
  return (u16)(u >> 16);
}
__device__ __forceinline__ float bf2f(u16 s) {
  return __uint_as_float(((unsigned)s) << 16);
}

// ---------------- conversion / gather ----------------

__global__ void cvt_f32_bf16(const float* __restrict__ in, u16* __restrict__ out) {
  size_t i = (size_t)blockIdx.x * 256 + threadIdx.x;
  float4 v = ((const float4*)in)[i];
  u16x4 o; o[0]=f2bf(v.x); o[1]=f2bf(v.y); o[2]=f2bf(v.z); o[3]=f2bf(v.w);
  ((u16x4*)out)[i] = o;
}

__global__ void gather_q(const int* __restrict__ batch, const float* __restrict__ lang,
                         u16* __restrict__ q) {
  int row = blockIdx.x;
  int src = batch[row];
  int t = threadIdx.x;
  float4 v = *(const float4*)(lang + (size_t)src * DIM + (t << 2));
  u16x4 o; o[0]=f2bf(v.x); o[1]=f2bf(v.y); o[2]=f2bf(v.z); o[3]=f2bf(v.w);
  *(u16x4*)(q + (size_t)row * DIM + (t << 2)) = o;
}

// out[c][r] = bf16(in[r][c]) ; 64x64 tiles via LDS. grid = (R/64, C/64)
__global__ void transpose_cvt(const float* __restrict__ in, u16* __restrict__ out,
                              int ldin, int ldout) {
  __shared__ u16 t[64][72];
  int r0 = blockIdx.x << 6;
  int c0 = blockIdx.y << 6;
  int tid = threadIdx.x;
  #pragma unroll
  for (int p = 0; p < 4; ++p) {
    int r = (p << 4) + (tid >> 4);
    int c = (tid & 15) << 2;
    float4 v = *(const float4*)(in + (size_t)(r0 + r) * ldin + c0 + c);
    t[c+0][r] = f2bf(v.x);
    t[c+1][r] = f2bf(v.y);
    t[c+2][r] = f2bf(v.z);
    t[c+3][r] = f2bf(v.w);
  }
  __syncthreads();
  #pragma unroll
  for (int qq = 0; qq < 2; ++qq) {
    int rr = tid >> 2;
    int cc = (((tid & 3) << 1) + qq) << 3;
    u16x8 w;
    #pragma unroll
    for (int j = 0; j < 8; ++j) w[j] = t[rr][cc + j];
    *(u16x8*)(out + (size_t)(c0 + rr) * ldout + r0 + cc) = w;
  }
}

// ---------------- small GEMM for qW: C[M,N]=A@B^T, 128x128 tile ----------------
__global__ void gemm_qw(const u16* __restrict__ A, const u16* __restrict__ B,
                        u16* __restrict__ C, int K, int kSteps, int ldc) {
  __shared__ u16 As[128 * 32];
  __shared__ u16 Bs[128 * 32];
  const int tid  = threadIdx.x;
  const int lane = tid & 63;
  const int wid  = tid >> 6;
  const int wr   = wid >> 1, wc = wid & 1;
  const int row0 = blockIdx.x << 7;
  const int col0 = blockIdx.y << 7;

  f32x4 acc[4][4];
  #pragma unroll
  for (int m = 0; m < 4; ++m)
    #pragma unroll
    for (int n = 0; n < 4; ++n) acc[m][n] = (f32x4){0.f,0.f,0.f,0.f};

  const int sr = lane >> 2;
  const int sc = (lane & 3) << 3;

  for (int ks = 0; ks < kSteps; ++ks) {
    const int kk = ks << 5;
    #pragma unroll
    for (int t = 0; t < 2; ++t) {
      const int i = wid * 2 + t;
      const u16* gA = A + (size_t)(row0 + (i << 4) + sr) * K + kk + sc;
      const u16* gB = B + (size_t)(col0 + (i << 4) + sr) * K + kk + sc;
      __builtin_amdgcn_global_load_lds((const __attribute__((address_space(1))) void*)gA,
                                       (__attribute__((address_space(3))) void*)(As + i * 512),
                                       16, 0, 0);
      __builtin_amdgcn_global_load_lds((const __attribute__((address_space(1))) void*)gB,
                                       (__attribute__((address_space(3))) void*)(Bs + i * 512),
                                       16, 0, 0);
    }
    __syncthreads();
    bf16x8 a[4], b[4];
    #pragma unroll
    for (int m = 0; m < 4; ++m)
      a[m] = *(const bf16x8*)(As + ((wr << 6) + (m << 4) + (lane & 15)) * 32 + ((lane >> 4) << 3));
    #pragma unroll
    for (int n = 0; n < 4; ++n)
      b[n] = *(const bf16x8*)(Bs + ((wc << 6) + (n << 4) + (lane & 15)) * 32 + ((lane >> 4) << 3));
    #pragma unroll
    for (int m = 0; m < 4; ++m)
      #pragma unroll
      for (int n = 0; n < 4; ++n)
        acc[m][n] = __builtin_amdgcn_mfma_f32_16x16x32_bf16(a[m], b[n], acc[m][n], 0, 0, 0);
    __syncthreads();
  }

  const int r0 = row0 + (wr << 6);
  const int c0 = col0 + (wc << 6);
  const int fq = (lane >> 4) << 2;
  const int fr = lane & 15;
  #pragma unroll
  for (int m = 0; m < 4; ++m)
    #pragma unroll
    for (int n = 0; n < 4; ++n) {
      int col = c0 + (n << 4) + fr;
      #pragma unroll
      for (int j = 0; j < 4; ++j) {
        int row = r0 + (m << 4) + fq + j;
        C[(size_t)row * ldc + col] = f2bf(acc[m][n][j]);
      }
    }
}

// ---------------- 256x256 deep-pipelined GEMM: C[M,N] = A[M,K] @ B[N,K]^T ----
// 8 waves (2M x 4N), BK=64, 2 LDS K-tile buffers (128 KiB), counted vmcnt(8),
// XOR slot swizzle (write: pre-swizzled global src; read: same swizzle).
// MODE 1: C(u16) = bf16(exp(acc));  MODE 2: C(f32, +z slice) += acc.

template<int MODE>
__global__ __launch_bounds__(512, 2) void gemm8(const u16* __restrict__ A,
                                                const u16* __restrict__ B,
                                                void* __restrict__ Cout,
                                                int K, int nTiles, int ldc) {
  __shared__ __align__(16) u16 lds[65536];  // 2 bufs x (A 256x64 | B 256x64) bf16
  const int tid  = threadIdx.x;
  const int lane = tid & 63;
  const int wid  = tid >> 6;        // 0..7
  const int wr   = wid >> 2;        // 0..1 (M)
  const int wc   = wid & 3;         // 0..3 (N)
  const int row0 = blockIdx.x << 8;
  const int col0 = blockIdx.y << 8;
  const int kbase = blockIdx.z * (nTiles << 6);
  const int fr = lane & 15;
  const int fq = lane >> 4;
  const int rb = tid >> 3;          // staging row within 64-row group
  const int ss = tid & 7;           // staging 16B slot

#define STAGE8(d, kk)                                                              \
  {                                                                                \
    _Pragma("unroll")                                                              \
    for (int c = 0; c < 4; ++c) {                                                  \
      const int ra = (c << 6) + rb;                                                \
      const u16* gA = A + (size_t)(row0 + ra) * K + (kk) + ((ss ^ (ra & 7)) << 3); \
      __builtin_amdgcn_global_load_lds(                                            \
          (const __attribute__((address_space(1))) void*)gA,                       \
          (__attribute__((address_space(3))) void*)(lds + (d) * 32768 + (((c << 6) + (wid << 3)) << 6)), \
          16, 0, 0);                                                               \
    }                                                                              \
    _Pragma("unroll")                                                              \
    for (int c = 0; c < 4; ++c) {                                                  \
      const int rn = (c << 6) + rb;                                                \
      const u16* gB = B + (size_t)(col0 + rn) * K + (kk) + ((ss ^ (rn & 7)) << 3); \
      __builtin_amdgcn_global_load_lds(                                            \
          (const __attribute__((address_space(1))) void*)gB,                       \
          (__attribute__((address_space(3))) void*)(lds + (d) * 32768 + 16384 + (((c << 6) + (wid << 3)) << 6)), \
          16, 0, 0);                                                               \
    }                                                                              \
  }

  f32x4 acc[8][4];
  #pragma unroll
  for (int m = 0; m < 8; ++m)
    #pragma unroll
    for (int n = 0; n < 4; ++n) acc[m][n] = (f32x4){0.f, 0.f, 0.f, 0.f};

  STAGE8(0, kbase)
  STAGE8(1, kbase + 64)

  bf16x8 a[4][2], b[2][2];

  for (int t = 0; t < nTiles; ++t) {
    const int d = t & 1;
    const u16* Abuf = lds + d * 32768;
    const u16* Bbuf = Abuf + 16384;
    // wait for current tile's 8 loads; keep next tile's 8 in flight
    if (t + 1 < nTiles) { asm volatile("s_waitcnt vmcnt(8)" ::: "memory"); }
    else                { asm volatile("s_waitcnt vmcnt(0)" ::: "memory"); }
    asm volatile("s_barrier" ::: "memory");

    #pragma unroll
    for (int ph = 0; ph < 4; ++ph) {
      const int mh = ph >> 1, nh = ph & 1;
      if (nh == 0) {
        #pragma unroll
        for (int mq = 0; mq < 4; ++mq)
          #pragma unroll
          for (int ks = 0; ks < 2; ++ks) {
            const int row  = (wr << 7) + (mh << 6) + (mq << 4) + fr;
            const int slot = ((ks << 2) + fq) ^ (row & 7);
            a[mq][ks] = *(const bf16x8*)(Abuf + (row << 6) + (slot << 3));
          }
      }
      #pragma unroll
      for (int nq = 0; nq < 2; ++nq)
        #pragma unroll
        for (int ks = 0; ks < 2; ++ks) {
          const int row  = (wc << 6) + (nh << 5) + (nq << 4) + fr;
          const int slot = ((ks << 2) + fq) ^ (row & 7);
          b[nq][ks] = *(const bf16x8*)(Bbuf + (row << 6) + (slot << 3));
        }
      asm volatile("s_barrier" ::: "memory");
      __builtin_amdgcn_s_setprio(1);
      #pragma unroll
      for (int mq = 0; mq < 4; ++mq)
        #pragma unroll
        for (int nq = 0; nq < 2; ++nq)
          #pragma unroll
          for (int ks = 0; ks < 2; ++ks)
            acc[(mh << 2) + mq][(nh << 1) + nq] =
                __builtin_amdgcn_mfma_f32_16x16x32_bf16(
                    a[mq][ks], b[nq][ks], acc[(mh << 2) + mq][(nh << 1) + nq], 0, 0, 0);
      __builtin_amdgcn_s_setprio(0);
      asm volatile("s_barrier" ::: "memory");
    }
    // all waves done reading buf d (their reads completed before their last
    // barrier) -> safe to overwrite with tile t+2
    if (t + 2 < nTiles) STAGE8(d, kbase + ((t + 2) << 6))
  }

  if (MODE == 1) {
    u16* C = (u16*)Cout;
    #pragma unroll
    for (int m = 0; m < 8; ++m)
      #pragma unroll
      for (int n = 0; n < 4; ++n) {
        const int col = col0 + (wc << 6) + (n << 4) + fr;
        #pragma unroll
        for (int j = 0; j < 4; ++j) {
          const int row = row0 + (wr << 7) + (m << 4) + (fq << 2) + j;
          C[(size_t)row * ldc + col] = f2bf(__expf(acc[m][n][j]));
        }
      }
  } else {
    float* C = (float*)Cout + (size_t)blockIdx.z * NTOK * DIM;
    #pragma unroll
    for (int m = 0; m < 8; ++m)
      #pragma unroll
      for (int n = 0; n < 4; ++n) {
        const int col = col0 + (wc << 6) + (n << 4) + fr;
        #pragma unroll
        for (int j = 0; j < 4; ++j) {
          const int row = row0 + (wr << 7) + (m << 4) + (fq << 2) + j;
          C[(size_t)row * ldc + col] += acc[m][n][j];
        }
      }
  }
#undef STAGE8
}

// ---------------- denom accumulate ----------------
__global__ void rowsum_acc(const u16* __restrict__ P, float* __restrict__ denom, int C) {
  __shared__ float red[256];
  int row = blockIdx.x;
  const u16x8* p = (const u16x8*)(P + (size_t)row * C);
  float s = 0.f;
  for (int c = threadIdx.x; c < (C >> 3); c += 256) {
    u16x8 v = p[c];
    #pragma unroll
    for (int j = 0; j < 8; ++j) s += bf2f(v[j]);
  }
  red[threadIdx.x] = s;
  __syncthreads();
  for (int o = 128; o > 0; o >>= 1) {
    if (threadIdx.x < o) red[threadIdx.x] += red[threadIdx.x + o];
    __syncthreads();
  }
  if (threadIdx.x == 0) denom[row] += red[0];
}

// ---------------- finalize ----------------
__global__ void finalize(const float* __restrict__ parts, const float* __restrict__ denom,
                         const float* __restrict__ ve, const int* __restrict__ batch,
                         float* __restrict__ out) {
  int row = blockIdx.x;
  int t = threadIdx.x;
  float inv = 0.5f / denom[row];
  float4 a = *(const float4*)(ve + (size_t)batch[row] * DIM + (t << 2));
  float sx = 0.f, sy = 0.f, sz = 0.f, sw = 0.f;
  #pragma unroll
  for (int ks = 0; ks < KSPLIT; ++ks) {
    float4 pv = *(const float4*)(parts + ((size_t)ks * NTOK + row) * DIM + (t << 2));
    sx += pv.x; sy += pv.y; sz += pv.z; sw += pv.w;
  }
  float4 o;
  o.x = 0.5f * a.x + inv * sx;
  o.y = 0.5f * a.y + inv * sy;
  o.z = 0.5f * a.z + inv * sz;
  o.w = 0.5f * a.w + inv * sw;
  *(float4*)(out + (size_t)row * DIM + (t << 2)) = o;
}

// ---------------- launch ----------------
extern "C" void kernel_launch(void* const* d_in, const int* in_sizes, int n_in,
                              void* d_out, int out_size, void* d_ws, size_t ws_size,
                              hipStream_t stream) {
  const int*   batch = (const int*)d_in[0];
  const float* lang  = (const float*)d_in[1];
  const float* key   = (const float*)d_in[2];
  const float* ve    = (const float*)d_in[3];
  const float* W     = (const float*)d_in[4];
  float* out = (float*)d_out;

  const size_t szWt    = (size_t)DIM * DIM * 2;
  const size_t szQb    = (size_t)NTOK * DIM * 2;
  const size_t szQW    = (size_t)NTOK * DIM * 2;
  const size_t szParts = (size_t)KSPLIT * NTOK * DIM * 4;
  const size_t szDenom = (size_t)NTOK * 4;
  const size_t fixed = szWt + szQb + szQW + szParts + szDenom;

  // vocab chunk: multiple of 256 dividing 32000
  const int opts[2] = {6400, 1280};
  int CHUNK = 1280;
  for (int i = 0; i < 2; ++i) {
    size_t need = fixed + (size_t)opts[i] * (NTOK * 2 + DIM * 4);
    if (need <= ws_size) { CHUNK = opts[i]; break; }
  }
  const int NCHUNK = VOCAB / CHUNK;

  char* ws = (char*)d_ws;
  u16*   Wt    = (u16*)(ws);
  u16*   qb    = (u16*)(ws + szWt);
  u16*   qW    = (u16*)(ws + szWt + szQb);
  float* parts = (float*)(ws + szWt + szQb + szQW);
  float* denom = (float*)(ws + szWt + szQb + szQW + szParts);
  char*  dyn   = ws + fixed;
  u16*   keyc  = (u16*)(dyn);
  u16*   veTc  = (u16*)(dyn + (size_t)CHUNK * DIM * 2);
  u16*   Pc    = (u16*)(dyn + (size_t)CHUNK * DIM * 4);

  // prologue
  transpose_cvt<<<dim3(DIM / 64, DIM / 64), 256, 0, stream>>>(W, Wt, DIM, DIM);
  gather_q<<<NTOK, 256, 0, stream>>>(batch, lang, qb);
  gemm_qw<<<dim3(NTOK / 128, DIM / 128), 256, 0, stream>>>(qb, Wt, qW, DIM, DIM / 32, DIM);
  hipMemsetAsync(parts, 0, szParts, stream);
  hipMemsetAsync(denom, 0, szDenom, stream);

  for (int c = 0; c < NCHUNK; ++c) {
    const int v0 = c * CHUNK;
    cvt_f32_bf16<<<CHUNK * DIM / 1024, 256, 0, stream>>>(key + (size_t)v0 * DIM, keyc);
    transpose_cvt<<<dim3(CHUNK / 64, DIM / 64), 256, 0, stream>>>(ve + (size_t)v0 * DIM, veTc,
                                                                  DIM, CHUNK);
    // P_c = exp(qW @ keyc^T)   [NTOK x CHUNK]
    gemm8<1><<<dim3(NTOK / 256, CHUNK / 256), 512, 0, stream>>>(qW, keyc, Pc,
                                                                DIM, DIM / 64, CHUNK);
    rowsum_acc<<<NTOK, 256, 0, stream>>>(Pc, denom, CHUNK);
    // parts[z] += P_c @ veTc^T  [NTOK x DIM], split-K over chunk
    gemm8<2><<<dim3(NTOK / 256, DIM / 256, KSPLIT), 512, 0, stream>>>(Pc, veTc, parts,
                                                                      CHUNK, CHUNK / 64 / KSPLIT, DIM);
  }

  finalize<<<NTOK, 256, 0, stream>>>(parts, denom, ve, batch, out);
}

// Round 4
// 989.457 us; speedup vs baseline: 1.1874x; 1.1874x over previous
//
#include <hip/hip_runtime.h>

// out = 0.5*ve[batch] + 0.5 * softmax((lang[batch]@W) @ keyᵀ) @ ve
// (bias b cancels in softmax). bf16 MFMA 16x16x32, f32 accumulate.
// 256x256 8-wave pipelined GEMM: counted vmcnt (builtin barriers, NO asm
// "memory" clobbers -> no compiler waitcnt drains), XOR-swizzled LDS,
// setprio, XCD swizzle. Vocab chunked; KSPLIT picked from ws_size.

#define DIM   1024
#define VOCAB 32000
#define NTOK  4096

typedef unsigned short u16;
typedef __attribute__((ext_vector_type(8))) __bf16 bf16x8;
typedef __attribute__((ext_vector_type(4))) float  f32x4;
typedef __attribute__((ext_vector_type(8))) u16    u16x8;
typedef __attribute__((ext_vector_type(4))) u16    u16x4;

__device__ __forceinline__ u16 f2bf(float f) {  // round-to-nearest-even
  unsigned u = __float_as_uint(f);
  u += 0x7FFFu + ((u >> 16) & 1u);
  return (u16)(u >> 16);
}
__device__ __forceinline__ float bf2f(u16 s) {
  return __uint_as_float(((unsigned)s) << 16);
}

// ---------------- conversion / gather ----------------

__global__ void cvt_f32_bf16(const float* __restrict__ in, u16* __restrict__ out) {
  size_t i = (size_t)blockIdx.x * 256 + threadIdx.x;
  float4 v = ((const float4*)in)[i];
  u16x4 o; o[0]=f2bf(v.x); o[1]=f2bf(v.y); o[2]=f2bf(v.z); o[3]=f2bf(v.w);
  ((u16x4*)out)[i] = o;
}

__global__ void gather_q(const int* __restrict__ batch, const float* __restrict__ lang,
                         u16* __restrict__ q) {
  int row = blockIdx.x;
  int src = batch[row];
  int t = threadIdx.x;
  float4 v = *(const float4*)(lang + (size_t)src * DIM + (t << 2));
  u16x4 o; o[0]=f2bf(v.x); o[1]=f2bf(v.y); o[2]=f2bf(v.z); o[3]=f2bf(v.w);
  *(u16x4*)(q + (size_t)row * DIM + (t << 2)) = o;
}

// out[c][r] = bf16(in[r][c]) ; 64x64 tiles via LDS. grid = (R/64, C/64)
__global__ void transpose_cvt(const float* __restrict__ in, u16* __restrict__ out,
                              int ldin, int ldout) {
  __shared__ u16 t[64][72];
  int r0 = blockIdx.x << 6;
  int c0 = blockIdx.y << 6;
  int tid = threadIdx.x;
  #pragma unroll
  for (int p = 0; p < 4; ++p) {
    int r = (p << 4) + (tid >> 4);
    int c = (tid & 15) << 2;
    float4 v = *(const float4*)(in + (size_t)(r0 + r) * ldin + c0 + c);
    t[c+0][r] = f2bf(v.x);
    t[c+1][r] = f2bf(v.y);
    t[c+2][r] = f2bf(v.z);
    t[c+3][r] = f2bf(v.w);
  }
  __syncthreads();
  #pragma unroll
  for (int qq = 0; qq < 2; ++qq) {
    int rr = tid >> 2;
    int cc = (((tid & 3) << 1) + qq) << 3;
    u16x8 w;
    #pragma unroll
    for (int j = 0; j < 8; ++j) w[j] = t[rr][cc + j];
    *(u16x8*)(out + (size_t)(c0 + rr) * ldout + r0 + cc) = w;
  }
}

// ---------------- small GEMM for qW: C[M,N]=A@B^T, 128x128 tile ----------------
__global__ void gemm_qw(const u16* __restrict__ A, const u16* __restrict__ B,
                        u16* __restrict__ C, int K, int kSteps, int ldc) {
  __shared__ u16 As[128 * 32];
  __shared__ u16 Bs[128 * 32];
  const int tid  = threadIdx.x;
  const int lane = tid & 63;
  const int wid  = tid >> 6;
  const int wr   = wid >> 1, wc = wid & 1;
  const int row0 = blockIdx.x << 7;
  const int col0 = blockIdx.y << 7;

  f32x4 acc[4][4];
  #pragma unroll
  for (int m = 0; m < 4; ++m)
    #pragma unroll
    for (int n = 0; n < 4; ++n) acc[m][n] = (f32x4){0.f,0.f,0.f,0.f};

  const int sr = lane >> 2;
  const int sc = (lane & 3) << 3;

  for (int ks = 0; ks < kSteps; ++ks) {
    const int kk = ks << 5;
    #pragma unroll
    for (int t = 0; t < 2; ++t) {
      const int i = wid * 2 + t;
      const u16* gA = A + (size_t)(row0 + (i << 4) + sr) * K + kk + sc;
      const u16* gB = B + (size_t)(col0 + (i << 4) + sr) * K + kk + sc;
      __builtin_amdgcn_global_load_lds((const __attribute__((address_space(1))) void*)gA,
                                       (__attribute__((address_space(3))) void*)(As + i * 512),
                                       16, 0, 0);
      __builtin_amdgcn_global_load_lds((const __attribute__((address_space(1))) void*)gB,
                                       (__attribute__((address_space(3))) void*)(Bs + i * 512),
                                       16, 0, 0);
    }
    __syncthreads();
    bf16x8 a[4], b[4];
    #pragma unroll
    for (int m = 0; m < 4; ++m)
      a[m] = *(const bf16x8*)(As + ((wr << 6) + (m << 4) + (lane & 15)) * 32 + ((lane >> 4) << 3));
    #pragma unroll
    for (int n = 0; n < 4; ++n)
      b[n] = *(const bf16x8*)(Bs + ((wc << 6) + (n << 4) + (lane & 15)) * 32 + ((lane >> 4) << 3));
    #pragma unroll
    for (int m = 0; m < 4; ++m)
      #pragma unroll
      for (int n = 0; n < 4; ++n)
        acc[m][n] = __builtin_amdgcn_mfma_f32_16x16x32_bf16(a[m], b[n], acc[m][n], 0, 0, 0);
    __syncthreads();
  }

  const int r0 = row0 + (wr << 6);
  const int c0 = col0 + (wc << 6);
  const int fq = (lane >> 4) << 2;
  const int fr = lane & 15;
  #pragma unroll
  for (int m = 0; m < 4; ++m)
    #pragma unroll
    for (int n = 0; n < 4; ++n) {
      int col = c0 + (n << 4) + fr;
      #pragma unroll
      for (int j = 0; j < 4; ++j) {
        int row = r0 + (m << 4) + fq + j;
        C[(size_t)row * ldc + col] = f2bf(acc[m][n][j]);
      }
    }
}

// ---------------- 256x256 pipelined GEMM: C[M,N] = A[M,K] @ B[N,K]^T ----------
// 8 waves (2M x 4N), BK=64, 2 LDS buffers, 2-tile prefetch, counted vmcnt(8).
// MODE 1: C(u16) = bf16(exp(acc));  MODE 2: C(f32, +z slice) += acc.
// gridDim.x MUST be 16 (NTOK/256); gridDim.x*gridDim.y must be mult of 8.

#define SB() __builtin_amdgcn_sched_barrier(0)
#define BAR() { SB(); __builtin_amdgcn_s_barrier(); SB(); }

template<int MODE>
__global__ __launch_bounds__(512, 2) void gemm8(const u16* __restrict__ A,
                                                const u16* __restrict__ B,
                                                void* __restrict__ Cout,
                                                int K, int nTiles, int ldc) {
  __shared__ __align__(16) u16 lds[65536];  // 2 bufs x (A 256x64 | B 256x64) bf16
  const int tid  = threadIdx.x;
  const int lane = tid & 63;
  const int wid  = tid >> 6;        // 0..7
  const int wr   = wid >> 2;        // 0..1 (M)
  const int wc   = wid & 3;         // 0..3 (N)

  // XCD-aware swizzle (bijective: nwg % 8 == 0 for all our grids)
  const int nwg = (int)(gridDim.x * gridDim.y);
  int lin = blockIdx.y * gridDim.x + blockIdx.x;
  { const int cpx = nwg >> 3; lin = (lin & 7) * cpx + (lin >> 3); }
  const int row0 = (lin & 15) << 8;    // gridDim.x == 16
  const int col0 = (lin >> 4) << 8;

  const int kbase = blockIdx.z * (nTiles << 6);
  const int fr = lane & 15;
  const int fq = lane >> 4;
  const int rb = tid >> 3;          // staging row within 64-row group
  const int ss = tid & 7;           // staging 16B slot

#define STAGE8(d, kk)                                                              \
  {                                                                                \
    _Pragma("unroll")                                                              \
    for (int c = 0; c < 4; ++c) {                                                  \
      const int ra = (c << 6) + rb;                                                \
      const u16* gA = A + (size_t)(row0 + ra) * K + (kk) + ((ss ^ (ra & 7)) << 3); \
      __builtin_amdgcn_global_load_lds(                                            \
          (const __attribute__((address_space(1))) void*)gA,                       \
          (__attribute__((address_space(3))) void*)(lds + (d) * 32768 + (((c << 6) + (wid << 3)) << 6)), \
          16, 0, 0);                                                               \
    }                                                                              \
    _Pragma("unroll")                                                              \
    for (int c = 0; c < 4; ++c) {                                                  \
      const int rn = (c << 6) + rb;                                                \
      const u16* gB = B + (size_t)(col0 + rn) * K + (kk) + ((ss ^ (rn & 7)) << 3); \
      __builtin_amdgcn_global_load_lds(                                            \
          (const __attribute__((address_space(1))) void*)gB,                       \
          (__attribute__((address_space(3))) void*)(lds + (d) * 32768 + 16384 + (((c << 6) + (wid << 3)) << 6)), \
          16, 0, 0);                                                               \
    }                                                                              \
  }

  f32x4 acc[8][4];
  #pragma unroll
  for (int m = 0; m < 8; ++m)
    #pragma unroll
    for (int n = 0; n < 4; ++n) acc[m][n] = (f32x4){0.f, 0.f, 0.f, 0.f};

  STAGE8(0, kbase)
  STAGE8(1, kbase + 64)

  bf16x8 a[4][2], b[2][2];

  for (int t = 0; t < nTiles; ++t) {
    const int d = t & 1;
    const u16* Abuf = lds + d * 32768;
    const u16* Bbuf = Abuf + 16384;
    // wait own loads for this tile (keep next tile's 8 in flight), then sync.
    // NO "memory" clobber: a clobber makes LLVM drain vmcnt/lgkmcnt to 0.
    SB();
    if (t + 1 < nTiles) { asm volatile("s_waitcnt vmcnt(8)"); }
    else                { asm volatile("s_waitcnt vmcnt(0)"); }
    BAR();

    #pragma unroll
    for (int ph = 0; ph < 4; ++ph) {
      const int mh = ph >> 1, nh = ph & 1;
      if (nh == 0) {
        #pragma unroll
        for (int mq = 0; mq < 4; ++mq)
          #pragma unroll
          for (int ks = 0; ks < 2; ++ks) {
            const int row  = (wr << 7) + (mh << 6) + (mq << 4) + fr;
            const int slot = ((ks << 2) + fq) ^ (row & 7);
            a[mq][ks] = *(const bf16x8*)(Abuf + (row << 6) + (slot << 3));
          }
      }
      #pragma unroll
      for (int nq = 0; nq < 2; ++nq)
        #pragma unroll
        for (int ks = 0; ks < 2; ++ks) {
          const int row  = (wc << 6) + (nh << 5) + (nq << 4) + fr;
          const int slot = ((ks << 2) + fq) ^ (row & 7);
          b[nq][ks] = *(const bf16x8*)(Bbuf + (row << 6) + (slot << 3));
        }
      BAR();
      __builtin_amdgcn_s_setprio(1);
      #pragma unroll
      for (int mq = 0; mq < 4; ++mq)
        #pragma unroll
        for (int nq = 0; nq < 2; ++nq)
          #pragma unroll
          for (int ks = 0; ks < 2; ++ks)
            acc[(mh << 2) + mq][(nh << 1) + nq] =
                __builtin_amdgcn_mfma_f32_16x16x32_bf16(
                    a[mq][ks], b[nq][ks], acc[(mh << 2) + mq][(nh << 1) + nq], 0, 0, 0);
      __builtin_amdgcn_s_setprio(0);
      BAR();
    }
    // after last barrier all waves consumed buf d -> safe to restage (tile t+2)
    if (t + 2 < nTiles) STAGE8(d, kbase + ((t + 2) << 6))
  }

  if (MODE == 1) {
    u16* C = (u16*)Cout;
    #pragma unroll
    for (int m = 0; m < 8; ++m)
      #pragma unroll
      for (int n = 0; n < 4; ++n) {
        const int col = col0 + (wc << 6) + (n << 4) + fr;
        #pragma unroll
        for (int j = 0; j < 4; ++j) {
          const int row = row0 + (wr << 7) + (m << 4) + (fq << 2) + j;
          C[(size_t)row * ldc + col] = f2bf(__expf(acc[m][n][j]));
        }
      }
  } else {
    float* C = (float*)Cout + (size_t)blockIdx.z * NTOK * DIM;
    #pragma unroll
    for (int m = 0; m < 8; ++m)
      #pragma unroll
      for (int n = 0; n < 4; ++n) {
        const int col = col0 + (wc << 6) + (n << 4) + fr;
        #pragma unroll
        for (int j = 0; j < 4; ++j) {
          const int row = row0 + (wr << 7) + (m << 4) + (fq << 2) + j;
          C[(size_t)row * ldc + col] += acc[m][n][j];
        }
      }
  }
#undef STAGE8
}

// ---------------- denom accumulate ----------------
__global__ void rowsum_acc(const u16* __restrict__ P, float* __restrict__ denom, int C) {
  __shared__ float red[256];
  int row = blockIdx.x;
  const u16x8* p = (const u16x8*)(P + (size_t)row * C);
  float s = 0.f;
  for (int c = threadIdx.x; c < (C >> 3); c += 256) {
    u16x8 v = p[c];
    #pragma unroll
    for (int j = 0; j < 8; ++j) s += bf2f(v[j]);
  }
  red[threadIdx.x] = s;
  __syncthreads();
  for (int o = 128; o > 0; o >>= 1) {
    if (threadIdx.x < o) red[threadIdx.x] += red[threadIdx.x + o];
    __syncthreads();
  }
  if (threadIdx.x == 0) denom[row] += red[0];
}

// ---------------- finalize ----------------
__global__ void finalize(const float* __restrict__ parts, const float* __restrict__ denom,
                         const float* __restrict__ ve, const int* __restrict__ batch,
                         float* __restrict__ out, int nks) {
  int row = blockIdx.x;
  int t = threadIdx.x;
  float inv = 0.5f / denom[row];
  float4 a = *(const float4*)(ve + (size_t)batch[row] * DIM + (t << 2));
  float sx = 0.f, sy = 0.f, sz = 0.f, sw = 0.f;
  for (int ks = 0; ks < nks; ++ks) {
    float4 pv = *(const float4*)(parts + ((size_t)ks * NTOK + row) * DIM + (t << 2));
    sx += pv.x; sy += pv.y; sz += pv.z; sw += pv.w;
  }
  float4 o;
  o.x = 0.5f * a.x + inv * sx;
  o.y = 0.5f * a.y + inv * sy;
  o.z = 0.5f * a.z + inv * sz;
  o.w = 0.5f * a.w + inv * sw;
  *(float4*)(out + (size_t)row * DIM + (t << 2)) = o;
}

// ---------------- launch ----------------
extern "C" void kernel_launch(void* const* d_in, const int* in_sizes, int n_in,
                              void* d_out, int out_size, void* d_ws, size_t ws_size,
                              hipStream_t stream) {
  const int*   batch = (const int*)d_in[0];
  const float* lang  = (const float*)d_in[1];
  const float* key   = (const float*)d_in[2];
  const float* ve    = (const float*)d_in[3];
  const float* W     = (const float*)d_in[4];
  float* out = (float*)d_out;

  const size_t szWt    = (size_t)DIM * DIM * 2;
  const size_t szQb    = (size_t)NTOK * DIM * 2;
  const size_t szQW    = (size_t)NTOK * DIM * 2;
  const size_t szDenom = (size_t)NTOK * 4;
  const size_t base = szWt + szQb + szQW + szDenom;

  // deterministic config selection from ws_size:
  // prefer (CHUNK=6400, KSPLIT=4); fallback (6400,2); last resort (1280,2)
  int CHUNK = 1280, KS = 2;
  {
    const int copt[3] = {6400, 6400, 1280};
    const int kopt[3] = {4, 2, 2};
    for (int i = 0; i < 3; ++i) {
      size_t need = base + (size_t)kopt[i] * NTOK * DIM * 4
                  + (size_t)copt[i] * (NTOK * 2 + DIM * 4);
      if (need <= ws_size) { CHUNK = copt[i]; KS = kopt[i]; break; }
    }
  }
  const int NCHUNK = VOCAB / CHUNK;
  const size_t szParts = (size_t)KS * NTOK * DIM * 4;

  char* ws = (char*)d_ws;
  u16*   Wt    = (u16*)(ws);
  u16*   qb    = (u16*)(ws + szWt);
  u16*   qW    = (u16*)(ws + szWt + szQb);
  float* denom = (float*)(ws + szWt + szQb + szQW);
  float* parts = (float*)(ws + base);
  char*  dyn   = ws + base + szParts;
  u16*   keyc  = (u16*)(dyn);
  u16*   veTc  = (u16*)(dyn + (size_t)CHUNK * DIM * 2);
  u16*   Pc    = (u16*)(dyn + (size_t)CHUNK * DIM * 4);

  // prologue
  transpose_cvt<<<dim3(DIM / 64, DIM / 64), 256, 0, stream>>>(W, Wt, DIM, DIM);
  gather_q<<<NTOK, 256, 0, stream>>>(batch, lang, qb);
  gemm_qw<<<dim3(NTOK / 128, DIM / 128), 256, 0, stream>>>(qb, Wt, qW, DIM, DIM / 32, DIM);
  hipMemsetAsync(parts, 0, szParts, stream);
  hipMemsetAsync(denom, 0, szDenom, stream);

  for (int c = 0; c < NCHUNK; ++c) {
    const int v0 = c * CHUNK;
    cvt_f32_bf16<<<CHUNK * DIM / 1024, 256, 0, stream>>>(key + (size_t)v0 * DIM, keyc);
    transpose_cvt<<<dim3(CHUNK / 64, DIM / 64), 256, 0, stream>>>(ve + (size_t)v0 * DIM, veTc,
                                                                  DIM, CHUNK);
    // P_c = exp(qW @ keyc^T)   [NTOK x CHUNK]
    gemm8<1><<<dim3(NTOK / 256, CHUNK / 256), 512, 0, stream>>>(qW, keyc, Pc,
                                                                DIM, DIM / 64, CHUNK);
    rowsum_acc<<<NTOK, 256, 0, stream>>>(Pc, denom, CHUNK);
    // parts[z] += P_c @ veTc^T  [NTOK x DIM], split-K over chunk
    gemm8<2><<<dim3(NTOK / 256, DIM / 256, KS), 512, 0, stream>>>(Pc, veTc, parts,
                                                                  CHUNK, CHUNK / 64 / KS, DIM);
  }

  finalize<<<NTOK, 256, 0, stream>>>(parts, denom, ve, batch, out, KS);
}

// Round 5
// 825.358 us; speedup vs baseline: 1.4235x; 1.1988x over previous
//
#include <hip/hip_runtime.h>

// out = 0.5*ve[batch] + 0.5 * softmax((lang[batch]@W) @ keyᵀ) @ ve
// (bias b cancels in softmax). bf16 MFMA 16x16x32, f32 accumulate.
// Full-P dataflow: P=exp(qW@keyᵀ) materialized once (row-sums fused into the
// epilogue), then one deep-K 256² pipelined GEMM for P@veT. Deterministic
// fallback to vocab-chunked scheme if ws_size is too small.

#define DIM   1024
#define VOCAB 32000
#define NTOK  4096

typedef unsigned short u16;
typedef __attribute__((ext_vector_type(8))) __bf16 bf16x8;
typedef __attribute__((ext_vector_type(4))) float  f32x4;
typedef __attribute__((ext_vector_type(8))) u16    u16x8;
typedef __attribute__((ext_vector_type(4))) u16    u16x4;

__device__ __forceinline__ u16 f2bf(float f) {  // round-to-nearest-even
  unsigned u = __float_as_uint(f);
  u += 0x7FFFu + ((u >> 16) & 1u);
  return (u16)(u >> 16);
}
__device__ __forceinline__ float bf2f(u16 s) {
  return __uint_as_float(((unsigned)s) << 16);
}

#define SB() __builtin_amdgcn_sched_barrier(0)
#define BAR() { SB(); __builtin_amdgcn_s_barrier(); SB(); }

// ---------------- conversion / gather ----------------

__global__ void cvt_f32_bf16(const float* __restrict__ in, u16* __restrict__ out) {
  size_t i = (size_t)blockIdx.x * 256 + threadIdx.x;
  float4 v = ((const float4*)in)[i];
  u16x4 o; o[0]=f2bf(v.x); o[1]=f2bf(v.y); o[2]=f2bf(v.z); o[3]=f2bf(v.w);
  ((u16x4*)out)[i] = o;
}

__global__ void gather_q(const int* __restrict__ batch, const float* __restrict__ lang,
                         u16* __restrict__ q) {
  int row = blockIdx.x;
  int src = batch[row];
  int t = threadIdx.x;
  float4 v = *(const float4*)(lang + (size_t)src * DIM + (t << 2));
  u16x4 o; o[0]=f2bf(v.x); o[1]=f2bf(v.y); o[2]=f2bf(v.z); o[3]=f2bf(v.w);
  *(u16x4*)(q + (size_t)row * DIM + (t << 2)) = o;
}

// out[c][r] = bf16(in[r][c]) ; 64x64 tiles via LDS. grid = (R/64, C/64)
__global__ void transpose_cvt(const float* __restrict__ in, u16* __restrict__ out,
                              int ldin, int ldout) {
  __shared__ u16 t[64][72];
  int r0 = blockIdx.x << 6;
  int c0 = blockIdx.y << 6;
  int tid = threadIdx.x;
  #pragma unroll
  for (int p = 0; p < 4; ++p) {
    int r = (p << 4) + (tid >> 4);
    int c = (tid & 15) << 2;
    float4 v = *(const float4*)(in + (size_t)(r0 + r) * ldin + c0 + c);
    t[c+0][r] = f2bf(v.x);
    t[c+1][r] = f2bf(v.y);
    t[c+2][r] = f2bf(v.z);
    t[c+3][r] = f2bf(v.w);
  }
  __syncthreads();
  #pragma unroll
  for (int qq = 0; qq < 2; ++qq) {
    int rr = tid >> 2;
    int cc = (((tid & 3) << 1) + qq) << 3;
    u16x8 w;
    #pragma unroll
    for (int j = 0; j < 8; ++j) w[j] = t[rr][cc + j];
    *(u16x8*)(out + (size_t)(c0 + rr) * ldout + r0 + cc) = w;
  }
}

// ---------------- small GEMM for qW: C[M,N]=A@B^T, 128x128 tile ----------------
__global__ void gemm_qw(const u16* __restrict__ A, const u16* __restrict__ B,
                        u16* __restrict__ C, int K, int kSteps, int ldc) {
  __shared__ u16 As[128 * 32];
  __shared__ u16 Bs[128 * 32];
  const int tid  = threadIdx.x;
  const int lane = tid & 63;
  const int wid  = tid >> 6;
  const int wr   = wid >> 1, wc = wid & 1;
  const int row0 = blockIdx.x << 7;
  const int col0 = blockIdx.y << 7;

  f32x4 acc[4][4];
  #pragma unroll
  for (int m = 0; m < 4; ++m)
    #pragma unroll
    for (int n = 0; n < 4; ++n) acc[m][n] = (f32x4){0.f,0.f,0.f,0.f};

  const int sr = lane >> 2;
  const int sc = (lane & 3) << 3;

  for (int ks = 0; ks < kSteps; ++ks) {
    const int kk = ks << 5;
    #pragma unroll
    for (int t = 0; t < 2; ++t) {
      const int i = wid * 2 + t;
      const u16* gA = A + (size_t)(row0 + (i << 4) + sr) * K + kk + sc;
      const u16* gB = B + (size_t)(col0 + (i << 4) + sr) * K + kk + sc;
      __builtin_amdgcn_global_load_lds((const __attribute__((address_space(1))) void*)gA,
                                       (__attribute__((address_space(3))) void*)(As + i * 512),
                                       16, 0, 0);
      __builtin_amdgcn_global_load_lds((const __attribute__((address_space(1))) void*)gB,
                                       (__attribute__((address_space(3))) void*)(Bs + i * 512),
                                       16, 0, 0);
    }
    __syncthreads();
    bf16x8 a[4], b[4];
    #pragma unroll
    for (int m = 0; m < 4; ++m)
      a[m] = *(const bf16x8*)(As + ((wr << 6) + (m << 4) + (lane & 15)) * 32 + ((lane >> 4) << 3));
    #pragma unroll
    for (int n = 0; n < 4; ++n)
      b[n] = *(const bf16x8*)(Bs + ((wc << 6) + (n << 4) + (lane & 15)) * 32 + ((lane >> 4) << 3));
    #pragma unroll
    for (int m = 0; m < 4; ++m)
      #pragma unroll
      for (int n = 0; n < 4; ++n)
        acc[m][n] = __builtin_amdgcn_mfma_f32_16x16x32_bf16(a[m], b[n], acc[m][n], 0, 0, 0);
    __syncthreads();
  }

  const int r0 = row0 + (wr << 6);
  const int c0 = col0 + (wc << 6);
  const int fq = (lane >> 4) << 2;
  const int fr = lane & 15;
  #pragma unroll
  for (int m = 0; m < 4; ++m)
    #pragma unroll
    for (int n = 0; n < 4; ++n) {
      int col = c0 + (n << 4) + fr;
      #pragma unroll
      for (int j = 0; j < 4; ++j) {
        int row = r0 + (m << 4) + fq + j;
        C[(size_t)row * ldc + col] = f2bf(acc[m][n][j]);
      }
    }
}

// ---------------- 128x128 pipelined exp-GEMM (MODE1), 2 blocks/CU -------------
// 4 waves (2M x 2N), BK=64, 2 LDS buffers (64 KiB), counted vmcnt(8).
// Epilogue: P = bf16(exp(acc)), per-(row,colblock) row-sum partial to dpart.
__global__ __launch_bounds__(256, 2) void gemm128e(const u16* __restrict__ A,
                                                   const u16* __restrict__ B,
                                                   u16* __restrict__ P,
                                                   float* __restrict__ dpart,
                                                   int K, int nTiles, int ldc, int cb0) {
  __shared__ __align__(16) u16 lds[32768];  // 2 bufs x (A 128x64 | B 128x64)
  const int tid  = threadIdx.x;
  const int lane = tid & 63;
  const int wid  = tid >> 6;        // 0..3
  const int wr   = wid >> 1;        // 0..1 (M)
  const int wc   = wid & 1;         // 0..1 (N)

  const int nwg = (int)(gridDim.x * gridDim.y);
  int lin = blockIdx.y * gridDim.x + blockIdx.x;
  { const int cpx = nwg >> 3; lin = (lin & 7) * cpx + (lin >> 3); }
  const int row0 = (lin & 31) << 7;    // gridDim.x == 32
  const int cblk = lin >> 5;
  const int col0 = cblk << 7;

  const int fr = lane & 15;
  const int fq = lane >> 4;
  const int rb = tid >> 3;          // 0..31 staging row within 32-row group
  const int ss = tid & 7;           // staging 16B slot

#define STG128(d, kk)                                                              \
  {                                                                                \
    _Pragma("unroll")                                                              \
    for (int c = 0; c < 4; ++c) {                                                  \
      const int ra = (c << 5) + rb;                                                \
      const u16* gA = A + (size_t)(row0 + ra) * K + (kk) + ((ss ^ (ra & 7)) << 3); \
      __builtin_amdgcn_global_load_lds(                                            \
          (const __attribute__((address_space(1))) void*)gA,                       \
          (__attribute__((address_space(3))) void*)(lds + (d) * 16384 + (((c << 5) + (wid << 3)) << 6)), \
          16, 0, 0);                                                               \
    }                                                                              \
    _Pragma("unroll")                                                              \
    for (int c = 0; c < 4; ++c) {                                                  \
      const int rn = (c << 5) + rb;                                                \
      const u16* gB = B + (size_t)(col0 + rn) * K + (kk) + ((ss ^ (rn & 7)) << 3); \
      __builtin_amdgcn_global_load_lds(                                            \
          (const __attribute__((address_space(1))) void*)gB,                       \
          (__attribute__((address_space(3))) void*)(lds + (d) * 16384 + 8192 + (((c << 5) + (wid << 3)) << 6)), \
          16, 0, 0);                                                               \
    }                                                                              \
  }

  f32x4 acc[4][4];
  #pragma unroll
  for (int m = 0; m < 4; ++m)
    #pragma unroll
    for (int n = 0; n < 4; ++n) acc[m][n] = (f32x4){0.f, 0.f, 0.f, 0.f};

  STG128(0, 0)
  STG128(1, 64)

  bf16x8 a[4], b[4];

  for (int t = 0; t < nTiles; ++t) {
    const int d = t & 1;
    const u16* Abuf = lds + d * 16384;
    const u16* Bbuf = Abuf + 8192;
    SB();
    if (t + 1 < nTiles) { asm volatile("s_waitcnt vmcnt(8)"); }
    else                { asm volatile("s_waitcnt vmcnt(0)"); }
    BAR();

    #pragma unroll
    for (int ks = 0; ks < 2; ++ks) {
      #pragma unroll
      for (int mq = 0; mq < 4; ++mq) {
        const int row  = (wr << 6) + (mq << 4) + fr;
        const int slot = ((ks << 2) + fq) ^ (row & 7);
        a[mq] = *(const bf16x8*)(Abuf + (row << 6) + (slot << 3));
      }
      #pragma unroll
      for (int nq = 0; nq < 4; ++nq) {
        const int row  = (wc << 6) + (nq << 4) + fr;
        const int slot = ((ks << 2) + fq) ^ (row & 7);
        b[nq] = *(const bf16x8*)(Bbuf + (row << 6) + (slot << 3));
      }
      BAR();
      __builtin_amdgcn_s_setprio(1);
      #pragma unroll
      for (int mq = 0; mq < 4; ++mq)
        #pragma unroll
        for (int nq = 0; nq < 4; ++nq)
          acc[mq][nq] = __builtin_amdgcn_mfma_f32_16x16x32_bf16(
              a[mq], b[nq], acc[mq][nq], 0, 0, 0);
      __builtin_amdgcn_s_setprio(0);
      BAR();
    }
    if (t + 2 < nTiles) STG128(d, (t + 2) << 6)
  }
#undef STG128

  // epilogue: P = bf16(exp(acc)); per-row partial sums
  float rs[16];
  #pragma unroll
  for (int i = 0; i < 16; ++i) rs[i] = 0.f;
  #pragma unroll
  for (int mq = 0; mq < 4; ++mq)
    #pragma unroll
    for (int nq = 0; nq < 4; ++nq) {
      const int col = col0 + (wc << 6) + (nq << 4) + fr;
      #pragma unroll
      for (int j = 0; j < 4; ++j) {
        const int row = row0 + (wr << 6) + (mq << 4) + (fq << 2) + j;
        float e = __expf(acc[mq][nq][j]);
        P[(size_t)row * ldc + col] = f2bf(e);
        rs[(mq << 2) + j] += e;
      }
    }
  #pragma unroll
  for (int i = 0; i < 16; ++i) {
    #pragma unroll
    for (int s = 8; s >= 1; s >>= 1) rs[i] += __shfl_xor(rs[i], s, 16);
  }
  __syncthreads();
  float* dsm = (float*)lds;   // 2 x 128 floats, per-wc slices (deterministic)
  if (fr == 0) {
    #pragma unroll
    for (int mq = 0; mq < 4; ++mq)
      #pragma unroll
      for (int j = 0; j < 4; ++j)
        dsm[(wc << 7) + (wr << 6) + (mq << 4) + (fq << 2) + j] = rs[(mq << 2) + j];
  }
  __syncthreads();
  if (tid < 128)
    dpart[(size_t)(row0 + tid) * 256 + cb0 + cblk] = dsm[tid] + dsm[128 + tid];
}

// ---------------- 256x256 pipelined GEMM: C[M,N] = A[M,K] @ B[N,K]^T ----------
// 8 waves (2M x 4N), BK=64, 2 LDS buffers, counted vmcnt(8).
// MODE 2: C(f32, slice z) += acc (chunked fallback);  MODE 3: plain store.
template<int MODE>
__global__ __launch_bounds__(512, 2) void gemm256(const u16* __restrict__ A,
                                                  const u16* __restrict__ B,
                                                  float* __restrict__ Cout,
                                                  int K, int nTiles, int ldc) {
  __shared__ __align__(16) u16 lds[65536];
  const int tid  = threadIdx.x;
  const int lane = tid & 63;
  const int wid  = tid >> 6;
  const int wr   = wid >> 2;
  const int wc   = wid & 3;

  const int nwg = (int)(gridDim.x * gridDim.y);
  int lin = blockIdx.y * gridDim.x + blockIdx.x;
  { const int cpx = nwg >> 3; lin = (lin & 7) * cpx + (lin >> 3); }
  const int row0 = (lin & 15) << 8;    // gridDim.x == 16
  const int col0 = (lin >> 4) << 8;

  const int kbase = blockIdx.z * (nTiles << 6);
  const int fr = lane & 15;
  const int fq = lane >> 4;
  const int rb = tid >> 3;
  const int ss = tid & 7;

#define STG256(d, kk)                                                              \
  {                                                                                \
    _Pragma("unroll")                                                              \
    for (int c = 0; c < 4; ++c) {                                                  \
      const int ra = (c << 6) + rb;                                                \
      const u16* gA = A + (size_t)(row0 + ra) * K + (kk) + ((ss ^ (ra & 7)) << 3); \
      __builtin_amdgcn_global_load_lds(                                            \
          (const __attribute__((address_space(1))) void*)gA,                       \
          (__attribute__((address_space(3))) void*)(lds + (d) * 32768 + (((c << 6) + (wid << 3)) << 6)), \
          16, 0, 0);                                                               \
    }                                                                              \
    _Pragma("unroll")                                                              \
    for (int c = 0; c < 4; ++c) {                                                  \
      const int rn = (c << 6) + rb;                                                \
      const u16* gB = B + (size_t)(col0 + rn) * K + (kk) + ((ss ^ (rn & 7)) << 3); \
      __builtin_amdgcn_global_load_lds(                                            \
          (const __attribute__((address_space(1))) void*)gB,                       \
          (__attribute__((address_space(3))) void*)(lds + (d) * 32768 + 16384 + (((c << 6) + (wid << 3)) << 6)), \
          16, 0, 0);                                                               \
    }                                                                              \
  }

  f32x4 acc[8][4];
  #pragma unroll
  for (int m = 0; m < 8; ++m)
    #pragma unroll
    for (int n = 0; n < 4; ++n) acc[m][n] = (f32x4){0.f, 0.f, 0.f, 0.f};

  STG256(0, kbase)
  STG256(1, kbase + 64)

  bf16x8 a[4][2], b[2][2];

  for (int t = 0; t < nTiles; ++t) {
    const int d = t & 1;
    const u16* Abuf = lds + d * 32768;
    const u16* Bbuf = Abuf + 16384;
    SB();
    if (t + 1 < nTiles) { asm volatile("s_waitcnt vmcnt(8)"); }
    else                { asm volatile("s_waitcnt vmcnt(0)"); }
    BAR();

    #pragma unroll
    for (int ph = 0; ph < 4; ++ph) {
      const int mh = ph >> 1, nh = ph & 1;
      if (nh == 0) {
        #pragma unroll
        for (int mq = 0; mq < 4; ++mq)
          #pragma unroll
          for (int ks = 0; ks < 2; ++ks) {
            const int row  = (wr << 7) + (mh << 6) + (mq << 4) + fr;
            const int slot = ((ks << 2) + fq) ^ (row & 7);
            a[mq][ks] = *(const bf16x8*)(Abuf + (row << 6) + (slot << 3));
          }
      }
      #pragma unroll
      for (int nq = 0; nq < 2; ++nq)
        #pragma unroll
        for (int ks = 0; ks < 2; ++ks) {
          const int row  = (wc << 6) + (nh << 5) + (nq << 4) + fr;
          const int slot = ((ks << 2) + fq) ^ (row & 7);
          b[nq][ks] = *(const bf16x8*)(Bbuf + (row << 6) + (slot << 3));
        }
      BAR();
      __builtin_amdgcn_s_setprio(1);
      #pragma unroll
      for (int mq = 0; mq < 4; ++mq)
        #pragma unroll
        for (int nq = 0; nq < 2; ++nq)
          #pragma unroll
          for (int ks = 0; ks < 2; ++ks)
            acc[(mh << 2) + mq][(nh << 1) + nq] =
                __builtin_amdgcn_mfma_f32_16x16x32_bf16(
                    a[mq][ks], b[nq][ks], acc[(mh << 2) + mq][(nh << 1) + nq], 0, 0, 0);
      __builtin_amdgcn_s_setprio(0);
      BAR();
    }
    if (t + 2 < nTiles) STG256(d, kbase + ((t + 2) << 6))
  }
#undef STG256

  float* C = Cout + (size_t)blockIdx.z * NTOK * DIM;
  #pragma unroll
  for (int m = 0; m < 8; ++m)
    #pragma unroll
    for (int n = 0; n < 4; ++n) {
      const int col = col0 + (wc << 6) + (n << 4) + fr;
      #pragma unroll
      for (int j = 0; j < 4; ++j) {
        const int row = row0 + (wr << 7) + (m << 4) + (fq << 2) + j;
        if (MODE == 2) C[(size_t)row * ldc + col] += acc[m][n][j];
        else           C[(size_t)row * ldc + col]  = acc[m][n][j];
      }
    }
}

// ---------------- denom reduce: denom[row] = sum of 250 colblock partials -----
__global__ void denom_reduce(const float* __restrict__ dpart, float* __restrict__ denom) {
  int row = blockIdx.x;
  int l = threadIdx.x;              // 64
  float s = 0.f;
  #pragma unroll
  for (int k = 0; k < 4; ++k) {
    int idx = l + (k << 6);
    if (idx < 250) s += dpart[(size_t)row * 256 + idx];
  }
  #pragma unroll
  for (int off = 32; off >= 1; off >>= 1) s += __shfl_down(s, off, 64);
  if (l == 0) denom[row] = s;
}

// ---------------- finalize ----------------
__global__ void finalize(const float* __restrict__ parts, const float* __restrict__ denom,
                         const float* __restrict__ ve, const int* __restrict__ batch,
                         float* __restrict__ out, int nks) {
  int row = blockIdx.x;
  int t = threadIdx.x;
  float inv = 0.5f / denom[row];
  float4 a = *(const float4*)(ve + (size_t)batch[row] * DIM + (t << 2));
  float sx = 0.f, sy = 0.f, sz = 0.f, sw = 0.f;
  for (int ks = 0; ks < nks; ++ks) {
    float4 pv = *(const float4*)(parts + ((size_t)ks * NTOK + row) * DIM + (t << 2));
    sx += pv.x; sy += pv.y; sz += pv.z; sw += pv.w;
  }
  float4 o;
  o.x = 0.5f * a.x + inv * sx;
  o.y = 0.5f * a.y + inv * sy;
  o.z = 0.5f * a.z + inv * sz;
  o.w = 0.5f * a.w + inv * sw;
  *(float4*)(out + (size_t)row * DIM + (t << 2)) = o;
}

// ---------------- launch ----------------
extern "C" void kernel_launch(void* const* d_in, const int* in_sizes, int n_in,
                              void* d_out, int out_size, void* d_ws, size_t ws_size,
                              hipStream_t stream) {
  const int*   batch = (const int*)d_in[0];
  const float* lang  = (const float*)d_in[1];
  const float* key   = (const float*)d_in[2];
  const float* ve    = (const float*)d_in[3];
  const float* W     = (const float*)d_in[4];
  float* out = (float*)d_out;

  const size_t szWt    = (size_t)DIM * DIM * 2;          //  2 MiB
  const size_t szQb    = (size_t)NTOK * DIM * 2;         //  8 MiB
  const size_t szQW    = (size_t)NTOK * DIM * 2;         //  8 MiB
  const size_t szDpart = (size_t)NTOK * 256 * 4;         //  4 MiB
  const size_t szDenom = (size_t)NTOK * 4;
  const size_t base    = szWt + szQb + szQW + szDpart + szDenom;

  char* ws = (char*)d_ws;
  u16*   Wt    = (u16*)(ws);
  u16*   qb    = (u16*)(ws + szWt);
  u16*   qW    = (u16*)(ws + szWt + szQb);
  float* dpart = (float*)(ws + szWt + szQb + szQW);
  float* denom = (float*)(ws + szWt + szQb + szQW + szDpart);

  // full-P plan sizes
  const int KSF = 4;
  const size_t szPartsF = (size_t)KSF * NTOK * DIM * 4;  // 67 MiB
  const size_t szKeyb   = (size_t)VOCAB * DIM * 2;       // 65.5 MB
  const size_t szVeT    = (size_t)VOCAB * DIM * 2;       // 65.5 MB
  const size_t szP      = (size_t)NTOK * VOCAB * 2;      // 262 MB
  const bool fullP = (base + szPartsF + szKeyb + szVeT + szP) <= ws_size;

  // shared prologue
  transpose_cvt<<<dim3(DIM / 64, DIM / 64), 256, 0, stream>>>(W, Wt, DIM, DIM);
  gather_q<<<NTOK, 256, 0, stream>>>(batch, lang, qb);
  gemm_qw<<<dim3(NTOK / 128, DIM / 128), 256, 0, stream>>>(qb, Wt, qW, DIM, DIM / 32, DIM);

  if (fullP) {
    float* parts = (float*)(ws + base);
    u16*   keyb  = (u16*)(ws + base + szPartsF);
    u16*   veT   = (u16*)(ws + base + szPartsF + szKeyb);
    u16*   P     = (u16*)(ws + base + szPartsF + szKeyb + szVeT);

    cvt_f32_bf16<<<VOCAB * DIM / 1024, 256, 0, stream>>>(key, keyb);
    transpose_cvt<<<dim3(VOCAB / 64, DIM / 64), 256, 0, stream>>>(ve, veT, DIM, VOCAB);
    // P = exp(qW @ keyb^T), fused row-sum partials
    gemm128e<<<dim3(NTOK / 128, VOCAB / 128), 256, 0, stream>>>(qW, keyb, P, dpart,
                                                                DIM, DIM / 64, VOCAB, 0);
    denom_reduce<<<NTOK, 64, 0, stream>>>(dpart, denom);
    // parts[z] = P @ veT^T (split-K over vocab, plain store)
    gemm256<3><<<dim3(NTOK / 256, DIM / 256, KSF), 512, 0, stream>>>(P, veT, parts,
                                                                     VOCAB, VOCAB / 64 / KSF, DIM);
    finalize<<<NTOK, 256, 0, stream>>>(parts, denom, ve, batch, out, KSF);
  } else {
    // chunked fallback
    const int KS = 2;
    const size_t szParts = (size_t)KS * NTOK * DIM * 4;
    int CHUNK = 1280;
    {
      const int copt[2] = {6400, 1280};
      for (int i = 0; i < 2; ++i) {
        size_t need = base + szParts + (size_t)copt[i] * (NTOK * 2 + DIM * 4);
        if (need <= ws_size) { CHUNK = copt[i]; break; }
      }
    }
    const int NCHUNK = VOCAB / CHUNK;
    float* parts = (float*)(ws + base);
    char*  dyn   = ws + base + szParts;
    u16*   keyc  = (u16*)(dyn);
    u16*   veTc  = (u16*)(dyn + (size_t)CHUNK * DIM * 2);
    u16*   Pc    = (u16*)(dyn + (size_t)CHUNK * DIM * 4);

    hipMemsetAsync(parts, 0, szParts, stream);
    for (int c = 0; c < NCHUNK; ++c) {
      const int v0 = c * CHUNK;
      cvt_f32_bf16<<<CHUNK * DIM / 1024, 256, 0, stream>>>(key + (size_t)v0 * DIM, keyc);
      transpose_cvt<<<dim3(CHUNK / 64, DIM / 64), 256, 0, stream>>>(ve + (size_t)v0 * DIM, veTc,
                                                                    DIM, CHUNK);
      gemm128e<<<dim3(NTOK / 128, CHUNK / 128), 256, 0, stream>>>(qW, keyc, Pc, dpart,
                                                                  DIM, DIM / 64, CHUNK, v0 >> 7);
      gemm256<2><<<dim3(NTOK / 256, DIM / 256, KS), 512, 0, stream>>>(Pc, veTc, parts,
                                                                      CHUNK, CHUNK / 64 / KS, DIM);
    }
    denom_reduce<<<NTOK, 64, 0, stream>>>(dpart, denom);
    finalize<<<NTOK, 256, 0, stream>>>(parts, denom, ve, batch, out, KS);
  }
}

// Round 6
// 743.130 us; speedup vs baseline: 1.5810x; 1.1107x over previous
//
#include <hip/hip_runtime.h>

// out = 0.5*ve[batch] + 0.5 * softmax((lang[batch]@W) @ keyᵀ) @ ve
// (bias b cancels in softmax). bf16 MFMA 16x16x32, f32 accumulate.
// Full-P dataflow: P=exp(qW@keyᵀ) via 256² pipelined GEMM with fused row-sum
// partials, then one deep-K 256² GEMM for P@veT. Chunked fallback if ws small.

#define DIM   1024
#define VOCAB 32000
#define NTOK  4096

typedef unsigned short u16;
typedef __attribute__((ext_vector_type(8))) __bf16 bf16x8;
typedef __attribute__((ext_vector_type(4))) float  f32x4;
typedef __attribute__((ext_vector_type(8))) u16    u16x8;
typedef __attribute__((ext_vector_type(4))) u16    u16x4;

__device__ __forceinline__ u16 f2bf(float f) {  // round-to-nearest-even
  unsigned u = __float_as_uint(f);
  u += 0x7FFFu + ((u >> 16) & 1u);
  return (u16)(u >> 16);
}
__device__ __forceinline__ float bf2f(u16 s) {
  return __uint_as_float(((unsigned)s) << 16);
}

#define SB() __builtin_amdgcn_sched_barrier(0)
#define BAR() { SB(); __builtin_amdgcn_s_barrier(); SB(); }

// ---------------- conversion / gather ----------------

__global__ void cvt_f32_bf16(const float* __restrict__ in, u16* __restrict__ out) {
  size_t i = (size_t)blockIdx.x * 256 + threadIdx.x;
  float4 v = ((const float4*)in)[i];
  u16x4 o; o[0]=f2bf(v.x); o[1]=f2bf(v.y); o[2]=f2bf(v.z); o[3]=f2bf(v.w);
  ((u16x4*)out)[i] = o;
}

__global__ void gather_q(const int* __restrict__ batch, const float* __restrict__ lang,
                         u16* __restrict__ q) {
  int row = blockIdx.x;
  int src = batch[row];
  int t = threadIdx.x;
  float4 v = *(const float4*)(lang + (size_t)src * DIM + (t << 2));
  u16x4 o; o[0]=f2bf(v.x); o[1]=f2bf(v.y); o[2]=f2bf(v.z); o[3]=f2bf(v.w);
  *(u16x4*)(q + (size_t)row * DIM + (t << 2)) = o;
}

// out[c][r] = bf16(in[r][c]) ; 64x64 tiles via LDS. grid = (R/64, C/64)
__global__ void transpose_cvt(const float* __restrict__ in, u16* __restrict__ out,
                              int ldin, int ldout) {
  __shared__ u16 t[64][72];
  int r0 = blockIdx.x << 6;
  int c0 = blockIdx.y << 6;
  int tid = threadIdx.x;
  #pragma unroll
  for (int p = 0; p < 4; ++p) {
    int r = (p << 4) + (tid >> 4);
    int c = (tid & 15) << 2;
    float4 v = *(const float4*)(in + (size_t)(r0 + r) * ldin + c0 + c);
    t[c+0][r] = f2bf(v.x);
    t[c+1][r] = f2bf(v.y);
    t[c+2][r] = f2bf(v.z);
    t[c+3][r] = f2bf(v.w);
  }
  __syncthreads();
  #pragma unroll
  for (int qq = 0; qq < 2; ++qq) {
    int rr = tid >> 2;
    int cc = (((tid & 3) << 1) + qq) << 3;
    u16x8 w;
    #pragma unroll
    for (int j = 0; j < 8; ++j) w[j] = t[rr][cc + j];
    *(u16x8*)(out + (size_t)(c0 + rr) * ldout + r0 + cc) = w;
  }
}

// ---------------- small GEMM for qW: C[M,N]=A@B^T, 128x128 tile ----------------
__global__ void gemm_qw(const u16* __restrict__ A, const u16* __restrict__ B,
                        u16* __restrict__ C, int K, int kSteps, int ldc) {
  __shared__ u16 As[128 * 32];
  __shared__ u16 Bs[128 * 32];
  const int tid  = threadIdx.x;
  const int lane = tid & 63;
  const int wid  = tid >> 6;
  const int wr   = wid >> 1, wc = wid & 1;
  const int row0 = blockIdx.x << 7;
  const int col0 = blockIdx.y << 7;

  f32x4 acc[4][4];
  #pragma unroll
  for (int m = 0; m < 4; ++m)
    #pragma unroll
    for (int n = 0; n < 4; ++n) acc[m][n] = (f32x4){0.f,0.f,0.f,0.f};

  const int sr = lane >> 2;
  const int sc = (lane & 3) << 3;

  for (int ks = 0; ks < kSteps; ++ks) {
    const int kk = ks << 5;
    #pragma unroll
    for (int t = 0; t < 2; ++t) {
      const int i = wid * 2 + t;
      const u16* gA = A + (size_t)(row0 + (i << 4) + sr) * K + kk + sc;
      const u16* gB = B + (size_t)(col0 + (i << 4) + sr) * K + kk + sc;
      __builtin_amdgcn_global_load_lds((const __attribute__((address_space(1))) void*)gA,
                                       (__attribute__((address_space(3))) void*)(As + i * 512),
                                       16, 0, 0);
      __builtin_amdgcn_global_load_lds((const __attribute__((address_space(1))) void*)gB,
                                       (__attribute__((address_space(3))) void*)(Bs + i * 512),
                                       16, 0, 0);
    }
    __syncthreads();
    bf16x8 a[4], b[4];
    #pragma unroll
    for (int m = 0; m < 4; ++m)
      a[m] = *(const bf16x8*)(As + ((wr << 6) + (m << 4) + (lane & 15)) * 32 + ((lane >> 4) << 3));
    #pragma unroll
    for (int n = 0; n < 4; ++n)
      b[n] = *(const bf16x8*)(Bs + ((wc << 6) + (n << 4) + (lane & 15)) * 32 + ((lane >> 4) << 3));
    #pragma unroll
    for (int m = 0; m < 4; ++m)
      #pragma unroll
      for (int n = 0; n < 4; ++n)
        acc[m][n] = __builtin_amdgcn_mfma_f32_16x16x32_bf16(a[m], b[n], acc[m][n], 0, 0, 0);
    __syncthreads();
  }

  const int r0 = row0 + (wr << 6);
  const int c0 = col0 + (wc << 6);
  const int fq = (lane >> 4) << 2;
  const int fr = lane & 15;
  #pragma unroll
  for (int m = 0; m < 4; ++m)
    #pragma unroll
    for (int n = 0; n < 4; ++n) {
      int col = c0 + (n << 4) + fr;
      #pragma unroll
      for (int j = 0; j < 4; ++j) {
        int row = r0 + (m << 4) + fq + j;
        C[(size_t)row * ldc + col] = f2bf(acc[m][n][j]);
      }
    }
}

// ---------------- 128x128 pipelined exp-GEMM (chunked fallback only) ----------
__global__ __launch_bounds__(256, 2) void gemm128e(const u16* __restrict__ A,
                                                   const u16* __restrict__ B,
                                                   u16* __restrict__ P,
                                                   float* __restrict__ dpart,
                                                   int K, int nTiles, int ldc, int cb0) {
  __shared__ __align__(16) u16 lds[32768];  // 2 bufs x (A 128x64 | B 128x64)
  const int tid  = threadIdx.x;
  const int lane = tid & 63;
  const int wid  = tid >> 6;        // 0..3
  const int wr   = wid >> 1;        // 0..1 (M)
  const int wc   = wid & 1;         // 0..1 (N)

  const int nwg = (int)(gridDim.x * gridDim.y);
  int lin = blockIdx.y * gridDim.x + blockIdx.x;
  { const int cpx = nwg >> 3; lin = (lin & 7) * cpx + (lin >> 3); }
  const int row0 = (lin & 31) << 7;    // gridDim.x == 32
  const int cblk = lin >> 5;
  const int col0 = cblk << 7;

  const int fr = lane & 15;
  const int fq = lane >> 4;
  const int rb = tid >> 3;
  const int ss = tid & 7;

#define STG128(d, kk)                                                              \
  {                                                                                \
    _Pragma("unroll")                                                              \
    for (int c = 0; c < 4; ++c) {                                                  \
      const int ra = (c << 5) + rb;                                                \
      const u16* gA = A + (size_t)(row0 + ra) * K + (kk) + ((ss ^ (ra & 7)) << 3); \
      __builtin_amdgcn_global_load_lds(                                            \
          (const __attribute__((address_space(1))) void*)gA,                       \
          (__attribute__((address_space(3))) void*)(lds + (d) * 16384 + (((c << 5) + (wid << 3)) << 6)), \
          16, 0, 0);                                                               \
    }                                                                              \
    _Pragma("unroll")                                                              \
    for (int c = 0; c < 4; ++c) {                                                  \
      const int rn = (c << 5) + rb;                                                \
      const u16* gB = B + (size_t)(col0 + rn) * K + (kk) + ((ss ^ (rn & 7)) << 3); \
      __builtin_amdgcn_global_load_lds(                                            \
          (const __attribute__((address_space(1))) void*)gB,                       \
          (__attribute__((address_space(3))) void*)(lds + (d) * 16384 + 8192 + (((c << 5) + (wid << 3)) << 6)), \
          16, 0, 0);                                                               \
    }                                                                              \
  }

  f32x4 acc[4][4];
  #pragma unroll
  for (int m = 0; m < 4; ++m)
    #pragma unroll
    for (int n = 0; n < 4; ++n) acc[m][n] = (f32x4){0.f, 0.f, 0.f, 0.f};

  STG128(0, 0)
  STG128(1, 64)

  bf16x8 a[4], b[4];

  for (int t = 0; t < nTiles; ++t) {
    const int d = t & 1;
    const u16* Abuf = lds + d * 16384;
    const u16* Bbuf = Abuf + 8192;
    SB();
    if (t + 1 < nTiles) { asm volatile("s_waitcnt vmcnt(8)"); }
    else                { asm volatile("s_waitcnt vmcnt(0)"); }
    BAR();

    #pragma unroll
    for (int ks = 0; ks < 2; ++ks) {
      #pragma unroll
      for (int mq = 0; mq < 4; ++mq) {
        const int row  = (wr << 6) + (mq << 4) + fr;
        const int slot = ((ks << 2) + fq) ^ (row & 7);
        a[mq] = *(const bf16x8*)(Abuf + (row << 6) + (slot << 3));
      }
      #pragma unroll
      for (int nq = 0; nq < 4; ++nq) {
        const int row  = (wc << 6) + (nq << 4) + fr;
        const int slot = ((ks << 2) + fq) ^ (row & 7);
        b[nq] = *(const bf16x8*)(Bbuf + (row << 6) + (slot << 3));
      }
      BAR();
      __builtin_amdgcn_s_setprio(1);
      #pragma unroll
      for (int mq = 0; mq < 4; ++mq)
        #pragma unroll
        for (int nq = 0; nq < 4; ++nq)
          acc[mq][nq] = __builtin_amdgcn_mfma_f32_16x16x32_bf16(
              a[mq], b[nq], acc[mq][nq], 0, 0, 0);
      __builtin_amdgcn_s_setprio(0);
      BAR();
    }
    if (t + 2 < nTiles) STG128(d, (t + 2) << 6)
  }
#undef STG128

  float rs[16];
  #pragma unroll
  for (int i = 0; i < 16; ++i) rs[i] = 0.f;
  #pragma unroll
  for (int mq = 0; mq < 4; ++mq)
    #pragma unroll
    for (int nq = 0; nq < 4; ++nq) {
      const int col = col0 + (wc << 6) + (nq << 4) + fr;
      #pragma unroll
      for (int j = 0; j < 4; ++j) {
        const int row = row0 + (wr << 6) + (mq << 4) + (fq << 2) + j;
        float e = __expf(acc[mq][nq][j]);
        P[(size_t)row * ldc + col] = f2bf(e);
        rs[(mq << 2) + j] += e;
      }
    }
  #pragma unroll
  for (int i = 0; i < 16; ++i) {
    #pragma unroll
    for (int s = 8; s >= 1; s >>= 1) rs[i] += __shfl_xor(rs[i], s, 16);
  }
  __syncthreads();
  float* dsm = (float*)lds;
  if (fr == 0) {
    #pragma unroll
    for (int mq = 0; mq < 4; ++mq)
      #pragma unroll
      for (int j = 0; j < 4; ++j)
        dsm[(wc << 7) + (wr << 6) + (mq << 4) + (fq << 2) + j] = rs[(mq << 2) + j];
  }
  __syncthreads();
  if (tid < 128)
    dpart[(size_t)(row0 + tid) * 256 + cb0 + cblk] = dsm[tid] + dsm[128 + tid];
}

// ---------------- 256x256 pipelined exp-GEMM: P = exp(A@B^T), fused rowsum ----
// 8 waves (2M x 4N), BK=64, counted vmcnt(8). grid = (16, N/256).
__global__ __launch_bounds__(512, 2) void gemm256e(const u16* __restrict__ A,
                                                   const u16* __restrict__ B,
                                                   u16* __restrict__ P,
                                                   float* __restrict__ dpart,
                                                   int K, int nTiles, int ldc) {
  __shared__ __align__(16) u16 lds[65536];
  const int tid  = threadIdx.x;
  const int lane = tid & 63;
  const int wid  = tid >> 6;
  const int wr   = wid >> 2;        // 0..1 (M)
  const int wc   = wid & 3;         // 0..3 (N)

  const int nwg = (int)(gridDim.x * gridDim.y);
  int lin = blockIdx.y * gridDim.x + blockIdx.x;
  { const int cpx = nwg >> 3; lin = (lin & 7) * cpx + (lin >> 3); }
  const int row0 = (lin & 15) << 8;    // gridDim.x == 16
  const int cblk = lin >> 4;
  const int col0 = cblk << 8;

  const int fr = lane & 15;
  const int fq = lane >> 4;
  const int rb = tid >> 3;
  const int ss = tid & 7;

#define STG256(d, kk)                                                              \
  {                                                                                \
    _Pragma("unroll")                                                              \
    for (int c = 0; c < 4; ++c) {                                                  \
      const int ra = (c << 6) + rb;                                                \
      const u16* gA = A + (size_t)(row0 + ra) * K + (kk) + ((ss ^ (ra & 7)) << 3); \
      __builtin_amdgcn_global_load_lds(                                            \
          (const __attribute__((address_space(1))) void*)gA,                       \
          (__attribute__((address_space(3))) void*)(lds + (d) * 32768 + (((c << 6) + (wid << 3)) << 6)), \
          16, 0, 0);                                                               \
    }                                                                              \
    _Pragma("unroll")                                                              \
    for (int c = 0; c < 4; ++c) {                                                  \
      const int rn = (c << 6) + rb;                                                \
      const u16* gB = B + (size_t)(col0 + rn) * K + (kk) + ((ss ^ (rn & 7)) << 3); \
      __builtin_amdgcn_global_load_lds(                                            \
          (const __attribute__((address_space(1))) void*)gB,                       \
          (__attribute__((address_space(3))) void*)(lds + (d) * 32768 + 16384 + (((c << 6) + (wid << 3)) << 6)), \
          16, 0, 0);                                                               \
    }                                                                              \
  }

  f32x4 acc[8][4];
  #pragma unroll
  for (int m = 0; m < 8; ++m)
    #pragma unroll
    for (int n = 0; n < 4; ++n) acc[m][n] = (f32x4){0.f, 0.f, 0.f, 0.f};

  STG256(0, 0)
  STG256(1, 64)

  bf16x8 a[4][2], b[2][2];

  for (int t = 0; t < nTiles; ++t) {
    const int d = t & 1;
    const u16* Abuf = lds + d * 32768;
    const u16* Bbuf = Abuf + 16384;
    SB();
    if (t + 1 < nTiles) { asm volatile("s_waitcnt vmcnt(8)"); }
    else                { asm volatile("s_waitcnt vmcnt(0)"); }
    BAR();

    #pragma unroll
    for (int ph = 0; ph < 4; ++ph) {
      const int mh = ph >> 1, nh = ph & 1;
      if (nh == 0) {
        #pragma unroll
        for (int mq = 0; mq < 4; ++mq)
          #pragma unroll
          for (int ks = 0; ks < 2; ++ks) {
            const int row  = (wr << 7) + (mh << 6) + (mq << 4) + fr;
            const int slot = ((ks << 2) + fq) ^ (row & 7);
            a[mq][ks] = *(const bf16x8*)(Abuf + (row << 6) + (slot << 3));
          }
      }
      #pragma unroll
      for (int nq = 0; nq < 2; ++nq)
        #pragma unroll
        for (int ks = 0; ks < 2; ++ks) {
          const int row  = (wc << 6) + (nh << 5) + (nq << 4) + fr;
          const int slot = ((ks << 2) + fq) ^ (row & 7);
          b[nq][ks] = *(const bf16x8*)(Bbuf + (row << 6) + (slot << 3));
        }
      BAR();
      __builtin_amdgcn_s_setprio(1);
      #pragma unroll
      for (int mq = 0; mq < 4; ++mq)
        #pragma unroll
        for (int nq = 0; nq < 2; ++nq)
          #pragma unroll
          for (int ks = 0; ks < 2; ++ks)
            acc[(mh << 2) + mq][(nh << 1) + nq] =
                __builtin_amdgcn_mfma_f32_16x16x32_bf16(
                    a[mq][ks], b[nq][ks], acc[(mh << 2) + mq][(nh << 1) + nq], 0, 0, 0);
      __builtin_amdgcn_s_setprio(0);
      BAR();
    }
    if (t + 2 < nTiles) STG256(d, (t + 2) << 6)
  }
#undef STG256

  // epilogue: P = bf16(exp(acc)); fused per-(row,colblock) row-sum partials
  float rs[32];                       // [m*4+j], m=0..7, j=0..3
  #pragma unroll
  for (int i = 0; i < 32; ++i) rs[i] = 0.f;
  #pragma unroll
  for (int m = 0; m < 8; ++m)
    #pragma unroll
    for (int n = 0; n < 4; ++n) {
      const int col = col0 + (wc << 6) + (n << 4) + fr;
      #pragma unroll
      for (int j = 0; j < 4; ++j) {
        const int row = row0 + (wr << 7) + (m << 4) + (fq << 2) + j;
        float e = __expf(acc[m][n][j]);
        P[(size_t)row * ldc + col] = f2bf(e);
        rs[(m << 2) + j] += e;
      }
    }
  #pragma unroll
  for (int i = 0; i < 32; ++i) {
    #pragma unroll
    for (int s = 8; s >= 1; s >>= 1) rs[i] += __shfl_xor(rs[i], s, 16);
  }
  __syncthreads();                    // LDS free for reuse
  float* dsm = (float*)lds;           // [wc][256] = 4 KiB
  if (fr == 0) {
    #pragma unroll
    for (int m = 0; m < 8; ++m)
      #pragma unroll
      for (int j = 0; j < 4; ++j)
        dsm[(wc << 8) + (wr << 7) + (m << 4) + (fq << 2) + j] = rs[(m << 2) + j];
  }
  __syncthreads();
  if (tid < 256)
    dpart[(size_t)(row0 + tid) * 256 + cblk] =
        dsm[tid] + dsm[256 + tid] + dsm[512 + tid] + dsm[768 + tid];
}

// ---------------- 256x256 pipelined GEMM: C[M,N] = A[M,K] @ B[N,K]^T ----------
// MODE 2: C(f32, slice z) += acc (chunked fallback);  MODE 3: plain store.
template<int MODE>
__global__ __launch_bounds__(512, 2) void gemm256(const u16* __restrict__ A,
                                                  const u16* __restrict__ B,
                                                  float* __restrict__ Cout,
                                                  int K, int nTiles, int ldc) {
  __shared__ __align__(16) u16 lds[65536];
  const int tid  = threadIdx.x;
  const int lane = tid & 63;
  const int wid  = tid >> 6;
  const int wr   = wid >> 2;
  const int wc   = wid & 3;

  const int nwg = (int)(gridDim.x * gridDim.y);
  int lin = blockIdx.y * gridDim.x + blockIdx.x;
  { const int cpx = nwg >> 3; lin = (lin & 7) * cpx + (lin >> 3); }
  const int row0 = (lin & 15) << 8;    // gridDim.x == 16
  const int col0 = (lin >> 4) << 8;

  const int kbase = blockIdx.z * (nTiles << 6);
  const int fr = lane & 15;
  const int fq = lane >> 4;
  const int rb = tid >> 3;
  const int ss = tid & 7;

#define STG256(d, kk)                                                              \
  {                                                                                \
    _Pragma("unroll")                                                              \
    for (int c = 0; c < 4; ++c) {                                                  \
      const int ra = (c << 6) + rb;                                                \
      const u16* gA = A + (size_t)(row0 + ra) * K + (kk) + ((ss ^ (ra & 7)) << 3); \
      __builtin_amdgcn_global_load_lds(                                            \
          (const __attribute__((address_space(1))) void*)gA,                       \
          (__attribute__((address_space(3))) void*)(lds + (d) * 32768 + (((c << 6) + (wid << 3)) << 6)), \
          16, 0, 0);                                                               \
    }                                                                              \
    _Pragma("unroll")                                                              \
    for (int c = 0; c < 4; ++c) {                                                  \
      const int rn = (c << 6) + rb;                                                \
      const u16* gB = B + (size_t)(col0 + rn) * K + (kk) + ((ss ^ (rn & 7)) << 3); \
      __builtin_amdgcn_global_load_lds(                                            \
          (const __attribute__((address_space(1))) void*)gB,                       \
          (__attribute__((address_space(3))) void*)(lds + (d) * 32768 + 16384 + (((c << 6) + (wid << 3)) << 6)), \
          16, 0, 0);                                                               \
    }                                                                              \
  }

  f32x4 acc[8][4];
  #pragma unroll
  for (int m = 0; m < 8; ++m)
    #pragma unroll
    for (int n = 0; n < 4; ++n) acc[m][n] = (f32x4){0.f, 0.f, 0.f, 0.f};

  STG256(0, kbase)
  STG256(1, kbase + 64)

  bf16x8 a[4][2], b[2][2];

  for (int t = 0; t < nTiles; ++t) {
    const int d = t & 1;
    const u16* Abuf = lds + d * 32768;
    const u16* Bbuf = Abuf + 16384;
    SB();
    if (t + 1 < nTiles) { asm volatile("s_waitcnt vmcnt(8)"); }
    else                { asm volatile("s_waitcnt vmcnt(0)"); }
    BAR();

    #pragma unroll
    for (int ph = 0; ph < 4; ++ph) {
      const int mh = ph >> 1, nh = ph & 1;
      if (nh == 0) {
        #pragma unroll
        for (int mq = 0; mq < 4; ++mq)
          #pragma unroll
          for (int ks = 0; ks < 2; ++ks) {
            const int row  = (wr << 7) + (mh << 6) + (mq << 4) + fr;
            const int slot = ((ks << 2) + fq) ^ (row & 7);
            a[mq][ks] = *(const bf16x8*)(Abuf + (row << 6) + (slot << 3));
          }
      }
      #pragma unroll
      for (int nq = 0; nq < 2; ++nq)
        #pragma unroll
        for (int ks = 0; ks < 2; ++ks) {
          const int row  = (wc << 6) + (nh << 5) + (nq << 4) + fr;
          const int slot = ((ks << 2) + fq) ^ (row & 7);
          b[nq][ks] = *(const bf16x8*)(Bbuf + (row << 6) + (slot << 3));
        }
      BAR();
      __builtin_amdgcn_s_setprio(1);
      #pragma unroll
      for (int mq = 0; mq < 4; ++mq)
        #pragma unroll
        for (int nq = 0; nq < 2; ++nq)
          #pragma unroll
          for (int ks = 0; ks < 2; ++ks)
            acc[(mh << 2) + mq][(nh << 1) + nq] =
                __builtin_amdgcn_mfma_f32_16x16x32_bf16(
                    a[mq][ks], b[nq][ks], acc[(mh << 2) + mq][(nh << 1) + nq], 0, 0, 0);
      __builtin_amdgcn_s_setprio(0);
      BAR();
    }
    if (t + 2 < nTiles) STG256(d, kbase + ((t + 2) << 6))
  }
#undef STG256

  float* C = Cout + (size_t)blockIdx.z * NTOK * DIM;
  #pragma unroll
  for (int m = 0; m < 8; ++m)
    #pragma unroll
    for (int n = 0; n < 4; ++n) {
      const int col = col0 + (wc << 6) + (n << 4) + fr;
      #pragma unroll
      for (int j = 0; j < 4; ++j) {
        const int row = row0 + (wr << 7) + (m << 4) + (fq << 2) + j;
        if (MODE == 2) C[(size_t)row * ldc + col] += acc[m][n][j];
        else           C[(size_t)row * ldc + col]  = acc[m][n][j];
      }
    }
}

// ---------------- denom reduce: denom[row] = sum of npart colblock partials ---
__global__ void denom_reduce(const float* __restrict__ dpart, float* __restrict__ denom,
                             int npart) {
  int row = blockIdx.x;
  int l = threadIdx.x;              // 64
  float s = 0.f;
  #pragma unroll
  for (int k = 0; k < 4; ++k) {
    int idx = l + (k << 6);
    if (idx < npart) s += dpart[(size_t)row * 256 + idx];
  }
  #pragma unroll
  for (int off = 32; off >= 1; off >>= 1) s += __shfl_down(s, off, 64);
  if (l == 0) denom[row] = s;
}

// ---------------- finalize ----------------
__global__ void finalize(const float* __restrict__ parts, const float* __restrict__ denom,
                         const float* __restrict__ ve, const int* __restrict__ batch,
                         float* __restrict__ out, int nks) {
  int row = blockIdx.x;
  int t = threadIdx.x;
  float inv = 0.5f / denom[row];
  float4 a = *(const float4*)(ve + (size_t)batch[row] * DIM + (t << 2));
  float sx = 0.f, sy = 0.f, sz = 0.f, sw = 0.f;
  for (int ks = 0; ks < nks; ++ks) {
    float4 pv = *(const float4*)(parts + ((size_t)ks * NTOK + row) * DIM + (t << 2));
    sx += pv.x; sy += pv.y; sz += pv.z; sw += pv.w;
  }
  float4 o;
  o.x = 0.5f * a.x + inv * sx;
  o.y = 0.5f * a.y + inv * sy;
  o.z = 0.5f * a.z + inv * sz;
  o.w = 0.5f * a.w + inv * sw;
  *(float4*)(out + (size_t)row * DIM + (t << 2)) = o;
}

// ---------------- launch ----------------
extern "C" void kernel_launch(void* const* d_in, const int* in_sizes, int n_in,
                              void* d_out, int out_size, void* d_ws, size_t ws_size,
                              hipStream_t stream) {
  const int*   batch = (const int*)d_in[0];
  const float* lang  = (const float*)d_in[1];
  const float* key   = (const float*)d_in[2];
  const float* ve    = (const float*)d_in[3];
  const float* W     = (const float*)d_in[4];
  float* out = (float*)d_out;

  const size_t szWt    = (size_t)DIM * DIM * 2;
  const size_t szQb    = (size_t)NTOK * DIM * 2;
  const size_t szQW    = (size_t)NTOK * DIM * 2;
  const size_t szDpart = (size_t)NTOK * 256 * 4;
  const size_t szDenom = (size_t)NTOK * 4;
  const size_t base    = szWt + szQb + szQW + szDpart + szDenom;

  char* ws = (char*)d_ws;
  u16*   Wt    = (u16*)(ws);
  u16*   qb    = (u16*)(ws + szWt);
  u16*   qW    = (u16*)(ws + szWt + szQb);
  float* dpart = (float*)(ws + szWt + szQb + szQW);
  float* denom = (float*)(ws + szWt + szQb + szQW + szDpart);

  const int KSF = 4;
  const size_t szPartsF = (size_t)KSF * NTOK * DIM * 4;
  const size_t szKeyb   = (size_t)VOCAB * DIM * 2;
  const size_t szVeT    = (size_t)VOCAB * DIM * 2;
  const size_t szP      = (size_t)NTOK * VOCAB * 2;
  const bool fullP = (base + szPartsF + szKeyb + szVeT + szP) <= ws_size;

  transpose_cvt<<<dim3(DIM / 64, DIM / 64), 256, 0, stream>>>(W, Wt, DIM, DIM);
  gather_q<<<NTOK, 256, 0, stream>>>(batch, lang, qb);
  gemm_qw<<<dim3(NTOK / 128, DIM / 128), 256, 0, stream>>>(qb, Wt, qW, DIM, DIM / 32, DIM);

  if (fullP) {
    float* parts = (float*)(ws + base);
    u16*   keyb  = (u16*)(ws + base + szPartsF);
    u16*   veT   = (u16*)(ws + base + szPartsF + szKeyb);
    u16*   P     = (u16*)(ws + base + szPartsF + szKeyb + szVeT);

    cvt_f32_bf16<<<VOCAB * DIM / 1024, 256, 0, stream>>>(key, keyb);
    transpose_cvt<<<dim3(VOCAB / 64, DIM / 64), 256, 0, stream>>>(ve, veT, DIM, VOCAB);
    // P = exp(qW @ keyb^T), fused row-sum partials (256² pipeline, 2000 WGs)
    gemm256e<<<dim3(NTOK / 256, VOCAB / 256), 512, 0, stream>>>(qW, keyb, P, dpart,
                                                                DIM, DIM / 64, VOCAB);
    denom_reduce<<<NTOK, 64, 0, stream>>>(dpart, denom, VOCAB / 256);
    // parts[z] = P @ veT^T (split-K over vocab, plain store)
    gemm256<3><<<dim3(NTOK / 256, DIM / 256, KSF), 512, 0, stream>>>(P, veT, parts,
                                                                     VOCAB, VOCAB / 64 / KSF, DIM);
    finalize<<<NTOK, 256, 0, stream>>>(parts, denom, ve, batch, out, KSF);
  } else {
    // chunked fallback
    const int KS = 2;
    const size_t szParts = (size_t)KS * NTOK * DIM * 4;
    int CHUNK = 1280;
    {
      const int copt[2] = {6400, 1280};
      for (int i = 0; i < 2; ++i) {
        size_t need = base + szParts + (size_t)copt[i] * (NTOK * 2 + DIM * 4);
        if (need <= ws_size) { CHUNK = copt[i]; break; }
      }
    }
    const int NCHUNK = VOCAB / CHUNK;
    float* parts = (float*)(ws + base);
    char*  dyn   = ws + base + szParts;
    u16*   keyc  = (u16*)(dyn);
    u16*   veTc  = (u16*)(dyn + (size_t)CHUNK * DIM * 2);
    u16*   Pc    = (u16*)(dyn + (size_t)CHUNK * DIM * 4);

    hipMemsetAsync(parts, 0, szParts, stream);
    for (int c = 0; c < NCHUNK; ++c) {
      const int v0 = c * CHUNK;
      cvt_f32_bf16<<<CHUNK * DIM / 1024, 256, 0, stream>>>(key + (size_t)v0 * DIM, keyc);
      transpose_cvt<<<dim3(CHUNK / 64, DIM / 64), 256, 0, stream>>>(ve + (size_t)v0 * DIM, veTc,
                                                                    DIM, CHUNK);
      gemm128e<<<dim3(NTOK / 128, CHUNK / 128), 256, 0, stream>>>(qW, keyc, Pc, dpart,
                                                                  DIM, DIM / 64, CHUNK, v0 >> 7);
      gemm256<2><<<dim3(NTOK / 256, DIM / 256, KS), 512, 0, stream>>>(Pc, veTc, parts,
                                                                      CHUNK, CHUNK / 64 / KS, DIM);
    }
    denom_reduce<<<NTOK, 64, 0, stream>>>(dpart, denom, 250);
    finalize<<<NTOK, 256, 0, stream>>>(parts, denom, ve, batch, out, KS);
  }
}

// Round 7
// 721.686 us; speedup vs baseline: 1.6280x; 1.0297x over previous
//
#include <hip/hip_runtime.h>

// out = 0.5*ve[batch] + 0.5 * softmax((lang[batch]@W) @ keyᵀ) @ ve
// (bias b cancels in softmax). bf16 MFMA 16x16x32, f32 accumulate.
// Full-P dataflow. 256² pipelined GEMMs: counted vmcnt, XOR-swizzled LDS,
// setprio, XCD swizzle, B-fragments cached in regs (4-window tile structure).

#define DIM   1024
#define VOCAB 32000
#define NTOK  4096

typedef unsigned short u16;
typedef __attribute__((ext_vector_type(8))) __bf16 bf16x8;
typedef __attribute__((ext_vector_type(4))) float  f32x4;
typedef __attribute__((ext_vector_type(8))) u16    u16x8;
typedef __attribute__((ext_vector_type(4))) u16    u16x4;

__device__ __forceinline__ u16 f2bf(float f) {  // round-to-nearest-even
  unsigned u = __float_as_uint(f);
  u += 0x7FFFu + ((u >> 16) & 1u);
  return (u16)(u >> 16);
}
__device__ __forceinline__ float bf2f(u16 s) {
  return __uint_as_float(((unsigned)s) << 16);
}

#define SB() __builtin_amdgcn_sched_barrier(0)
#define BAR() { SB(); __builtin_amdgcn_s_barrier(); SB(); }

// ---------------- conversion / gather ----------------

__global__ void cvt_f32_bf16(const float* __restrict__ in, u16* __restrict__ out) {
  size_t i = (size_t)blockIdx.x * 256 + threadIdx.x;
  float4 v = ((const float4*)in)[i];
  u16x4 o; o[0]=f2bf(v.x); o[1]=f2bf(v.y); o[2]=f2bf(v.z); o[3]=f2bf(v.w);
  ((u16x4*)out)[i] = o;
}

__global__ void gather_q(const int* __restrict__ batch, const float* __restrict__ lang,
                         u16* __restrict__ q) {
  int row = blockIdx.x;
  int src = batch[row];
  int t = threadIdx.x;
  float4 v = *(const float4*)(lang + (size_t)src * DIM + (t << 2));
  u16x4 o; o[0]=f2bf(v.x); o[1]=f2bf(v.y); o[2]=f2bf(v.z); o[3]=f2bf(v.w);
  *(u16x4*)(q + (size_t)row * DIM + (t << 2)) = o;
}

// out[c][r] = bf16(in[r][c]) ; 64x64 tiles via LDS. grid = (R/64, C/64)
__global__ void transpose_cvt(const float* __restrict__ in, u16* __restrict__ out,
                              int ldin, int ldout) {
  __shared__ u16 t[64][66];   // 66: bank-spread pad
  int r0 = blockIdx.x << 6;
  int c0 = blockIdx.y << 6;
  int tid = threadIdx.x;
  #pragma unroll
  for (int p = 0; p < 4; ++p) {
    int r = (p << 4) + (tid >> 4);
    int c = (tid & 15) << 2;
    float4 v = *(const float4*)(in + (size_t)(r0 + r) * ldin + c0 + c);
    t[c+0][r] = f2bf(v.x);
    t[c+1][r] = f2bf(v.y);
    t[c+2][r] = f2bf(v.z);
    t[c+3][r] = f2bf(v.w);
  }
  __syncthreads();
  #pragma unroll
  for (int qq = 0; qq < 2; ++qq) {
    int rr = tid >> 2;
    int cc = (((tid & 3) << 1) + qq) << 3;
    u16x8 w;
    #pragma unroll
    for (int j = 0; j < 8; ++j) w[j] = t[rr][cc + j];
    *(u16x8*)(out + (size_t)(c0 + rr) * ldout + r0 + cc) = w;
  }
}

// ---------------- small GEMM for qW: C[M,N]=A@B^T, 128x128 tile ----------------
__global__ void gemm_qw(const u16* __restrict__ A, const u16* __restrict__ B,
                        u16* __restrict__ C, int K, int kSteps, int ldc) {
  __shared__ u16 As[128 * 32];
  __shared__ u16 Bs[128 * 32];
  const int tid  = threadIdx.x;
  const int lane = tid & 63;
  const int wid  = tid >> 6;
  const int wr   = wid >> 1, wc = wid & 1;
  const int row0 = blockIdx.x << 7;
  const int col0 = blockIdx.y << 7;

  f32x4 acc[4][4];
  #pragma unroll
  for (int m = 0; m < 4; ++m)
    #pragma unroll
    for (int n = 0; n < 4; ++n) acc[m][n] = (f32x4){0.f,0.f,0.f,0.f};

  const int sr = lane >> 2;
  const int sc = (lane & 3) << 3;

  for (int ks = 0; ks < kSteps; ++ks) {
    const int kk = ks << 5;
    #pragma unroll
    for (int t = 0; t < 2; ++t) {
      const int i = wid * 2 + t;
      const u16* gA = A + (size_t)(row0 + (i << 4) + sr) * K + kk + sc;
      const u16* gB = B + (size_t)(col0 + (i << 4) + sr) * K + kk + sc;
      __builtin_amdgcn_global_load_lds((const __attribute__((address_space(1))) void*)gA,
                                       (__attribute__((address_space(3))) void*)(As + i * 512),
                                       16, 0, 0);
      __builtin_amdgcn_global_load_lds((const __attribute__((address_space(1))) void*)gB,
                                       (__attribute__((address_space(3))) void*)(Bs + i * 512),
                                       16, 0, 0);
    }
    __syncthreads();
    bf16x8 a[4], b[4];
    #pragma unroll
    for (int m = 0; m < 4; ++m)
      a[m] = *(const bf16x8*)(As + ((wr << 6) + (m << 4) + (lane & 15)) * 32 + ((lane >> 4) << 3));
    #pragma unroll
    for (int n = 0; n < 4; ++n)
      b[n] = *(const bf16x8*)(Bs + ((wc << 6) + (n << 4) + (lane & 15)) * 32 + ((lane >> 4) << 3));
    #pragma unroll
    for (int m = 0; m < 4; ++m)
      #pragma unroll
      for (int n = 0; n < 4; ++n)
        acc[m][n] = __builtin_amdgcn_mfma_f32_16x16x32_bf16(a[m], b[n], acc[m][n], 0, 0, 0);
    __syncthreads();
  }

  const int r0 = row0 + (wr << 6);
  const int c0 = col0 + (wc << 6);
  const int fq = (lane >> 4) << 2;
  const int fr = lane & 15;
  #pragma unroll
  for (int m = 0; m < 4; ++m)
    #pragma unroll
    for (int n = 0; n < 4; ++n) {
      int col = c0 + (n << 4) + fr;
      #pragma unroll
      for (int j = 0; j < 4; ++j) {
        int row = r0 + (m << 4) + fq + j;
        C[(size_t)row * ldc + col] = f2bf(acc[m][n][j]);
      }
    }
}

// ---------------- 128x128 pipelined exp-GEMM (chunked fallback only) ----------
__global__ __launch_bounds__(256, 2) void gemm128e(const u16* __restrict__ A,
                                                   const u16* __restrict__ B,
                                                   u16* __restrict__ P,
                                                   float* __restrict__ dpart,
                                                   int K, int nTiles, int ldc, int cb0) {
  __shared__ __align__(16) u16 lds[32768];
  const int tid  = threadIdx.x;
  const int lane = tid & 63;
  const int wid  = tid >> 6;
  const int wr   = wid >> 1;
  const int wc   = wid & 1;

  const int nwg = (int)(gridDim.x * gridDim.y);
  int lin = blockIdx.y * gridDim.x + blockIdx.x;
  { const int cpx = nwg >> 3; lin = (lin & 7) * cpx + (lin >> 3); }
  const int row0 = (lin & 31) << 7;
  const int cblk = lin >> 5;
  const int col0 = cblk << 7;

  const int fr = lane & 15;
  const int fq = lane >> 4;
  const int rb = tid >> 3;
  const int ss = tid & 7;

#define STG128(d, kk)                                                              \
  {                                                                                \
    _Pragma("unroll")                                                              \
    for (int c = 0; c < 4; ++c) {                                                  \
      const int ra = (c << 5) + rb;                                                \
      const u16* gA = A + (size_t)(row0 + ra) * K + (kk) + ((ss ^ (ra & 7)) << 3); \
      __builtin_amdgcn_global_load_lds(                                            \
          (const __attribute__((address_space(1))) void*)gA,                       \
          (__attribute__((address_space(3))) void*)(lds + (d) * 16384 + (((c << 5) + (wid << 3)) << 6)), \
          16, 0, 0);                                                               \
    }                                                                              \
    _Pragma("unroll")                                                              \
    for (int c = 0; c < 4; ++c) {                                                  \
      const int rn = (c << 5) + rb;                                                \
      const u16* gB = B + (size_t)(col0 + rn) * K + (kk) + ((ss ^ (rn & 7)) << 3); \
      __builtin_amdgcn_global_load_lds(                                            \
          (const __attribute__((address_space(1))) void*)gB,                       \
          (__attribute__((address_space(3))) void*)(lds + (d) * 16384 + 8192 + (((c << 5) + (wid << 3)) << 6)), \
          16, 0, 0);                                                               \
    }                                                                              \
  }

  f32x4 acc[4][4];
  #pragma unroll
  for (int m = 0; m < 4; ++m)
    #pragma unroll
    for (int n = 0; n < 4; ++n) acc[m][n] = (f32x4){0.f, 0.f, 0.f, 0.f};

  STG128(0, 0)
  STG128(1, 64)

  bf16x8 a[4], b[4];

  for (int t = 0; t < nTiles; ++t) {
    const int d = t & 1;
    const u16* Abuf = lds + d * 16384;
    const u16* Bbuf = Abuf + 8192;
    SB();
    if (t + 1 < nTiles) { asm volatile("s_waitcnt vmcnt(8)"); }
    else                { asm volatile("s_waitcnt vmcnt(0)"); }
    BAR();

    #pragma unroll
    for (int ks = 0; ks < 2; ++ks) {
      #pragma unroll
      for (int mq = 0; mq < 4; ++mq) {
        const int row  = (wr << 6) + (mq << 4) + fr;
        const int slot = ((ks << 2) + fq) ^ (row & 7);
        a[mq] = *(const bf16x8*)(Abuf + (row << 6) + (slot << 3));
      }
      #pragma unroll
      for (int nq = 0; nq < 4; ++nq) {
        const int row  = (wc << 6) + (nq << 4) + fr;
        const int slot = ((ks << 2) + fq) ^ (row & 7);
        b[nq] = *(const bf16x8*)(Bbuf + (row << 6) + (slot << 3));
      }
      BAR();
      __builtin_amdgcn_s_setprio(1);
      #pragma unroll
      for (int mq = 0; mq < 4; ++mq)
        #pragma unroll
        for (int nq = 0; nq < 4; ++nq)
          acc[mq][nq] = __builtin_amdgcn_mfma_f32_16x16x32_bf16(
              a[mq], b[nq], acc[mq][nq], 0, 0, 0);
      __builtin_amdgcn_s_setprio(0);
      BAR();
    }
    if (t + 2 < nTiles) STG128(d, (t + 2) << 6)
  }
#undef STG128

  float rs[16];
  #pragma unroll
  for (int i = 0; i < 16; ++i) rs[i] = 0.f;
  #pragma unroll
  for (int mq = 0; mq < 4; ++mq)
    #pragma unroll
    for (int nq = 0; nq < 4; ++nq) {
      const int col = col0 + (wc << 6) + (nq << 4) + fr;
      #pragma unroll
      for (int j = 0; j < 4; ++j) {
        const int row = row0 + (wr << 6) + (mq << 4) + (fq << 2) + j;
        float e = __expf(acc[mq][nq][j]);
        P[(size_t)row * ldc + col] = f2bf(e);
        rs[(mq << 2) + j] += e;
      }
    }
  #pragma unroll
  for (int i = 0; i < 16; ++i) {
    #pragma unroll
    for (int s = 8; s >= 1; s >>= 1) rs[i] += __shfl_xor(rs[i], s, 16);
  }
  __syncthreads();
  float* dsm = (float*)lds;
  if (fr == 0) {
    #pragma unroll
    for (int mq = 0; mq < 4; ++mq)
      #pragma unroll
      for (int j = 0; j < 4; ++j)
        dsm[(wc << 7) + (wr << 6) + (mq << 4) + (fq << 2) + j] = rs[(mq << 2) + j];
  }
  __syncthreads();
  if (tid < 128)
    dpart[(size_t)(row0 + tid) * 256 + cb0 + cblk] = dsm[tid] + dsm[128 + tid];
}

// ---------------- shared 256² K-loop body (4-window, B cached in regs) --------
#define STG256(d, kk)                                                              \
  {                                                                                \
    _Pragma("unroll")                                                              \
    for (int c = 0; c < 4; ++c) {                                                  \
      const int ra = (c << 6) + rb;                                                \
      const u16* gA = A + (size_t)(row0 + ra) * K + (kk) + ((ss ^ (ra & 7)) << 3); \
      __builtin_amdgcn_global_load_lds(                                            \
          (const __attribute__((address_space(1))) void*)gA,                       \
          (__attribute__((address_space(3))) void*)(lds + (d) * 32768 + (((c << 6) + (wid << 3)) << 6)), \
          16, 0, 0);                                                               \
    }                                                                              \
    _Pragma("unroll")                                                              \
    for (int c = 0; c < 4; ++c) {                                                  \
      const int rn = (c << 6) + rb;                                                \
      const u16* gB = B + (size_t)(col0 + rn) * K + (kk) + ((ss ^ (rn & 7)) << 3); \
      __builtin_amdgcn_global_load_lds(                                            \
          (const __attribute__((address_space(1))) void*)gB,                       \
          (__attribute__((address_space(3))) void*)(lds + (d) * 32768 + 16384 + (((c << 6) + (wid << 3)) << 6)), \
          16, 0, 0);                                                               \
    }                                                                              \
  }

#define KLOOP256(kbase)                                                            \
  STG256(0, (kbase))                                                               \
  STG256(1, (kbase) + 64)                                                          \
  for (int t = 0; t < nTiles; ++t) {                                               \
    const int d = t & 1;                                                           \
    const u16* Abuf = lds + d * 32768;                                             \
    const u16* Bbuf = Abuf + 16384;                                                \
    SB();                                                                          \
    if (t + 1 < nTiles) { asm volatile("s_waitcnt vmcnt(8)"); }                    \
    else                { asm volatile("s_waitcnt vmcnt(0)"); }                    \
    BAR();                                                                         \
    /* W1: A half 0 + ALL B fragments */                                           \
    _Pragma("unroll")                                                              \
    for (int mq = 0; mq < 4; ++mq)                                                 \
      _Pragma("unroll")                                                            \
      for (int ks = 0; ks < 2; ++ks) {                                             \
        const int row  = (wr << 7) + (mq << 4) + fr;                               \
        const int slot = ((ks << 2) + fq) ^ (row & 7);                             \
        a[mq][ks] = *(const bf16x8*)(Abuf + (row << 6) + (slot << 3));             \
      }                                                                            \
    _Pragma("unroll")                                                              \
    for (int nh = 0; nh < 2; ++nh)                                                 \
      _Pragma("unroll")                                                            \
      for (int nq = 0; nq < 2; ++nq)                                               \
        _Pragma("unroll")                                                          \
        for (int ks = 0; ks < 2; ++ks) {                                           \
          const int row  = (wc << 6) + (nh << 5) + (nq << 4) + fr;                 \
          const int slot = ((ks << 2) + fq) ^ (row & 7);                           \
          b[nh][nq][ks] = *(const bf16x8*)(Bbuf + (row << 6) + (slot << 3));       \
        }                                                                          \
    BAR();                                                                         \
    __builtin_amdgcn_s_setprio(1);                                                 \
    _Pragma("unroll")                                                              \
    for (int mq = 0; mq < 4; ++mq)                                                 \
      _Pragma("unroll")                                                            \
      for (int nh = 0; nh < 2; ++nh)                                               \
        _Pragma("unroll")                                                          \
        for (int nq = 0; nq < 2; ++nq)                                             \
          _Pragma("unroll")                                                        \
          for (int ks = 0; ks < 2; ++ks)                                           \
            acc[mq][(nh << 1) + nq] = __builtin_amdgcn_mfma_f32_16x16x32_bf16(     \
                a[mq][ks], b[nh][nq][ks], acc[mq][(nh << 1) + nq], 0, 0, 0);       \
    __builtin_amdgcn_s_setprio(0);                                                 \
    BAR();                                                                         \
    /* W3: A half 1 */                                                             \
    _Pragma("unroll")                                                              \
    for (int mq = 0; mq < 4; ++mq)                                                 \
      _Pragma("unroll")                                                            \
      for (int ks = 0; ks < 2; ++ks) {                                             \
        const int row  = (wr << 7) + 64 + (mq << 4) + fr;                          \
        const int slot = ((ks << 2) + fq) ^ (row & 7);                             \
        a[mq][ks] = *(const bf16x8*)(Abuf + (row << 6) + (slot << 3));             \
      }                                                                            \
    BAR();                                                                         \
    __builtin_amdgcn_s_setprio(1);                                                 \
    _Pragma("unroll")                                                              \
    for (int mq = 0; mq < 4; ++mq)                                                 \
      _Pragma("unroll")                                                            \
      for (int nh = 0; nh < 2; ++nh)                                               \
        _Pragma("unroll")                                                          \
        for (int nq = 0; nq < 2; ++nq)                                             \
          _Pragma("unroll")                                                        \
          for (int ks = 0; ks < 2; ++ks)                                           \
            acc[4 + mq][(nh << 1) + nq] = __builtin_amdgcn_mfma_f32_16x16x32_bf16( \
                a[mq][ks], b[nh][nq][ks], acc[4 + mq][(nh << 1) + nq], 0, 0, 0);   \
    __builtin_amdgcn_s_setprio(0);                                                 \
    BAR();                                                                         \
    if (t + 2 < nTiles) STG256(d, (kbase) + ((t + 2) << 6))                        \
  }

// ---------------- 256x256 pipelined exp-GEMM: P = exp(A@B^T), fused rowsum ----
__global__ __launch_bounds__(512, 2) void gemm256e(const u16* __restrict__ A,
                                                   const u16* __restrict__ B,
                                                   u16* __restrict__ P,
                                                   float* __restrict__ dpart,
                                                   int K, int nTiles, int ldc) {
  __shared__ __align__(16) u16 lds[65536];
  const int tid  = threadIdx.x;
  const int lane = tid & 63;
  const int wid  = tid >> 6;
  const int wr   = wid >> 2;
  const int wc   = wid & 3;

  const int nwg = (int)(gridDim.x * gridDim.y);
  int lin = blockIdx.y * gridDim.x + blockIdx.x;
  { const int cpx = nwg >> 3; lin = (lin & 7) * cpx + (lin >> 3); }
  const int row0 = (lin & 15) << 8;    // gridDim.x == 16
  const int cblk = lin >> 4;
  const int col0 = cblk << 8;

  const int fr = lane & 15;
  const int fq = lane >> 4;
  const int rb = tid >> 3;
  const int ss = tid & 7;

  f32x4 acc[8][4];
  #pragma unroll
  for (int m = 0; m < 8; ++m)
    #pragma unroll
    for (int n = 0; n < 4; ++n) acc[m][n] = (f32x4){0.f, 0.f, 0.f, 0.f};

  bf16x8 a[4][2], b[2][2][2];

  KLOOP256(0)

  // epilogue: P = bf16(exp(acc)); fused per-(row,colblock) row-sum partials
  float rs[32];
  #pragma unroll
  for (int i = 0; i < 32; ++i) rs[i] = 0.f;
  #pragma unroll
  for (int m = 0; m < 8; ++m)
    #pragma unroll
    for (int n = 0; n < 4; ++n) {
      const int col = col0 + (wc << 6) + (n << 4) + fr;
      #pragma unroll
      for (int j = 0; j < 4; ++j) {
        const int row = row0 + (wr << 7) + (m << 4) + (fq << 2) + j;
        float e = __expf(acc[m][n][j]);
        P[(size_t)row * ldc + col] = f2bf(e);
        rs[(m << 2) + j] += e;
      }
    }
  #pragma unroll
  for (int i = 0; i < 32; ++i) {
    #pragma unroll
    for (int s = 8; s >= 1; s >>= 1) rs[i] += __shfl_xor(rs[i], s, 16);
  }
  __syncthreads();
  float* dsm = (float*)lds;           // [wc][256] = 4 KiB
  if (fr == 0) {
    #pragma unroll
    for (int m = 0; m < 8; ++m)
      #pragma unroll
      for (int j = 0; j < 4; ++j)
        dsm[(wc << 8) + (wr << 7) + (m << 4) + (fq << 2) + j] = rs[(m << 2) + j];
  }
  __syncthreads();
  if (tid < 256)
    dpart[(size_t)(row0 + tid) * 256 + cblk] =
        dsm[tid] + dsm[256 + tid] + dsm[512 + tid] + dsm[768 + tid];
}

// ---------------- 256x256 pipelined GEMM: C[M,N] = A[M,K] @ B[N,K]^T ----------
// MODE 2: C(f32, slice z) += acc (chunked fallback);  MODE 3: plain store.
template<int MODE>
__global__ __launch_bounds__(512, 2) void gemm256(const u16* __restrict__ A,
                                                  const u16* __restrict__ B,
                                                  float* __restrict__ Cout,
                                                  int K, int nTiles, int ldc) {
  __shared__ __align__(16) u16 lds[65536];
  const int tid  = threadIdx.x;
  const int lane = tid & 63;
  const int wid  = tid >> 6;
  const int wr   = wid >> 2;
  const int wc   = wid & 3;

  const int nwg = (int)(gridDim.x * gridDim.y);
  int lin = blockIdx.y * gridDim.x + blockIdx.x;
  { const int cpx = nwg >> 3; lin = (lin & 7) * cpx + (lin >> 3); }
  const int row0 = (lin & 15) << 8;    // gridDim.x == 16
  const int col0 = (lin >> 4) << 8;

  const int kbase = blockIdx.z * (nTiles << 6);
  const int fr = lane & 15;
  const int fq = lane >> 4;
  const int rb = tid >> 3;
  const int ss = tid & 7;

  f32x4 acc[8][4];
  #pragma unroll
  for (int m = 0; m < 8; ++m)
    #pragma unroll
    for (int n = 0; n < 4; ++n) acc[m][n] = (f32x4){0.f, 0.f, 0.f, 0.f};

  bf16x8 a[4][2], b[2][2][2];

  KLOOP256(kbase)

  float* C = Cout + (size_t)blockIdx.z * NTOK * DIM;
  #pragma unroll
  for (int m = 0; m < 8; ++m)
    #pragma unroll
    for (int n = 0; n < 4; ++n) {
      const int col = col0 + (wc << 6) + (n << 4) + fr;
      #pragma unroll
      for (int j = 0; j < 4; ++j) {
        const int row = row0 + (wr << 7) + (m << 4) + (fq << 2) + j;
        if (MODE == 2) C[(size_t)row * ldc + col] += acc[m][n][j];
        else           C[(size_t)row * ldc + col]  = acc[m][n][j];
      }
    }
}

// ---------------- denom reduce ----------------
__global__ void denom_reduce(const float* __restrict__ dpart, float* __restrict__ denom,
                             int npart) {
  int row = blockIdx.x;
  int l = threadIdx.x;              // 64
  float s = 0.f;
  #pragma unroll
  for (int k = 0; k < 4; ++k) {
    int idx = l + (k << 6);
    if (idx < npart) s += dpart[(size_t)row * 256 + idx];
  }
  #pragma unroll
  for (int off = 32; off >= 1; off >>= 1) s += __shfl_down(s, off, 64);
  if (l == 0) denom[row] = s;
}

// ---------------- finalize ----------------
__global__ void finalize(const float* __restrict__ parts, const float* __restrict__ denom,
                         const float* __restrict__ ve, const int* __restrict__ batch,
                         float* __restrict__ out, int nks) {
  int row = blockIdx.x;
  int t = threadIdx.x;
  float inv = 0.5f / denom[row];
  float4 a = *(const float4*)(ve + (size_t)batch[row] * DIM + (t << 2));
  float sx = 0.f, sy = 0.f, sz = 0.f, sw = 0.f;
  for (int ks = 0; ks < nks; ++ks) {
    float4 pv = *(const float4*)(parts + ((size_t)ks * NTOK + row) * DIM + (t << 2));
    sx += pv.x; sy += pv.y; sz += pv.z; sw += pv.w;
  }
  float4 o;
  o.x = 0.5f * a.x + inv * sx;
  o.y = 0.5f * a.y + inv * sy;
  o.z = 0.5f * a.z + inv * sz;
  o.w = 0.5f * a.w + inv * sw;
  *(float4*)(out + (size_t)row * DIM + (t << 2)) = o;
}

// ---------------- launch ----------------
extern "C" void kernel_launch(void* const* d_in, const int* in_sizes, int n_in,
                              void* d_out, int out_size, void* d_ws, size_t ws_size,
                              hipStream_t stream) {
  const int*   batch = (const int*)d_in[0];
  const float* lang  = (const float*)d_in[1];
  const float* key   = (const float*)d_in[2];
  const float* ve    = (const float*)d_in[3];
  const float* W     = (const float*)d_in[4];
  float* out = (float*)d_out;

  const size_t szWt    = (size_t)DIM * DIM * 2;
  const size_t szQb    = (size_t)NTOK * DIM * 2;
  const size_t szQW    = (size_t)NTOK * DIM * 2;
  const size_t szDpart = (size_t)NTOK * 256 * 4;
  const size_t szDenom = (size_t)NTOK * 4;
  const size_t base    = szWt + szQb + szQW + szDpart + szDenom;

  char* ws = (char*)d_ws;
  u16*   Wt    = (u16*)(ws);
  u16*   qb    = (u16*)(ws + szWt);
  u16*   qW    = (u16*)(ws + szWt + szQb);
  float* dpart = (float*)(ws + szWt + szQb + szQW);
  float* denom = (float*)(ws + szWt + szQb + szQW + szDpart);

  const int KSF = 4;
  const size_t szPartsF = (size_t)KSF * NTOK * DIM * 4;
  const size_t szKeyb   = (size_t)VOCAB * DIM * 2;
  const size_t szVeT    = (size_t)VOCAB * DIM * 2;
  const size_t szP      = (size_t)NTOK * VOCAB * 2;
  const bool fullP = (base + szPartsF + szKeyb + szVeT + szP) <= ws_size;

  transpose_cvt<<<dim3(DIM / 64, DIM / 64), 256, 0, stream>>>(W, Wt, DIM, DIM);
  gather_q<<<NTOK, 256, 0, stream>>>(batch, lang, qb);
  gemm_qw<<<dim3(NTOK / 128, DIM / 128), 256, 0, stream>>>(qb, Wt, qW, DIM, DIM / 32, DIM);

  if (fullP) {
    float* parts = (float*)(ws + base);
    u16*   keyb  = (u16*)(ws + base + szPartsF);
    u16*   veT   = (u16*)(ws + base + szPartsF + szKeyb);
    u16*   P     = (u16*)(ws + base + szPartsF + szKeyb + szVeT);

    cvt_f32_bf16<<<VOCAB * DIM / 1024, 256, 0, stream>>>(key, keyb);
    transpose_cvt<<<dim3(VOCAB / 64, DIM / 64), 256, 0, stream>>>(ve, veT, DIM, VOCAB);
    gemm256e<<<dim3(NTOK / 256, VOCAB / 256), 512, 0, stream>>>(qW, keyb, P, dpart,
                                                                DIM, DIM / 64, VOCAB);
    denom_reduce<<<NTOK, 64, 0, stream>>>(dpart, denom, VOCAB / 256);
    gemm256<3><<<dim3(NTOK / 256, DIM / 256, KSF), 512, 0, stream>>>(P, veT, parts,
                                                                     VOCAB, VOCAB / 64 / KSF, DIM);
    finalize<<<NTOK, 256, 0, stream>>>(parts, denom, ve, batch, out, KSF);
  } else {
    // chunked fallback
    const int KS = 2;
    const size_t szParts = (size_t)KS * NTOK * DIM * 4;
    int CHUNK = 1280;
    {
      const int copt[2] = {6400, 1280};
      for (int i = 0; i < 2; ++i) {
        size_t need = base + szParts + (size_t)copt[i] * (NTOK * 2 + DIM * 4);
        if (need <= ws_size) { CHUNK = copt[i]; break; }
      }
    }
    const int NCHUNK = VOCAB / CHUNK;
    float* parts = (float*)(ws + base);
    char*  dyn   = ws + base + szParts;
    u16*   keyc  = (u16*)(dyn);
    u16*   veTc  = (u16*)(dyn + (size_t)CHUNK * DIM * 2);
    u16*   Pc    = (u16*)(dyn + (size_t)CHUNK * DIM * 4);

    hipMemsetAsync(parts, 0, szParts, stream);
    for (int c = 0; c < NCHUNK; ++c) {
      const int v0 = c * CHUNK;
      cvt_f32_bf16<<<CHUNK * DIM / 1024, 256, 0, stream>>>(key + (size_t)v0 * DIM, keyc);
      transpose_cvt<<<dim3(CHUNK / 64, DIM / 64), 256, 0, stream>>>(ve + (size_t)v0 * DIM, veTc,
                                                                    DIM, CHUNK);
      gemm128e<<<dim3(NTOK / 128, CHUNK / 128), 256, 0, stream>>>(qW, keyc, Pc, dpart,
                                                                  DIM, DIM / 64, CHUNK, v0 >> 7);
      gemm256<2><<<dim3(NTOK / 256, DIM / 256, KS), 512, 0, stream>>>(Pc, veTc, parts,
                                                                      CHUNK, CHUNK / 64 / KS, DIM);
    }
    denom_reduce<<<NTOK, 64, 0, stream>>>(dpart, denom, 250);
    finalize<<<NTOK, 256, 0, stream>>>(parts, denom, ve, batch, out, KS);
  }
}

// Round 8
// 697.923 us; speedup vs baseline: 1.6834x; 1.0340x over previous
//
#include <hip/hip_runtime.h>

// out = 0.5*ve[batch] + 0.5 * softmax((lang[batch]@W) @ keyᵀ) @ ve
// (bias b cancels in softmax). bf16 MFMA 16x16x32, f32 accumulate.
// Full-P dataflow. 256² pipelined GEMMs: counted vmcnt, XOR-swizzled LDS,
// XCD swizzle, barrier-free inner tile (2 barriers/K-tile; waves skew so
// LDS-read and MFMA pipes overlap across waves).

#define DIM   1024
#define VOCAB 32000
#define NTOK  4096

typedef unsigned short u16;
typedef __attribute__((ext_vector_type(8))) __bf16 bf16x8;
typedef __attribute__((ext_vector_type(4))) float  f32x4;
typedef __attribute__((ext_vector_type(8))) u16    u16x8;
typedef __attribute__((ext_vector_type(4))) u16    u16x4;

__device__ __forceinline__ u16 f2bf(float f) {  // round-to-nearest-even
  unsigned u = __float_as_uint(f);
  u += 0x7FFFu + ((u >> 16) & 1u);
  return (u16)(u >> 16);
}
__device__ __forceinline__ float bf2f(u16 s) {
  return __uint_as_float(((unsigned)s) << 16);
}

#define SB() __builtin_amdgcn_sched_barrier(0)
#define BAR() { SB(); __builtin_amdgcn_s_barrier(); SB(); }

// ---------------- conversion / gather ----------------

__global__ void cvt_f32_bf16(const float* __restrict__ in, u16* __restrict__ out) {
  size_t i = (size_t)blockIdx.x * 256 + threadIdx.x;
  float4 v = ((const float4*)in)[i];
  u16x4 o; o[0]=f2bf(v.x); o[1]=f2bf(v.y); o[2]=f2bf(v.z); o[3]=f2bf(v.w);
  ((u16x4*)out)[i] = o;
}

__global__ void gather_q(const int* __restrict__ batch, const float* __restrict__ lang,
                         u16* __restrict__ q) {
  int row = blockIdx.x;
  int src = batch[row];
  int t = threadIdx.x;
  float4 v = *(const float4*)(lang + (size_t)src * DIM + (t << 2));
  u16x4 o; o[0]=f2bf(v.x); o[1]=f2bf(v.y); o[2]=f2bf(v.z); o[3]=f2bf(v.w);
  *(u16x4*)(q + (size_t)row * DIM + (t << 2)) = o;
}

// out[c][r] = bf16(in[r][c]) ; 64x64 tiles via LDS. grid = (R/64, C/64)
__global__ void transpose_cvt(const float* __restrict__ in, u16* __restrict__ out,
                              int ldin, int ldout) {
  __shared__ u16 t[64][66];   // 66: bank-spread pad
  int r0 = blockIdx.x << 6;
  int c0 = blockIdx.y << 6;
  int tid = threadIdx.x;
  #pragma unroll
  for (int p = 0; p < 4; ++p) {
    int r = (p << 4) + (tid >> 4);
    int c = (tid & 15) << 2;
    float4 v = *(const float4*)(in + (size_t)(r0 + r) * ldin + c0 + c);
    t[c+0][r] = f2bf(v.x);
    t[c+1][r] = f2bf(v.y);
    t[c+2][r] = f2bf(v.z);
    t[c+3][r] = f2bf(v.w);
  }
  __syncthreads();
  #pragma unroll
  for (int qq = 0; qq < 2; ++qq) {
    int rr = tid >> 2;
    int cc = (((tid & 3) << 1) + qq) << 3;
    u16x8 w;
    #pragma unroll
    for (int j = 0; j < 8; ++j) w[j] = t[rr][cc + j];
    *(u16x8*)(out + (size_t)(c0 + rr) * ldout + r0 + cc) = w;
  }
}

// ---------------- small GEMM for qW: C[M,N]=A@B^T, 128x128 tile ----------------
__global__ void gemm_qw(const u16* __restrict__ A, const u16* __restrict__ B,
                        u16* __restrict__ C, int K, int kSteps, int ldc) {
  __shared__ u16 As[128 * 32];
  __shared__ u16 Bs[128 * 32];
  const int tid  = threadIdx.x;
  const int lane = tid & 63;
  const int wid  = tid >> 6;
  const int wr   = wid >> 1, wc = wid & 1;
  const int row0 = blockIdx.x << 7;
  const int col0 = blockIdx.y << 7;

  f32x4 acc[4][4];
  #pragma unroll
  for (int m = 0; m < 4; ++m)
    #pragma unroll
    for (int n = 0; n < 4; ++n) acc[m][n] = (f32x4){0.f,0.f,0.f,0.f};

  const int sr = lane >> 2;
  const int sc = (lane & 3) << 3;

  for (int ks = 0; ks < kSteps; ++ks) {
    const int kk = ks << 5;
    #pragma unroll
    for (int t = 0; t < 2; ++t) {
      const int i = wid * 2 + t;
      const u16* gA = A + (size_t)(row0 + (i << 4) + sr) * K + kk + sc;
      const u16* gB = B + (size_t)(col0 + (i << 4) + sr) * K + kk + sc;
      __builtin_amdgcn_global_load_lds((const __attribute__((address_space(1))) void*)gA,
                                       (__attribute__((address_space(3))) void*)(As + i * 512),
                                       16, 0, 0);
      __builtin_amdgcn_global_load_lds((const __attribute__((address_space(1))) void*)gB,
                                       (__attribute__((address_space(3))) void*)(Bs + i * 512),
                                       16, 0, 0);
    }
    __syncthreads();
    bf16x8 a[4], b[4];
    #pragma unroll
    for (int m = 0; m < 4; ++m)
      a[m] = *(const bf16x8*)(As + ((wr << 6) + (m << 4) + (lane & 15)) * 32 + ((lane >> 4) << 3));
    #pragma unroll
    for (int n = 0; n < 4; ++n)
      b[n] = *(const bf16x8*)(Bs + ((wc << 6) + (n << 4) + (lane & 15)) * 32 + ((lane >> 4) << 3));
    #pragma unroll
    for (int m = 0; m < 4; ++m)
      #pragma unroll
      for (int n = 0; n < 4; ++n)
        acc[m][n] = __builtin_amdgcn_mfma_f32_16x16x32_bf16(a[m], b[n], acc[m][n], 0, 0, 0);
    __syncthreads();
  }

  const int r0 = row0 + (wr << 6);
  const int c0 = col0 + (wc << 6);
  const int fq = (lane >> 4) << 2;
  const int fr = lane & 15;
  #pragma unroll
  for (int m = 0; m < 4; ++m)
    #pragma unroll
    for (int n = 0; n < 4; ++n) {
      int col = c0 + (n << 4) + fr;
      #pragma unroll
      for (int j = 0; j < 4; ++j) {
        int row = r0 + (m << 4) + fq + j;
        C[(size_t)row * ldc + col] = f2bf(acc[m][n][j]);
      }
    }
}

// ---------------- 128x128 pipelined exp-GEMM (chunked fallback only) ----------
__global__ __launch_bounds__(256, 2) void gemm128e(const u16* __restrict__ A,
                                                   const u16* __restrict__ B,
                                                   u16* __restrict__ P,
                                                   float* __restrict__ dpart,
                                                   int K, int nTiles, int ldc, int cb0) {
  __shared__ __align__(16) u16 lds[32768];
  const int tid  = threadIdx.x;
  const int lane = tid & 63;
  const int wid  = tid >> 6;
  const int wr   = wid >> 1;
  const int wc   = wid & 1;

  const int nwg = (int)(gridDim.x * gridDim.y);
  int lin = blockIdx.y * gridDim.x + blockIdx.x;
  { const int cpx = nwg >> 3; lin = (lin & 7) * cpx + (lin >> 3); }
  const int row0 = (lin & 31) << 7;
  const int cblk = lin >> 5;
  const int col0 = cblk << 7;

  const int fr = lane & 15;
  const int fq = lane >> 4;
  const int rb = tid >> 3;
  const int ss = tid & 7;

#define STG128(d, kk)                                                              \
  {                                                                                \
    _Pragma("unroll")                                                              \
    for (int c = 0; c < 4; ++c) {                                                  \
      const int ra = (c << 5) + rb;                                                \
      const u16* gA = A + (size_t)(row0 + ra) * K + (kk) + ((ss ^ (ra & 7)) << 3); \
      __builtin_amdgcn_global_load_lds(                                            \
          (const __attribute__((address_space(1))) void*)gA,                       \
          (__attribute__((address_space(3))) void*)(lds + (d) * 16384 + (((c << 5) + (wid << 3)) << 6)), \
          16, 0, 0);                                                               \
    }                                                                              \
    _Pragma("unroll")                                                              \
    for (int c = 0; c < 4; ++c) {                                                  \
      const int rn = (c << 5) + rb;                                                \
      const u16* gB = B + (size_t)(col0 + rn) * K + (kk) + ((ss ^ (rn & 7)) << 3); \
      __builtin_amdgcn_global_load_lds(                                            \
          (const __attribute__((address_space(1))) void*)gB,                       \
          (__attribute__((address_space(3))) void*)(lds + (d) * 16384 + 8192 + (((c << 5) + (wid << 3)) << 6)), \
          16, 0, 0);                                                               \
    }                                                                              \
  }

  f32x4 acc[4][4];
  #pragma unroll
  for (int m = 0; m < 4; ++m)
    #pragma unroll
    for (int n = 0; n < 4; ++n) acc[m][n] = (f32x4){0.f, 0.f, 0.f, 0.f};

  STG128(0, 0)
  STG128(1, 64)

  bf16x8 a[4], b[4];

  for (int t = 0; t < nTiles; ++t) {
    const int d = t & 1;
    const u16* Abuf = lds + d * 16384;
    const u16* Bbuf = Abuf + 8192;
    SB();
    if (t + 1 < nTiles) { asm volatile("s_waitcnt vmcnt(8)"); }
    else                { asm volatile("s_waitcnt vmcnt(0)"); }
    BAR();

    #pragma unroll
    for (int ks = 0; ks < 2; ++ks) {
      #pragma unroll
      for (int mq = 0; mq < 4; ++mq) {
        const int row  = (wr << 6) + (mq << 4) + fr;
        const int slot = ((ks << 2) + fq) ^ (row & 7);
        a[mq] = *(const bf16x8*)(Abuf + (row << 6) + (slot << 3));
      }
      #pragma unroll
      for (int nq = 0; nq < 4; ++nq) {
        const int row  = (wc << 6) + (nq << 4) + fr;
        const int slot = ((ks << 2) + fq) ^ (row & 7);
        b[nq] = *(const bf16x8*)(Bbuf + (row << 6) + (slot << 3));
      }
      __builtin_amdgcn_s_setprio(1);
      #pragma unroll
      for (int mq = 0; mq < 4; ++mq)
        #pragma unroll
        for (int nq = 0; nq < 4; ++nq)
          acc[mq][nq] = __builtin_amdgcn_mfma_f32_16x16x32_bf16(
              a[mq], b[nq], acc[mq][nq], 0, 0, 0);
      __builtin_amdgcn_s_setprio(0);
    }
    BAR();
    if (t + 2 < nTiles) STG128(d, (t + 2) << 6)
  }
#undef STG128

  float rs[16];
  #pragma unroll
  for (int i = 0; i < 16; ++i) rs[i] = 0.f;
  #pragma unroll
  for (int mq = 0; mq < 4; ++mq)
    #pragma unroll
    for (int nq = 0; nq < 4; ++nq) {
      const int col = col0 + (wc << 6) + (nq << 4) + fr;
      #pragma unroll
      for (int j = 0; j < 4; ++j) {
        const int row = row0 + (wr << 6) + (mq << 4) + (fq << 2) + j;
        float e = __expf(acc[mq][nq][j]);
        P[(size_t)row * ldc + col] = f2bf(e);
        rs[(mq << 2) + j] += e;
      }
    }
  #pragma unroll
  for (int i = 0; i < 16; ++i) {
    #pragma unroll
    for (int s = 8; s >= 1; s >>= 1) rs[i] += __shfl_xor(rs[i], s, 16);
  }
  __syncthreads();
  float* dsm = (float*)lds;
  if (fr == 0) {
    #pragma unroll
    for (int mq = 0; mq < 4; ++mq)
      #pragma unroll
      for (int j = 0; j < 4; ++j)
        dsm[(wc << 7) + (wr << 6) + (mq << 4) + (fq << 2) + j] = rs[(mq << 2) + j];
  }
  __syncthreads();
  if (tid < 128)
    dpart[(size_t)(row0 + tid) * 256 + cb0 + cblk] = dsm[tid] + dsm[128 + tid];
}

// ---------------- shared 256² K-loop body (barrier-free inner tile) -----------
#define STG256(d, kk)                                                              \
  {                                                                                \
    _Pragma("unroll")                                                              \
    for (int c = 0; c < 4; ++c) {                                                  \
      const int ra = (c << 6) + rb;                                                \
      const u16* gA = A + (size_t)(row0 + ra) * K + (kk) + ((ss ^ (ra & 7)) << 3); \
      __builtin_amdgcn_global_load_lds(                                            \
          (const __attribute__((address_space(1))) void*)gA,                       \
          (__attribute__((address_space(3))) void*)(lds + (d) * 32768 + (((c << 6) + (wid << 3)) << 6)), \
          16, 0, 0);                                                               \
    }                                                                              \
    _Pragma("unroll")                                                              \
    for (int c = 0; c < 4; ++c) {                                                  \
      const int rn = (c << 6) + rb;                                                \
      const u16* gB = B + (size_t)(col0 + rn) * K + (kk) + ((ss ^ (rn & 7)) << 3); \
      __builtin_amdgcn_global_load_lds(                                            \
          (const __attribute__((address_space(1))) void*)gB,                       \
          (__attribute__((address_space(3))) void*)(lds + (d) * 32768 + 16384 + (((c << 6) + (wid << 3)) << 6)), \
          16, 0, 0);                                                               \
    }                                                                              \
  }

// per K-tile: {own-vmcnt + barrier} -> reads+MFMA (no barriers, compiler
// schedules; waves skew so LDS and MFMA pipes overlap) -> {barrier} -> restage.
#define KLOOP256(kbase)                                                            \
  STG256(0, (kbase))                                                               \
  STG256(1, (kbase) + 64)                                                          \
  for (int t = 0; t < nTiles; ++t) {                                               \
    const int d = t & 1;                                                           \
    const u16* Abuf = lds + d * 32768;                                             \
    const u16* Bbuf = Abuf + 16384;                                                \
    SB();                                                                          \
    if (t + 1 < nTiles) { asm volatile("s_waitcnt vmcnt(8)"); }                    \
    else                { asm volatile("s_waitcnt vmcnt(0)"); }                    \
    BAR();                                                                         \
    _Pragma("unroll")                                                              \
    for (int nh = 0; nh < 2; ++nh)                                                 \
      _Pragma("unroll")                                                            \
      for (int nq = 0; nq < 2; ++nq)                                               \
        _Pragma("unroll")                                                          \
        for (int ks = 0; ks < 2; ++ks) {                                           \
          const int row  = (wc << 6) + (nh << 5) + (nq << 4) + fr;                 \
          const int slot = ((ks << 2) + fq) ^ (row & 7);                           \
          b[nh][nq][ks] = *(const bf16x8*)(Bbuf + (row << 6) + (slot << 3));       \
        }                                                                          \
    _Pragma("unroll")                                                              \
    for (int mh = 0; mh < 2; ++mh) {                                               \
      _Pragma("unroll")                                                            \
      for (int mq = 0; mq < 4; ++mq)                                               \
        _Pragma("unroll")                                                          \
        for (int ks = 0; ks < 2; ++ks) {                                           \
          const int row  = (wr << 7) + (mh << 6) + (mq << 4) + fr;                 \
          const int slot = ((ks << 2) + fq) ^ (row & 7);                           \
          a[mq][ks] = *(const bf16x8*)(Abuf + (row << 6) + (slot << 3));           \
        }                                                                          \
      __builtin_amdgcn_s_setprio(1);                                               \
      _Pragma("unroll")                                                            \
      for (int mq = 0; mq < 4; ++mq)                                               \
        _Pragma("unroll")                                                          \
        for (int nh = 0; nh < 2; ++nh)                                             \
          _Pragma("unroll")                                                        \
          for (int nq = 0; nq < 2; ++nq)                                           \
            _Pragma("unroll")                                                      \
            for (int ks = 0; ks < 2; ++ks)                                         \
              acc[(mh << 2) + mq][(nh << 1) + nq] =                                \
                  __builtin_amdgcn_mfma_f32_16x16x32_bf16(                         \
                      a[mq][ks], b[nh][nq][ks], acc[(mh << 2) + mq][(nh << 1) + nq], 0, 0, 0); \
      __builtin_amdgcn_s_setprio(0);                                               \
    }                                                                              \
    BAR();                                                                         \
    if (t + 2 < nTiles) STG256(d, (kbase) + ((t + 2) << 6))                        \
  }

// ---------------- 256x256 pipelined exp-GEMM: P = exp(A@B^T), fused rowsum ----
__global__ __launch_bounds__(512, 2) void gemm256e(const u16* __restrict__ A,
                                                   const u16* __restrict__ B,
                                                   u16* __restrict__ P,
                                                   float* __restrict__ dpart,
                                                   int K, int nTiles, int ldc) {
  __shared__ __align__(16) u16 lds[65536];
  const int tid  = threadIdx.x;
  const int lane = tid & 63;
  const int wid  = tid >> 6;
  const int wr   = wid >> 2;
  const int wc   = wid & 3;

  const int nwg = (int)(gridDim.x * gridDim.y);
  int lin = blockIdx.y * gridDim.x + blockIdx.x;
  { const int cpx = nwg >> 3; lin = (lin & 7) * cpx + (lin >> 3); }
  const int row0 = (lin & 15) << 8;    // gridDim.x == 16
  const int cblk = lin >> 4;
  const int col0 = cblk << 8;

  const int fr = lane & 15;
  const int fq = lane >> 4;
  const int rb = tid >> 3;
  const int ss = tid & 7;

  f32x4 acc[8][4];
  #pragma unroll
  for (int m = 0; m < 8; ++m)
    #pragma unroll
    for (int n = 0; n < 4; ++n) acc[m][n] = (f32x4){0.f, 0.f, 0.f, 0.f};

  bf16x8 a[4][2], b[2][2][2];

  KLOOP256(0)

  // epilogue: P = bf16(exp(acc)); fused per-(row,colblock) row-sum partials
  float rs[32];
  #pragma unroll
  for (int i = 0; i < 32; ++i) rs[i] = 0.f;
  #pragma unroll
  for (int m = 0; m < 8; ++m)
    #pragma unroll
    for (int n = 0; n < 4; ++n) {
      const int col = col0 + (wc << 6) + (n << 4) + fr;
      #pragma unroll
      for (int j = 0; j < 4; ++j) {
        const int row = row0 + (wr << 7) + (m << 4) + (fq << 2) + j;
        float e = __expf(acc[m][n][j]);
        P[(size_t)row * ldc + col] = f2bf(e);
        rs[(m << 2) + j] += e;
      }
    }
  #pragma unroll
  for (int i = 0; i < 32; ++i) {
    #pragma unroll
    for (int s = 8; s >= 1; s >>= 1) rs[i] += __shfl_xor(rs[i], s, 16);
  }
  __syncthreads();
  float* dsm = (float*)lds;           // [wc][256] = 4 KiB
  if (fr == 0) {
    #pragma unroll
    for (int m = 0; m < 8; ++m)
      #pragma unroll
      for (int j = 0; j < 4; ++j)
        dsm[(wc << 8) + (wr << 7) + (m << 4) + (fq << 2) + j] = rs[(m << 2) + j];
  }
  __syncthreads();
  if (tid < 256)
    dpart[(size_t)(row0 + tid) * 256 + cblk] =
        dsm[tid] + dsm[256 + tid] + dsm[512 + tid] + dsm[768 + tid];
}

// ---------------- 256x256 pipelined GEMM: C[M,N] = A[M,K] @ B[N,K]^T ----------
// MODE 2: C(f32, slice z) += acc (chunked fallback);  MODE 3: plain store.
template<int MODE>
__global__ __launch_bounds__(512, 2) void gemm256(const u16* __restrict__ A,
                                                  const u16* __restrict__ B,
                                                  float* __restrict__ Cout,
                                                  int K, int nTiles, int ldc) {
  __shared__ __align__(16) u16 lds[65536];
  const int tid  = threadIdx.x;
  const int lane = tid & 63;
  const int wid  = tid >> 6;
  const int wr   = wid >> 2;
  const int wc   = wid & 3;

  const int nwg = (int)(gridDim.x * gridDim.y);
  int lin = blockIdx.y * gridDim.x + blockIdx.x;
  { const int cpx = nwg >> 3; lin = (lin & 7) * cpx + (lin >> 3); }
  const int row0 = (lin & 15) << 8;    // gridDim.x == 16
  const int col0 = (lin >> 4) << 8;

  const int kbase = blockIdx.z * (nTiles << 6);
  const int fr = lane & 15;
  const int fq = lane >> 4;
  const int rb = tid >> 3;
  const int ss = tid & 7;

  f32x4 acc[8][4];
  #pragma unroll
  for (int m = 0; m < 8; ++m)
    #pragma unroll
    for (int n = 0; n < 4; ++n) acc[m][n] = (f32x4){0.f, 0.f, 0.f, 0.f};

  bf16x8 a[4][2], b[2][2][2];

  KLOOP256(kbase)

  float* C = Cout + (size_t)blockIdx.z * NTOK * DIM;
  #pragma unroll
  for (int m = 0; m < 8; ++m)
    #pragma unroll
    for (int n = 0; n < 4; ++n) {
      const int col = col0 + (wc << 6) + (n << 4) + fr;
      #pragma unroll
      for (int j = 0; j < 4; ++j) {
        const int row = row0 + (wr << 7) + (m << 4) + (fq << 2) + j;
        if (MODE == 2) C[(size_t)row * ldc + col] += acc[m][n][j];
        else           C[(size_t)row * ldc + col]  = acc[m][n][j];
      }
    }
}

// ---------------- denom reduce ----------------
__global__ void denom_reduce(const float* __restrict__ dpart, float* __restrict__ denom,
                             int npart) {
  int row = blockIdx.x;
  int l = threadIdx.x;              // 64
  float s = 0.f;
  #pragma unroll
  for (int k = 0; k < 4; ++k) {
    int idx = l + (k << 6);
    if (idx < npart) s += dpart[(size_t)row * 256 + idx];
  }
  #pragma unroll
  for (int off = 32; off >= 1; off >>= 1) s += __shfl_down(s, off, 64);
  if (l == 0) denom[row] = s;
}

// ---------------- finalize ----------------
__global__ void finalize(const float* __restrict__ parts, const float* __restrict__ denom,
                         const float* __restrict__ ve, const int* __restrict__ batch,
                         float* __restrict__ out, int nks) {
  int row = blockIdx.x;
  int t = threadIdx.x;
  float inv = 0.5f / denom[row];
  float4 a = *(const float4*)(ve + (size_t)batch[row] * DIM + (t << 2));
  float sx = 0.f, sy = 0.f, sz = 0.f, sw = 0.f;
  for (int ks = 0; ks < nks; ++ks) {
    float4 pv = *(const float4*)(parts + ((size_t)ks * NTOK + row) * DIM + (t << 2));
    sx += pv.x; sy += pv.y; sz += pv.z; sw += pv.w;
  }
  float4 o;
  o.x = 0.5f * a.x + inv * sx;
  o.y = 0.5f * a.y + inv * sy;
  o.z = 0.5f * a.z + inv * sz;
  o.w = 0.5f * a.w + inv * sw;
  *(float4*)(out + (size_t)row * DIM + (t << 2)) = o;
}

// ---------------- launch ----------------
extern "C" void kernel_launch(void* const* d_in, const int* in_sizes, int n_in,
                              void* d_out, int out_size, void* d_ws, size_t ws_size,
                              hipStream_t stream) {
  const int*   batch = (const int*)d_in[0];
  const float* lang  = (const float*)d_in[1];
  const float* key   = (const float*)d_in[2];
  const float* ve    = (const float*)d_in[3];
  const float* W     = (const float*)d_in[4];
  float* out = (float*)d_out;

  const size_t szWt    = (size_t)DIM * DIM * 2;
  const size_t szQb    = (size_t)NTOK * DIM * 2;
  const size_t szQW    = (size_t)NTOK * DIM * 2;
  const size_t szDpart = (size_t)NTOK * 256 * 4;
  const size_t szDenom = (size_t)NTOK * 4;
  const size_t base    = szWt + szQb + szQW + szDpart + szDenom;

  char* ws = (char*)d_ws;
  u16*   Wt    = (u16*)(ws);
  u16*   qb    = (u16*)(ws + szWt);
  u16*   qW    = (u16*)(ws + szWt + szQb);
  float* dpart = (float*)(ws + szWt + szQb + szQW);
  float* denom = (float*)(ws + szWt + szQb + szQW + szDpart);

  const int KSF = 4;
  const size_t szPartsF = (size_t)KSF * NTOK * DIM * 4;
  const size_t szKeyb   = (size_t)VOCAB * DIM * 2;
  const size_t szVeT    = (size_t)VOCAB * DIM * 2;
  const size_t szP      = (size_t)NTOK * VOCAB * 2;
  const bool fullP = (base + szPartsF + szKeyb + szVeT + szP) <= ws_size;

  transpose_cvt<<<dim3(DIM / 64, DIM / 64), 256, 0, stream>>>(W, Wt, DIM, DIM);
  gather_q<<<NTOK, 256, 0, stream>>>(batch, lang, qb);
  gemm_qw<<<dim3(NTOK / 128, DIM / 128), 256, 0, stream>>>(qb, Wt, qW, DIM, DIM / 32, DIM);

  if (fullP) {
    float* parts = (float*)(ws + base);
    u16*   keyb  = (u16*)(ws + base + szPartsF);
    u16*   veT   = (u16*)(ws + base + szPartsF + szKeyb);
    u16*   P     = (u16*)(ws + base + szPartsF + szKeyb + szVeT);

    cvt_f32_bf16<<<VOCAB * DIM / 1024, 256, 0, stream>>>(key, keyb);
    transpose_cvt<<<dim3(VOCAB / 64, DIM / 64), 256, 0, stream>>>(ve, veT, DIM, VOCAB);
    gemm256e<<<dim3(NTOK / 256, VOCAB / 256), 512, 0, stream>>>(qW, keyb, P, dpart,
                                                                DIM, DIM / 64, VOCAB);
    denom_reduce<<<NTOK, 64, 0, stream>>>(dpart, denom, VOCAB / 256);
    gemm256<3><<<dim3(NTOK / 256, DIM / 256, KSF), 512, 0, stream>>>(P, veT, parts,
                                                                     VOCAB, VOCAB / 64 / KSF, DIM);
    finalize<<<NTOK, 256, 0, stream>>>(parts, denom, ve, batch, out, KSF);
  } else {
    // chunked fallback
    const int KS = 2;
    const size_t szParts = (size_t)KS * NTOK * DIM * 4;
    int CHUNK = 1280;
    {
      const int copt[2] = {6400, 1280};
      for (int i = 0; i < 2; ++i) {
        size_t need = base + szParts + (size_t)copt[i] * (NTOK * 2 + DIM * 4);
        if (need <= ws_size) { CHUNK = copt[i]; break; }
      }
    }
    const int NCHUNK = VOCAB / CHUNK;
    float* parts = (float*)(ws + base);
    char*  dyn   = ws + base + szParts;
    u16*   keyc  = (u16*)(dyn);
    u16*   veTc  = (u16*)(dyn + (size_t)CHUNK * DIM * 2);
    u16*   Pc    = (u16*)(dyn + (size_t)CHUNK * DIM * 4);

    hipMemsetAsync(parts, 0, szParts, stream);
    for (int c = 0; c < NCHUNK; ++c) {
      const int v0 = c * CHUNK;
      cvt_f32_bf16<<<CHUNK * DIM / 1024, 256, 0, stream>>>(key + (size_t)v0 * DIM, keyc);
      transpose_cvt<<<dim3(CHUNK / 64, DIM / 64), 256, 0, stream>>>(ve + (size_t)v0 * DIM, veTc,
                                                                    DIM, CHUNK);
      gemm128e<<<dim3(NTOK / 128, CHUNK / 128), 256, 0, stream>>>(qW, keyc, Pc, dpart,
                                                                  DIM, DIM / 64, CHUNK, v0 >> 7);
      gemm256<2><<<dim3(NTOK / 256, DIM / 256, KS), 512, 0, stream>>>(Pc, veTc, parts,
                                                                      CHUNK, CHUNK / 64 / KS, DIM);
    }
    denom_reduce<<<NTOK, 64, 0, stream>>>(dpart, denom, 250);
    finalize<<<NTOK, 256, 0, stream>>>(parts, denom, ve, batch, out, KS);
  }
}

// Round 10
// 664.577 us; speedup vs baseline: 1.7679x; 1.0502x over previous
//
#include <hip/hip_runtime.h>

// out = 0.5*ve[batch] + 0.5 * softmax((lang[batch]@W) @ keyᵀ) @ ve
// Full-P dataflow in fp8 e4m3 (inputs scaled x16, scores /256 before exp):
//   P8 = e4m3(exp(qW8 @ key8ᵀ /256)), fused row-sums; parts = P8 @ veT8ᵀ.
// 256² pipelined GEMMs: counted vmcnt, pair-interleaved K storage (one b128 =
// two K-subfragments), XOR chunk swizzle, XCD swizzle, 64 KiB LDS = 2 blk/CU.
// bf16 chunked fallback if ws_size too small.

#define DIM   1024
#define VOCAB 32000
#define NTOK  4096

typedef unsigned short u16;
typedef unsigned char  u8;
typedef long long      i64t;
typedef __attribute__((ext_vector_type(2))) long long i64x2;
typedef __attribute__((ext_vector_type(8))) __bf16 bf16x8;
typedef __attribute__((ext_vector_type(4))) float  f32x4;
typedef __attribute__((ext_vector_type(8))) u16    u16x8;
typedef __attribute__((ext_vector_type(4))) u16    u16x4;
typedef __attribute__((ext_vector_type(8))) u8     u8x8;

__device__ __forceinline__ u16 f2bf(float f) {  // round-to-nearest-even
  unsigned u = __float_as_uint(f);
  u += 0x7FFFu + ((u >> 16) & 1u);
  return (u16)(u >> 16);
}
__device__ __forceinline__ float bf2f(u16 s) {
  return __uint_as_float(((unsigned)s) << 16);
}
// f32 -> OCP e4m3 (RNE, no sat: inputs bounded ~2)
__device__ __forceinline__ u8 f2e4m3(float f) {
  unsigned u = __float_as_uint(f);
  unsigned s = (u >> 24) & 0x80u;
  int e = (int)((u >> 23) & 0xFF);
  unsigned m = u & 0x7FFFFF;
  int te = e - 127 + 7;
  if (te >= 1) {
    unsigned keep = m >> 20;
    unsigned rest = m & 0xFFFFF;
    keep += (rest > 0x80000u) || (rest == 0x80000u && (keep & 1));
    if (keep == 8) { keep = 0; te += 1; }
    return (u8)(s | ((unsigned)te << 3) | keep);
  } else {
    float q = fabsf(f) * 512.0f;     // quanta of 2^-9
    int qi = (int)rintf(q);
    if (qi > 7) return (u8)(s | (1u << 3));
    return (u8)(s | (unsigned)qi);
  }
}
// K-storage permutation within a 64-block: orig k -> pos (pair-interleave)
__device__ __forceinline__ int kperm(int k) {
  return ((k >> 3) & 3) * 16 + ((k >> 5) << 3) + (k & 7);
}

#define SB() __builtin_amdgcn_sched_barrier(0)
#define BAR() { SB(); __builtin_amdgcn_s_barrier(); SB(); }

// ---------------- conversion / gather ----------------

__global__ void cvt_f32_bf16(const float* __restrict__ in, u16* __restrict__ out) {
  size_t i = (size_t)blockIdx.x * 256 + threadIdx.x;
  float4 v = ((const float4*)in)[i];
  u16x4 o; o[0]=f2bf(v.x); o[1]=f2bf(v.y); o[2]=f2bf(v.z); o[3]=f2bf(v.w);
  ((u16x4*)out)[i] = o;
}

__global__ void gather_q(const int* __restrict__ batch, const float* __restrict__ lang,
                         u16* __restrict__ q) {
  int row = blockIdx.x;
  int src = batch[row];
  int t = threadIdx.x;
  float4 v = *(const float4*)(lang + (size_t)src * DIM + (t << 2));
  u16x4 o; o[0]=f2bf(v.x); o[1]=f2bf(v.y); o[2]=f2bf(v.z); o[3]=f2bf(v.w);
  *(u16x4*)(q + (size_t)row * DIM + (t << 2)) = o;
}

// bf16 transpose (W prologue + fallback): out[c][r] = bf16(in[r][c])
__global__ void transpose_cvt(const float* __restrict__ in, u16* __restrict__ out,
                              int ldin, int ldout) {
  __shared__ u16 t[64][66];
  int r0 = blockIdx.x << 6;
  int c0 = blockIdx.y << 6;
  int tid = threadIdx.x;
  #pragma unroll
  for (int p = 0; p < 4; ++p) {
    int r = (p << 4) + (tid >> 4);
    int c = (tid & 15) << 2;
    float4 v = *(const float4*)(in + (size_t)(r0 + r) * ldin + c0 + c);
    t[c+0][r] = f2bf(v.x);
    t[c+1][r] = f2bf(v.y);
    t[c+2][r] = f2bf(v.z);
    t[c+3][r] = f2bf(v.w);
  }
  __syncthreads();
  #pragma unroll
  for (int qq = 0; qq < 2; ++qq) {
    int rr = tid >> 2;
    int cc = (((tid & 3) << 1) + qq) << 3;
    u16x8 w;
    #pragma unroll
    for (int j = 0; j < 8; ++j) w[j] = t[rr][cc + j];
    *(u16x8*)(out + (size_t)(c0 + rr) * ldout + r0 + cc) = w;
  }
}

// key f32 -> fp8 x16, K(DIM)-permuted. one thread = 8 output bytes (one group)
__global__ void cvt_key_f8(const float* __restrict__ in, u8* __restrict__ out) {
  size_t g = (size_t)blockIdx.x * 256 + threadIdx.x;
  size_t row = g >> 7;               // DIM/8 = 128 groups per row
  int gg = (int)(g & 127);
  int b = gg >> 3, G = gg & 7;
  int O = ((G & 1) << 2) + (G >> 1); // inverse group perm
  const float* src = in + row * DIM + (b << 6) + (O << 3);
  float4 v0 = *(const float4*)src;
  float4 v1 = *(const float4*)(src + 4);
  u8x8 o;
  o[0]=f2e4m3(16.f*v0.x); o[1]=f2e4m3(16.f*v0.y); o[2]=f2e4m3(16.f*v0.z); o[3]=f2e4m3(16.f*v0.w);
  o[4]=f2e4m3(16.f*v1.x); o[5]=f2e4m3(16.f*v1.y); o[6]=f2e4m3(16.f*v1.z); o[7]=f2e4m3(16.f*v1.w);
  *(u8x8*)(out + row * DIM + (b << 6) + (G << 3)) = o;
}

// qW bf16 -> fp8 x16, K(DIM)-permuted
__global__ void cvt_qw_f8(const u16* __restrict__ in, u8* __restrict__ out) {
  size_t g = (size_t)blockIdx.x * 256 + threadIdx.x;
  size_t row = g >> 7;
  int gg = (int)(g & 127);
  int b = gg >> 3, G = gg & 7;
  int O = ((G & 1) << 2) + (G >> 1);
  u16x8 v = *(const u16x8*)(in + row * DIM + (b << 6) + (O << 3));
  u8x8 o;
  #pragma unroll
  for (int j = 0; j < 8; ++j) o[j] = f2e4m3(16.f * bf2f(v[j]));
  *(u8x8*)(out + row * DIM + (b << 6) + (G << 3)) = o;
}

// ve f32 [VOCAB][DIM] -> veT8 fp8 x16 [DIM][VOCAB], K(VOCAB)-permuted
__global__ void transpose_cvt_f8(const float* __restrict__ in, u8* __restrict__ out) {
  __shared__ float t[64][65];
  int r0 = blockIdx.x << 6;          // vocab base
  int c0 = blockIdx.y << 6;          // dim base
  int tid = threadIdx.x;
  #pragma unroll
  for (int p = 0; p < 4; ++p) {
    int r = (p << 4) + (tid >> 4);
    int c = (tid & 15) << 2;
    float4 v = *(const float4*)(in + (size_t)(r0 + r) * DIM + c0 + c);
    t[c+0][r] = v.x; t[c+1][r] = v.y; t[c+2][r] = v.z; t[c+3][r] = v.w;
  }
  __syncthreads();
  #pragma unroll
  for (int qq = 0; qq < 2; ++qq) {
    int rr = tid >> 2;                          // dim-local
    int O  = ((tid & 3) << 1) + qq;             // orig vocab group 0..7
    int cc = O << 3;
    int Gp = ((O & 3) << 1) + (O >> 2);         // stored group
    u8x8 w;
    #pragma unroll
    for (int j = 0; j < 8; ++j) w[j] = f2e4m3(16.f * t[rr][cc + j]);
    *(u8x8*)(out + (size_t)(c0 + rr) * VOCAB + r0 + (Gp << 3)) = w;
  }
}

// ---------------- small GEMM for qW: C[M,N]=A@B^T, 128x128 tile (bf16 out) ----
__global__ void gemm_qw(const u16* __restrict__ A, const u16* __restrict__ B,
                        u16* __restrict__ C, int K, int kSteps, int ldc) {
  __shared__ u16 As[128 * 32];
  __shared__ u16 Bs[128 * 32];
  const int tid  = threadIdx.x;
  const int lane = tid & 63;
  const int wid  = tid >> 6;
  const int wr   = wid >> 1, wc = wid & 1;
  const int row0 = blockIdx.x << 7;
  const int col0 = blockIdx.y << 7;

  f32x4 acc[4][4];
  #pragma unroll
  for (int m = 0; m < 4; ++m)
    #pragma unroll
    for (int n = 0; n < 4; ++n) acc[m][n] = (f32x4){0.f,0.f,0.f,0.f};

  const int sr = lane >> 2;
  const int sc = (lane & 3) << 3;

  for (int ks = 0; ks < kSteps; ++ks) {
    const int kk = ks << 5;
    #pragma unroll
    for (int t = 0; t < 2; ++t) {
      const int i = wid * 2 + t;
      const u16* gA = A + (size_t)(row0 + (i << 4) + sr) * K + kk + sc;
      const u16* gB = B + (size_t)(col0 + (i << 4) + sr) * K + kk + sc;
      __builtin_amdgcn_global_load_lds((const __attribute__((address_space(1))) void*)gA,
                                       (__attribute__((address_space(3))) void*)(As + i * 512),
                                       16, 0, 0);
      __builtin_amdgcn_global_load_lds((const __attribute__((address_space(1))) void*)gB,
                                       (__attribute__((address_space(3))) void*)(Bs + i * 512),
                                       16, 0, 0);
    }
    __syncthreads();
    bf16x8 a[4], b[4];
    #pragma unroll
    for (int m = 0; m < 4; ++m)
      a[m] = *(const bf16x8*)(As + ((wr << 6) + (m << 4) + (lane & 15)) * 32 + ((lane >> 4) << 3));
    #pragma unroll
    for (int n = 0; n < 4; ++n)
      b[n] = *(const bf16x8*)(Bs + ((wc << 6) + (n << 4) + (lane & 15)) * 32 + ((lane >> 4) << 3));
    #pragma unroll
    for (int m = 0; m < 4; ++m)
      #pragma unroll
      for (int n = 0; n < 4; ++n)
        acc[m][n] = __builtin_amdgcn_mfma_f32_16x16x32_bf16(a[m], b[n], acc[m][n], 0, 0, 0);
    __syncthreads();
  }

  const int r0 = row0 + (wr << 6);
  const int c0 = col0 + (wc << 6);
  const int fq = (lane >> 4) << 2;
  const int fr = lane & 15;
  #pragma unroll
  for (int m = 0; m < 4; ++m)
    #pragma unroll
    for (int n = 0; n < 4; ++n) {
      int col = c0 + (n << 4) + fr;
      #pragma unroll
      for (int j = 0; j < 4; ++j) {
        int row = r0 + (m << 4) + fq + j;
        C[(size_t)row * ldc + col] = f2bf(acc[m][n][j]);
      }
    }
}

// ---------------- fp8 256² K-loop (BK=64 bytes, 2 bufs = 64 KiB) --------------
#define STGF8(d, kk)                                                               \
  {                                                                                \
    _Pragma("unroll")                                                              \
    for (int c = 0; c < 2; ++c) {                                                  \
      const int ra = (tid >> 2) + (c << 7);                                        \
      const u8* gA = A + (size_t)(row0 + ra) * Kb + (kk) +                         \
                     (((tid & 3) ^ (ra & 3)) << 4);                                \
      __builtin_amdgcn_global_load_lds(                                            \
          (const __attribute__((address_space(1))) void*)gA,                       \
          (__attribute__((address_space(3))) void*)(lds + (d) * 32768 + (c << 13) + tid * 16), \
          16, 0, 0);                                                               \
    }                                                                              \
    _Pragma("unroll")                                                              \
    for (int c = 0; c < 2; ++c) {                                                  \
      const int rn = (tid >> 2) + (c << 7);                                        \
      const u8* gB = B + (size_t)(col0 + rn) * Kb + (kk) +                         \
                     (((tid & 3) ^ (rn & 3)) << 4);                                \
      __builtin_amdgcn_global_load_lds(                                            \
          (const __attribute__((address_space(1))) void*)gB,                       \
          (__attribute__((address_space(3))) void*)(lds + (d) * 32768 + 16384 + (c << 13) + tid * 16), \
          16, 0, 0);                                                               \
    }                                                                              \
  }

#define KLOOPF8(NT, KB)                                                            \
  STGF8(0, (KB))                                                                   \
  STGF8(1, (KB) + 64)                                                              \
  for (int t = 0; t < (NT); ++t) {                                                 \
    const int d = t & 1;                                                           \
    const u8* Abuf = lds + d * 32768;                                              \
    const u8* Bbuf = Abuf + 16384;                                                 \
    SB();                                                                          \
    if (t + 1 < (NT)) { asm volatile("s_waitcnt vmcnt(4)"); }                      \
    else              { asm volatile("s_waitcnt vmcnt(0)"); }                      \
    BAR();                                                                         \
    _Pragma("unroll")                                                              \
    for (int nh = 0; nh < 2; ++nh)                                                 \
      _Pragma("unroll")                                                            \
      for (int nq = 0; nq < 2; ++nq) {                                             \
        const int row = (wc << 6) + (nh << 5) + (nq << 4) + fr;                    \
        i64x2 v = *(const i64x2*)(Bbuf + row * 64 + ((fq ^ (row & 3)) << 4));      \
        b[nh][nq][0] = v[0]; b[nh][nq][1] = v[1];                                  \
      }                                                                            \
    _Pragma("unroll")                                                              \
    for (int mh = 0; mh < 2; ++mh) {                                               \
      _Pragma("unroll")                                                            \
      for (int mq = 0; mq < 4; ++mq) {                                             \
        const int row = (wr << 7) + (mh << 6) + (mq << 4) + fr;                    \
        i64x2 v = *(const i64x2*)(Abuf + row * 64 + ((fq ^ (row & 3)) << 4));      \
        a[mq][0] = v[0]; a[mq][1] = v[1];                                          \
      }                                                                            \
      __builtin_amdgcn_s_setprio(1);                                               \
      _Pragma("unroll")                                                            \
      for (int mq = 0; mq < 4; ++mq)                                               \
        _Pragma("unroll")                                                          \
        for (int nh = 0; nh < 2; ++nh)                                             \
          _Pragma("unroll")                                                        \
          for (int nq = 0; nq < 2; ++nq)                                           \
            _Pragma("unroll")                                                      \
            for (int ks = 0; ks < 2; ++ks)                                         \
              acc[(mh << 2) + mq][(nh << 1) + nq] =                                \
                  __builtin_amdgcn_mfma_f32_16x16x32_fp8_fp8(                      \
                      a[mq][ks], b[nh][nq][ks],                                    \
                      acc[(mh << 2) + mq][(nh << 1) + nq], 0, 0, 0);               \
      __builtin_amdgcn_s_setprio(0);                                               \
    }                                                                              \
    BAR();                                                                         \
    if (t + 2 < (NT)) STGF8(d, (KB) + ((t + 2) << 6))                              \
  }

// ---------------- fp8 exp-GEMM: P8 = e4m3(exp(acc/256)), fused rowsum ---------
__global__ __launch_bounds__(512, 2) void gemm256e8(const u8* __restrict__ A,
                                                    const u8* __restrict__ B,
                                                    u8* __restrict__ P,
                                                    float* __restrict__ dpart,
                                                    int Kb, int nTiles) {
  __shared__ __align__(16) u8 lds[65536];
  const int tid  = threadIdx.x;
  const int lane = tid & 63;
  const int wid  = tid >> 6;
  const int wr   = wid >> 2;
  const int wc   = wid & 3;

  const int nwg = (int)(gridDim.x * gridDim.y);
  int lin = blockIdx.y * gridDim.x + blockIdx.x;
  { const int cpx = nwg >> 3; lin = (lin & 7) * cpx + (lin >> 3); }
  const int row0 = (lin & 15) << 8;    // gridDim.x == 16
  const int cblk = lin >> 4;
  const int col0 = cblk << 8;

  const int fr = lane & 15;
  const int fq = lane >> 4;

  f32x4 acc[8][4];
  #pragma unroll
  for (int m = 0; m < 8; ++m)
    #pragma unroll
    for (int n = 0; n < 4; ++n) acc[m][n] = (f32x4){0.f, 0.f, 0.f, 0.f};

  i64t a[4][2], b[2][2][2];

  KLOOPF8(nTiles, 0)

  // epilogue: P8 = e4m3(exp(acc/256)) at K-permuted cols; fused row-sums
  const float inv256 = 1.0f / 256.0f;
  float rs[32];
  #pragma unroll
  for (int i = 0; i < 32; ++i) rs[i] = 0.f;
  #pragma unroll
  for (int m = 0; m < 8; ++m)
    #pragma unroll
    for (int n = 0; n < 4; ++n) {
      const int l6  = (n << 4) + fr;
      const int col = col0 + (wc << 6) + kperm(l6);
      #pragma unroll
      for (int j = 0; j < 4; ++j) {
        const int row = row0 + (wr << 7) + (m << 4) + (fq << 2) + j;
        float e = __expf(acc[m][n][j] * inv256);
        P[(size_t)row * VOCAB + col] = f2e4m3(e);
        rs[(m << 2) + j] += e;
      }
    }
  #pragma unroll
  for (int i = 0; i < 32; ++i) {
    #pragma unroll
    for (int s = 8; s >= 1; s >>= 1) rs[i] += __shfl_xor(rs[i], s, 16);
  }
  __syncthreads();
  float* dsm = (float*)lds;
  if (fr == 0) {
    #pragma unroll
    for (int m = 0; m < 8; ++m)
      #pragma unroll
      for (int j = 0; j < 4; ++j)
        dsm[(wc << 8) + (wr << 7) + (m << 4) + (fq << 2) + j] = rs[(m << 2) + j];
  }
  __syncthreads();
  if (tid < 256)
    dpart[(size_t)(row0 + tid) * 256 + cblk] =
        dsm[tid] + dsm[256 + tid] + dsm[512 + tid] + dsm[768 + tid];
}

// ---------------- fp8 PV GEMM: parts[z] = P8 @ veT8ᵀ (uneven split-K=8) -------
__global__ __launch_bounds__(512, 2) void gemm256p8(const u8* __restrict__ A,
                                                    const u8* __restrict__ B,
                                                    float* __restrict__ Cout,
                                                    int Kb) {
  __shared__ __align__(16) u8 lds[65536];
  const int tid  = threadIdx.x;
  const int lane = tid & 63;
  const int wid  = tid >> 6;
  const int wr   = wid >> 2;
  const int wc   = wid & 3;

  const int nwg = (int)(gridDim.x * gridDim.y);
  int lin = blockIdx.y * gridDim.x + blockIdx.x;
  { const int cpx = nwg >> 3; lin = (lin & 7) * cpx + (lin >> 3); }
  const int row0 = (lin & 15) << 8;    // gridDim.x == 16
  const int col0 = (lin >> 4) << 8;

  const int z = blockIdx.z;            // 0..7 ; 500 tiles = 4x63 + 4x62
  const int nT = (z < 4) ? 63 : 62;
  const int kb = ((z * 62 + ((z < 4) ? z : 4)) << 6);

  const int fr = lane & 15;
  const int fq = lane >> 4;

  f32x4 acc[8][4];
  #pragma unroll
  for (int m = 0; m < 8; ++m)
    #pragma unroll
    for (int n = 0; n < 4; ++n) acc[m][n] = (f32x4){0.f, 0.f, 0.f, 0.f};

  i64t a[4][2], b[2][2][2];

  KLOOPF8(nT, kb)

  float* C = Cout + (size_t)z * NTOK * DIM;
  #pragma unroll
  for (int m = 0; m < 8; ++m)
    #pragma unroll
    for (int n = 0; n < 4; ++n) {
      const int col = col0 + (wc << 6) + (n << 4) + fr;
      #pragma unroll
      for (int j = 0; j < 4; ++j) {
        const int row = row0 + (wr << 7) + (m << 4) + (fq << 2) + j;
        C[(size_t)row * DIM + col] = acc[m][n][j];
      }
    }
}

// ---------------- bf16 128² exp-GEMM + bf16 256² PV (chunked fallback) --------
__global__ __launch_bounds__(256, 2) void gemm128e(const u16* __restrict__ A,
                                                   const u16* __restrict__ B,
                                                   u16* __restrict__ P,
                                                   float* __restrict__ dpart,
                                                   int K, int nTiles, int ldc, int cb0) {
  __shared__ __align__(16) u16 lds[32768];
  const int tid  = threadIdx.x;
  const int lane = tid & 63;
  const int wid  = tid >> 6;
  const int wr   = wid >> 1;
  const int wc   = wid & 1;

  const int nwg = (int)(gridDim.x * gridDim.y);
  int lin = blockIdx.y * gridDim.x + blockIdx.x;
  { const int cpx = nwg >> 3; lin = (lin & 7) * cpx + (lin >> 3); }
  const int row0 = (lin & 31) << 7;
  const int cblk = lin >> 5;
  const int col0 = cblk << 7;

  const int fr = lane & 15;
  const int fq = lane >> 4;
  const int rb = tid >> 3;
  const int ss = tid & 7;

#define STG128(d, kk)                                                              \
  {                                                                                \
    _Pragma("unroll")                                                              \
    for (int c = 0; c < 4; ++c) {                                                  \
      const int ra = (c << 5) + rb;                                                \
      const u16* gA = A + (size_t)(row0 + ra) * K + (kk) + ((ss ^ (ra & 7)) << 3); \
      __builtin_amdgcn_global_load_lds(                                            \
          (const __attribute__((address_space(1))) void*)gA,                       \
          (__attribute__((address_space(3))) void*)(lds + (d) * 16384 + (((c << 5) + (wid << 3)) << 6)), \
          16, 0, 0);                                                               \
    }                                                                              \
    _Pragma("unroll")                                                              \
    for (int c = 0; c < 4; ++c) {                                                  \
      const int rn = (c << 5) + rb;                                                \
      const u16* gB = B + (size_t)(col0 + rn) * K + (kk) + ((ss ^ (rn & 7)) << 3); \
      __builtin_amdgcn_global_load_lds(                                            \
          (const __attribute__((address_space(1))) void*)gB,                       \
          (__attribute__((address_space(3))) void*)(lds + (d) * 16384 + 8192 + (((c << 5) + (wid << 3)) << 6)), \
          16, 0, 0);                                                               \
    }                                                                              \
  }

  f32x4 acc[4][4];
  #pragma unroll
  for (int m = 0; m < 4; ++m)
    #pragma unroll
    for (int n = 0; n < 4; ++n) acc[m][n] = (f32x4){0.f, 0.f, 0.f, 0.f};

  STG128(0, 0)
  STG128(1, 64)

  bf16x8 a[4], b[4];

  for (int t = 0; t < nTiles; ++t) {
    const int d = t & 1;
    const u16* Abuf = lds + d * 16384;
    const u16* Bbuf = Abuf + 8192;
    SB();
    if (t + 1 < nTiles) { asm volatile("s_waitcnt vmcnt(8)"); }
    else                { asm volatile("s_waitcnt vmcnt(0)"); }
    BAR();

    #pragma unroll
    for (int ks = 0; ks < 2; ++ks) {
      #pragma unroll
      for (int mq = 0; mq < 4; ++mq) {
        const int row  = (wr << 6) + (mq << 4) + fr;
        const int slot = ((ks << 2) + fq) ^ (row & 7);
        a[mq] = *(const bf16x8*)(Abuf + (row << 6) + (slot << 3));
      }
      #pragma unroll
      for (int nq = 0; nq < 4; ++nq) {
        const int row  = (wc << 6) + (nq << 4) + fr;
        const int slot = ((ks << 2) + fq) ^ (row & 7);
        b[nq] = *(const bf16x8*)(Bbuf + (row << 6) + (slot << 3));
      }
      __builtin_amdgcn_s_setprio(1);
      #pragma unroll
      for (int mq = 0; mq < 4; ++mq)
        #pragma unroll
        for (int nq = 0; nq < 4; ++nq)
          acc[mq][nq] = __builtin_amdgcn_mfma_f32_16x16x32_bf16(
              a[mq], b[nq], acc[mq][nq], 0, 0, 0);
      __builtin_amdgcn_s_setprio(0);
    }
    BAR();
    if (t + 2 < nTiles) STG128(d, (t + 2) << 6)
  }
#undef STG128

  float rs[16];
  #pragma unroll
  for (int i = 0; i < 16; ++i) rs[i] = 0.f;
  #pragma unroll
  for (int mq = 0; mq < 4; ++mq)
    #pragma unroll
    for (int nq = 0; nq < 4; ++nq) {
      const int col = col0 + (wc << 6) + (nq << 4) + fr;
      #pragma unroll
      for (int j = 0; j < 4; ++j) {
        const int row = row0 + (wr << 6) + (mq << 4) + (fq << 2) + j;
        float e = __expf(acc[mq][nq][j]);
        P[(size_t)row * ldc + col] = f2bf(e);
        rs[(mq << 2) + j] += e;
      }
    }
  #pragma unroll
  for (int i = 0; i < 16; ++i) {
    #pragma unroll
    for (int s = 8; s >= 1; s >>= 1) rs[i] += __shfl_xor(rs[i], s, 16);
  }
  __syncthreads();
  float* dsm = (float*)lds;
  if (fr == 0) {
    #pragma unroll
    for (int mq = 0; mq < 4; ++mq)
      #pragma unroll
      for (int j = 0; j < 4; ++j)
        dsm[(wc << 7) + (wr << 6) + (mq << 4) + (fq << 2) + j] = rs[(mq << 2) + j];
  }
  __syncthreads();
  if (tid < 128)
    dpart[(size_t)(row0 + tid) * 256 + cb0 + cblk] = dsm[tid] + dsm[128 + tid];
}

#define STG256(d, kk)                                                              \
  {                                                                                \
    _Pragma("unroll")                                                              \
    for (int c = 0; c < 4; ++c) {                                                  \
      const int ra = (c << 6) + rb;                                                \
      const u16* gA = A + (size_t)(row0 + ra) * K + (kk) + ((ss ^ (ra & 7)) << 3); \
      __builtin_amdgcn_global_load_lds(                                            \
          (const __attribute__((address_space(1))) void*)gA,                       \
          (__attribute__((address_space(3))) void*)(lds + (d) * 32768 + (((c << 6) + (wid << 3)) << 6)), \
          16, 0, 0);                                                               \
    }                                                                              \
    _Pragma("unroll")                                                              \
    for (int c = 0; c < 4; ++c) {                                                  \
      const int rn = (c << 6) + rb;                                                \
      const u16* gB = B + (size_t)(col0 + rn) * K + (kk) + ((ss ^ (rn & 7)) << 3); \
      __builtin_amdgcn_global_load_lds(                                            \
          (const __attribute__((address_space(1))) void*)gB,                       \
          (__attribute__((address_space(3))) void*)(lds + (d) * 32768 + 16384 + (((c << 6) + (wid << 3)) << 6)), \
          16, 0, 0);                                                               \
    }                                                                              \
  }

// bf16 256² PV for fallback (MODE 2: += into parts slice)
__global__ __launch_bounds__(512, 2) void gemm256acc(const u16* __restrict__ A,
                                                     const u16* __restrict__ B,
                                                     float* __restrict__ Cout,
                                                     int K, int nTiles, int ldc) {
  __shared__ __align__(16) u16 lds[65536];
  const int tid  = threadIdx.x;
  const int lane = tid & 63;
  const int wid  = tid >> 6;
  const int wr   = wid >> 2;
  const int wc   = wid & 3;

  const int nwg = (int)(gridDim.x * gridDim.y);
  int lin = blockIdx.y * gridDim.x + blockIdx.x;
  { const int cpx = nwg >> 3; lin = (lin & 7) * cpx + (lin >> 3); }
  const int row0 = (lin & 15) << 8;
  const int col0 = (lin >> 4) << 8;

  const int kbase = blockIdx.z * (nTiles << 6);
  const int fr = lane & 15;
  const int fq = lane >> 4;
  const int rb = tid >> 3;
  const int ss = tid & 7;

  f32x4 acc[8][4];
  #pragma unroll
  for (int m = 0; m < 8; ++m)
    #pragma unroll
    for (int n = 0; n < 4; ++n) acc[m][n] = (f32x4){0.f, 0.f, 0.f, 0.f};

  bf16x8 a[4][2], b[2][2][2];

  STG256(0, kbase)
  STG256(1, kbase + 64)
  for (int t = 0; t < nTiles; ++t) {
    const int d = t & 1;
    const u16* Abuf = lds + d * 32768;
    const u16* Bbuf = Abuf + 16384;
    SB();
    if (t + 1 < nTiles) { asm volatile("s_waitcnt vmcnt(8)"); }
    else                { asm volatile("s_waitcnt vmcnt(0)"); }
    BAR();
    #pragma unroll
    for (int nh = 0; nh < 2; ++nh)
      #pragma unroll
      for (int nq = 0; nq < 2; ++nq)
        #pragma unroll
        for (int ks = 0; ks < 2; ++ks) {
          const int row  = (wc << 6) + (nh << 5) + (nq << 4) + fr;
          const int slot = ((ks << 2) + fq) ^ (row & 7);
          b[nh][nq][ks] = *(const bf16x8*)(Bbuf + (row << 6) + (slot << 3));
        }
    #pragma unroll
    for (int mh = 0; mh < 2; ++mh) {
      #pragma unroll
      for (int mq = 0; mq < 4; ++mq)
        #pragma unroll
        for (int ks = 0; ks < 2; ++ks) {
          const int row  = (wr << 7) + (mh << 6) + (mq << 4) + fr;
          const int slot = ((ks << 2) + fq) ^ (row & 7);
          a[mq][ks] = *(const bf16x8*)(Abuf + (row << 6) + (slot << 3));
        }
      __builtin_amdgcn_s_setprio(1);
      #pragma unroll
      for (int mq = 0; mq < 4; ++mq)
        #pragma unroll
        for (int nh = 0; nh < 2; ++nh)
          #pragma unroll
          for (int nq = 0; nq < 2; ++nq)
            #pragma unroll
            for (int ks = 0; ks < 2; ++ks)
              acc[(mh << 2) + mq][(nh << 1) + nq] =
                  __builtin_amdgcn_mfma_f32_16x16x32_bf16(
                      a[mq][ks], b[nh][nq][ks], acc[(mh << 2) + mq][(nh << 1) + nq], 0, 0, 0);
      __builtin_amdgcn_s_setprio(0);
    }
    BAR();
    if (t + 2 < nTiles) STG256(d, kbase + ((t + 2) << 6))
  }

  float* C = Cout + (size_t)blockIdx.z * NTOK * DIM;
  #pragma unroll
  for (int m = 0; m < 8; ++m)
    #pragma unroll
    for (int n = 0; n < 4; ++n) {
      const int col = col0 + (wc << 6) + (n << 4) + fr;
      #pragma unroll
      for (int j = 0; j < 4; ++j) {
        const int row = row0 + (wr << 7) + (m << 4) + (fq << 2) + j;
        C[(size_t)row * ldc + col] += acc[m][n][j];
      }
    }
}

// ---------------- denom reduce ----------------
__global__ void denom_reduce(const float* __restrict__ dpart, float* __restrict__ denom,
                             int npart) {
  int row = blockIdx.x;
  int l = threadIdx.x;              // 64
  float s = 0.f;
  #pragma unroll
  for (int k = 0; k < 4; ++k) {
    int idx = l + (k << 6);
    if (idx < npart) s += dpart[(size_t)row * 256 + idx];
  }
  #pragma unroll
  for (int off = 32; off >= 1; off >>= 1) s += __shfl_down(s, off, 64);
  if (l == 0) denom[row] = s;
}

// ---------------- finalize ----------------
__global__ void finalize(const float* __restrict__ parts, const float* __restrict__ denom,
                         const float* __restrict__ ve, const int* __restrict__ batch,
                         float* __restrict__ out, int nks, float pvInv) {
  int row = blockIdx.x;
  int t = threadIdx.x;
  float inv = 0.5f * pvInv / denom[row];
  float4 a = *(const float4*)(ve + (size_t)batch[row] * DIM + (t << 2));
  float sx = 0.f, sy = 0.f, sz = 0.f, sw = 0.f;
  for (int ks = 0; ks < nks; ++ks) {
    float4 pv = *(const float4*)(parts + ((size_t)ks * NTOK + row) * DIM + (t << 2));
    sx += pv.x; sy += pv.y; sz += pv.z; sw += pv.w;
  }
  float4 o;
  o.x = 0.5f * a.x + inv * sx;
  o.y = 0.5f * a.y + inv * sy;
  o.z = 0.5f * a.z + inv * sz;
  o.w = 0.5f * a.w + inv * sw;
  *(float4*)(out + (size_t)row * DIM + (t << 2)) = o;
}

// ---------------- launch ----------------
extern "C" void kernel_launch(void* const* d_in, const int* in_sizes, int n_in,
                              void* d_out, int out_size, void* d_ws, size_t ws_size,
                              hipStream_t stream) {
  const int*   batch = (const int*)d_in[0];
  const float* lang  = (const float*)d_in[1];
  const float* key   = (const float*)d_in[2];
  const float* ve    = (const float*)d_in[3];
  const float* W     = (const float*)d_in[4];
  float* out = (float*)d_out;

  const size_t szWt    = (size_t)DIM * DIM * 2;
  const size_t szQb    = (size_t)NTOK * DIM * 2;
  const size_t szQW    = (size_t)NTOK * DIM * 2;
  const size_t szDpart = (size_t)NTOK * 256 * 4;
  const size_t szDenom = (size_t)NTOK * 4;
  const size_t base    = szWt + szQb + szQW + szDpart + szDenom;

  char* ws = (char*)d_ws;
  u16*   Wt    = (u16*)(ws);
  u16*   qb    = (u16*)(ws + szWt);
  u16*   qW    = (u16*)(ws + szWt + szQb);
  float* dpart = (float*)(ws + szWt + szQb + szQW);
  float* denom = (float*)(ws + szWt + szQb + szQW + szDpart);

  const int KSF = 8;
  const size_t szPartsF = (size_t)KSF * NTOK * DIM * 4;     // 134 MB
  const size_t szQW8    = (size_t)NTOK * DIM;               //   4 MB
  const size_t szKey8   = (size_t)VOCAB * DIM;              //  33 MB
  const size_t szVeT8   = (size_t)DIM * VOCAB;              //  33 MB
  const size_t szP8     = (size_t)NTOK * VOCAB;             // 131 MB
  const bool fullP = (base + szPartsF + szQW8 + szKey8 + szVeT8 + szP8) <= ws_size;

  transpose_cvt<<<dim3(DIM / 64, DIM / 64), 256, 0, stream>>>(W, Wt, DIM, DIM);
  gather_q<<<NTOK, 256, 0, stream>>>(batch, lang, qb);
  gemm_qw<<<dim3(NTOK / 128, DIM / 128), 256, 0, stream>>>(qb, Wt, qW, DIM, DIM / 32, DIM);

  if (fullP) {
    float* parts = (float*)(ws + base);
    u8*    qW8   = (u8*)(ws + base + szPartsF);
    u8*    key8  = (u8*)(ws + base + szPartsF + szQW8);
    u8*    veT8  = (u8*)(ws + base + szPartsF + szQW8 + szKey8);
    u8*    P8    = (u8*)(ws + base + szPartsF + szQW8 + szKey8 + szVeT8);

    cvt_qw_f8<<<NTOK * DIM / 8 / 256, 256, 0, stream>>>(qW, qW8);
    cvt_key_f8<<<VOCAB * DIM / 8 / 256, 256, 0, stream>>>(key, key8);
    transpose_cvt_f8<<<dim3(VOCAB / 64, DIM / 64), 256, 0, stream>>>(ve, veT8);

    // P8 = e4m3(exp(qW8 @ key8ᵀ / 256)), fused row-sum partials
    gemm256e8<<<dim3(NTOK / 256, VOCAB / 256), 512, 0, stream>>>(qW8, key8, P8, dpart,
                                                                 DIM, DIM / 64);
    denom_reduce<<<NTOK, 64, 0, stream>>>(dpart, denom, VOCAB / 256);
    // parts[z] = P8 @ veT8ᵀ (uneven split-K = 8, 512 blocks = 2/CU)
    gemm256p8<<<dim3(NTOK / 256, DIM / 256, KSF), 512, 0, stream>>>(P8, veT8, parts, VOCAB);
    finalize<<<NTOK, 256, 0, stream>>>(parts, denom, ve, batch, out, KSF, 1.0f / 16.0f);
  } else {
    // bf16 chunked fallback (proven path)
    const int KS = 2;
    const size_t szParts = (size_t)KS * NTOK * DIM * 4;
    int CHUNK = 1280;
    {
      const int copt[2] = {6400, 1280};
      for (int i = 0; i < 2; ++i) {
        size_t need = base + szParts + (size_t)copt[i] * (NTOK * 2 + DIM * 4);
        if (need <= ws_size) { CHUNK = copt[i]; break; }
      }
    }
    const int NCHUNK = VOCAB / CHUNK;
    float* parts = (float*)(ws + base);
    char*  dyn   = ws + base + szParts;
    u16*   keyc  = (u16*)(dyn);
    u16*   veTc  = (u16*)(dyn + (size_t)CHUNK * DIM * 2);
    u16*   Pc    = (u16*)(dyn + (size_t)CHUNK * DIM * 4);

    hipMemsetAsync(parts, 0, szParts, stream);
    for (int c = 0; c < NCHUNK; ++c) {
      const int v0 = c * CHUNK;
      cvt_f32_bf16<<<CHUNK * DIM / 1024, 256, 0, stream>>>(key + (size_t)v0 * DIM, keyc);
      transpose_cvt<<<dim3(CHUNK / 64, DIM / 64), 256, 0, stream>>>(ve + (size_t)v0 * DIM, veTc,
                                                                    DIM, CHUNK);
      gemm128e<<<dim3(NTOK / 128, CHUNK / 128), 256, 0, stream>>>(qW, keyc, Pc, dpart,
                                                                  DIM, DIM / 64, CHUNK, v0 >> 7);
      gemm256acc<<<dim3(NTOK / 256, DIM / 256, KS), 512, 0, stream>>>(Pc, veTc, parts,
                                                                      CHUNK, CHUNK / 64 / KS, DIM);
    }
    denom_reduce<<<NTOK, 64, 0, stream>>>(dpart, denom, 250);
    finalize<<<NTOK, 256, 0, stream>>>(parts, denom, ve, batch, out, KS, 1.0f);
  }
}

// Round 11
// 578.907 us; speedup vs baseline: 2.0295x; 1.1480x over previous
//
#include <hip/hip_runtime.h>

// out = 0.5*ve[batch] + 0.5 * softmax((lang[batch]@W) @ keyᵀ) @ ve
// Full-P dataflow in fp8 e4m3 (inputs scaled x16, scores /256 before exp):
//   P8 = e4m3(exp(qW8 @ key8ᵀ /256)), fused row-sums; parts = P8 @ veT8ᵀ.
// 256² pipelined GEMMs: counted vmcnt, pair-interleaved K storage, quad-spread
// XOR swizzle (g=(row>>1)&3 -> conflict-free b128), split a0/a1 register sets
// (all 12 ds_reads at tile top -> reads overlap MFMA), 64 KiB LDS = 2 blk/CU.
// bf16 chunked fallback if ws_size too small.

#define DIM   1024
#define VOCAB 32000
#define NTOK  4096

typedef unsigned short u16;
typedef unsigned char  u8;
typedef long long      i64t;
typedef __attribute__((ext_vector_type(2))) long long i64x2;
typedef __attribute__((ext_vector_type(8))) __bf16 bf16x8;
typedef __attribute__((ext_vector_type(4))) float  f32x4;
typedef __attribute__((ext_vector_type(8))) u16    u16x8;
typedef __attribute__((ext_vector_type(4))) u16    u16x4;
typedef __attribute__((ext_vector_type(8))) u8     u8x8;

__device__ __forceinline__ u16 f2bf(float f) {  // round-to-nearest-even
  unsigned u = __float_as_uint(f);
  u += 0x7FFFu + ((u >> 16) & 1u);
  return (u16)(u >> 16);
}
__device__ __forceinline__ float bf2f(u16 s) {
  return __uint_as_float(((unsigned)s) << 16);
}
// f32 -> OCP e4m3 (RNE, general, for conversion kernels)
__device__ __forceinline__ u8 f2e4m3(float f) {
  unsigned u = __float_as_uint(f);
  unsigned s = (u >> 24) & 0x80u;
  int e = (int)((u >> 23) & 0xFF);
  unsigned m = u & 0x7FFFFF;
  int te = e - 127 + 7;
  if (te >= 1) {
    unsigned keep = m >> 20;
    unsigned rest = m & 0xFFFFF;
    keep += (rest > 0x80000u) || (rest == 0x80000u && (keep & 1));
    if (keep == 8) { keep = 0; te += 1; }
    return (u8)(s | ((unsigned)te << 3) | keep);
  } else {
    float q = fabsf(f) * 512.0f;
    int qi = (int)rintf(q);
    if (qi > 7) return (u8)(s | (1u << 3));
    return (u8)(s | (unsigned)qi);
  }
}
// fast e4m3 encode for e in (0.5, 2) — exp epilogue only
__device__ __forceinline__ u8 f2e4m3_exp(float e) {
  // e>=1: bits = 48 + rint(8e)  (=56 + rint((e-1)*8));  e<1: bits = 40 + rint(16e)
  float sc = (e >= 1.0f) ? 8.0f : 16.0f;
  int   bo = (e >= 1.0f) ? 48 : 40;
  return (u8)(bo + (int)rintf(e * sc));
}
// K-storage permutation within a 64-block: orig k -> pos (pair-interleave)
__device__ __forceinline__ int kperm(int k) {
  return ((k >> 3) & 3) * 16 + ((k >> 5) << 3) + (k & 7);
}

#define SB() __builtin_amdgcn_sched_barrier(0)
#define BAR() { SB(); __builtin_amdgcn_s_barrier(); SB(); }

// ---------------- conversion / gather ----------------

__global__ void cvt_f32_bf16(const float* __restrict__ in, u16* __restrict__ out) {
  size_t i = (size_t)blockIdx.x * 256 + threadIdx.x;
  float4 v = ((const float4*)in)[i];
  u16x4 o; o[0]=f2bf(v.x); o[1]=f2bf(v.y); o[2]=f2bf(v.z); o[3]=f2bf(v.w);
  ((u16x4*)out)[i] = o;
}

__global__ void gather_q(const int* __restrict__ batch, const float* __restrict__ lang,
                         u16* __restrict__ q) {
  int row = blockIdx.x;
  int src = batch[row];
  int t = threadIdx.x;
  float4 v = *(const float4*)(lang + (size_t)src * DIM + (t << 2));
  u16x4 o; o[0]=f2bf(v.x); o[1]=f2bf(v.y); o[2]=f2bf(v.z); o[3]=f2bf(v.w);
  *(u16x4*)(q + (size_t)row * DIM + (t << 2)) = o;
}

// bf16 transpose (W prologue + fallback): out[c][r] = bf16(in[r][c])
__global__ void transpose_cvt(const float* __restrict__ in, u16* __restrict__ out,
                              int ldin, int ldout) {
  __shared__ u16 t[64][66];
  int r0 = blockIdx.x << 6;
  int c0 = blockIdx.y << 6;
  int tid = threadIdx.x;
  #pragma unroll
  for (int p = 0; p < 4; ++p) {
    int r = (p << 4) + (tid >> 4);
    int c = (tid & 15) << 2;
    float4 v = *(const float4*)(in + (size_t)(r0 + r) * ldin + c0 + c);
    t[c+0][r] = f2bf(v.x);
    t[c+1][r] = f2bf(v.y);
    t[c+2][r] = f2bf(v.z);
    t[c+3][r] = f2bf(v.w);
  }
  __syncthreads();
  #pragma unroll
  for (int qq = 0; qq < 2; ++qq) {
    int rr = tid >> 2;
    int cc = (((tid & 3) << 1) + qq) << 3;
    u16x8 w;
    #pragma unroll
    for (int j = 0; j < 8; ++j) w[j] = t[rr][cc + j];
    *(u16x8*)(out + (size_t)(c0 + rr) * ldout + r0 + cc) = w;
  }
}

// key f32 -> fp8 x16, K(DIM)-permuted. one thread = 8 output bytes (one group)
__global__ void cvt_key_f8(const float* __restrict__ in, u8* __restrict__ out) {
  size_t g = (size_t)blockIdx.x * 256 + threadIdx.x;
  size_t row = g >> 7;               // DIM/8 = 128 groups per row
  int gg = (int)(g & 127);
  int b = gg >> 3, G = gg & 7;
  int O = ((G & 1) << 2) + (G >> 1); // inverse group perm
  const float* src = in + row * DIM + (b << 6) + (O << 3);
  float4 v0 = *(const float4*)src;
  float4 v1 = *(const float4*)(src + 4);
  u8x8 o;
  o[0]=f2e4m3(16.f*v0.x); o[1]=f2e4m3(16.f*v0.y); o[2]=f2e4m3(16.f*v0.z); o[3]=f2e4m3(16.f*v0.w);
  o[4]=f2e4m3(16.f*v1.x); o[5]=f2e4m3(16.f*v1.y); o[6]=f2e4m3(16.f*v1.z); o[7]=f2e4m3(16.f*v1.w);
  *(u8x8*)(out + row * DIM + (b << 6) + (G << 3)) = o;
}

// qW bf16 -> fp8 x16, K(DIM)-permuted
__global__ void cvt_qw_f8(const u16* __restrict__ in, u8* __restrict__ out) {
  size_t g = (size_t)blockIdx.x * 256 + threadIdx.x;
  size_t row = g >> 7;
  int gg = (int)(g & 127);
  int b = gg >> 3, G = gg & 7;
  int O = ((G & 1) << 2) + (G >> 1);
  u16x8 v = *(const u16x8*)(in + row * DIM + (b << 6) + (O << 3));
  u8x8 o;
  #pragma unroll
  for (int j = 0; j < 8; ++j) o[j] = f2e4m3(16.f * bf2f(v[j]));
  *(u8x8*)(out + row * DIM + (b << 6) + (G << 3)) = o;
}

// ve f32 [VOCAB][DIM] -> veT8 fp8 x16 [DIM][VOCAB], K(VOCAB)-permuted
__global__ void transpose_cvt_f8(const float* __restrict__ in, u8* __restrict__ out) {
  __shared__ float t[64][65];
  int r0 = blockIdx.x << 6;          // vocab base
  int c0 = blockIdx.y << 6;          // dim base
  int tid = threadIdx.x;
  #pragma unroll
  for (int p = 0; p < 4; ++p) {
    int r = (p << 4) + (tid >> 4);
    int c = (tid & 15) << 2;
    float4 v = *(const float4*)(in + (size_t)(r0 + r) * DIM + c0 + c);
    t[c+0][r] = v.x; t[c+1][r] = v.y; t[c+2][r] = v.z; t[c+3][r] = v.w;
  }
  __syncthreads();
  #pragma unroll
  for (int qq = 0; qq < 2; ++qq) {
    int rr = tid >> 2;                          // dim-local
    int O  = ((tid & 3) << 1) + qq;             // orig vocab group 0..7
    int cc = O << 3;
    int Gp = ((O & 3) << 1) + (O >> 2);         // stored group
    u8x8 w;
    #pragma unroll
    for (int j = 0; j < 8; ++j) w[j] = f2e4m3(16.f * t[rr][cc + j]);
    *(u8x8*)(out + (size_t)(c0 + rr) * VOCAB + r0 + (Gp << 3)) = w;
  }
}

// ---------------- small GEMM for qW: C[M,N]=A@B^T, 128x128 tile (bf16 out) ----
__global__ void gemm_qw(const u16* __restrict__ A, const u16* __restrict__ B,
                        u16* __restrict__ C, int K, int kSteps, int ldc) {
  __shared__ u16 As[128 * 32];
  __shared__ u16 Bs[128 * 32];
  const int tid  = threadIdx.x;
  const int lane = tid & 63;
  const int wid  = tid >> 6;
  const int wr   = wid >> 1, wc = wid & 1;
  const int row0 = blockIdx.x << 7;
  const int col0 = blockIdx.y << 7;

  f32x4 acc[4][4];
  #pragma unroll
  for (int m = 0; m < 4; ++m)
    #pragma unroll
    for (int n = 0; n < 4; ++n) acc[m][n] = (f32x4){0.f,0.f,0.f,0.f};

  const int sr = lane >> 2;
  const int sc = (lane & 3) << 3;

  for (int ks = 0; ks < kSteps; ++ks) {
    const int kk = ks << 5;
    #pragma unroll
    for (int t = 0; t < 2; ++t) {
      const int i = wid * 2 + t;
      const u16* gA = A + (size_t)(row0 + (i << 4) + sr) * K + kk + sc;
      const u16* gB = B + (size_t)(col0 + (i << 4) + sr) * K + kk + sc;
      __builtin_amdgcn_global_load_lds((const __attribute__((address_space(1))) void*)gA,
                                       (__attribute__((address_space(3))) void*)(As + i * 512),
                                       16, 0, 0);
      __builtin_amdgcn_global_load_lds((const __attribute__((address_space(1))) void*)gB,
                                       (__attribute__((address_space(3))) void*)(Bs + i * 512),
                                       16, 0, 0);
    }
    __syncthreads();
    bf16x8 a[4], b[4];
    #pragma unroll
    for (int m = 0; m < 4; ++m)
      a[m] = *(const bf16x8*)(As + ((wr << 6) + (m << 4) + (lane & 15)) * 32 + ((lane >> 4) << 3));
    #pragma unroll
    for (int n = 0; n < 4; ++n)
      b[n] = *(const bf16x8*)(Bs + ((wc << 6) + (n << 4) + (lane & 15)) * 32 + ((lane >> 4) << 3));
    #pragma unroll
    for (int m = 0; m < 4; ++m)
      #pragma unroll
      for (int n = 0; n < 4; ++n)
        acc[m][n] = __builtin_amdgcn_mfma_f32_16x16x32_bf16(a[m], b[n], acc[m][n], 0, 0, 0);
    __syncthreads();
  }

  const int r0 = row0 + (wr << 6);
  const int c0 = col0 + (wc << 6);
  const int fq = (lane >> 4) << 2;
  const int fr = lane & 15;
  #pragma unroll
  for (int m = 0; m < 4; ++m)
    #pragma unroll
    for (int n = 0; n < 4; ++n) {
      int col = c0 + (n << 4) + fr;
      #pragma unroll
      for (int j = 0; j < 4; ++j) {
        int row = r0 + (m << 4) + fq + j;
        C[(size_t)row * ldc + col] = f2bf(acc[m][n][j]);
      }
    }
}

// ---------------- fp8 256² K-loop (BK=64 bytes, 2 bufs = 64 KiB) --------------
// quad-spread swizzle: phys slot of fragment j in row r = j ^ ((r>>1)&3)
#define STGF8(d, kk)                                                               \
  {                                                                                \
    _Pragma("unroll")                                                              \
    for (int c = 0; c < 2; ++c) {                                                  \
      const int ra = (tid >> 2) + (c << 7);                                        \
      const u8* gA = A + (size_t)(row0 + ra) * Kb + (kk) +                         \
                     (((tid & 3) ^ ((ra >> 1) & 3)) << 4);                         \
      __builtin_amdgcn_global_load_lds(                                            \
          (const __attribute__((address_space(1))) void*)gA,                       \
          (__attribute__((address_space(3))) void*)(lds + (d) * 32768 + (c << 13) + tid * 16), \
          16, 0, 0);                                                               \
    }                                                                              \
    _Pragma("unroll")                                                              \
    for (int c = 0; c < 2; ++c) {                                                  \
      const int rn = (tid >> 2) + (c << 7);                                        \
      const u8* gB = B + (size_t)(col0 + rn) * Kb + (kk) +                         \
                     (((tid & 3) ^ ((rn >> 1) & 3)) << 4);                         \
      __builtin_amdgcn_global_load_lds(                                            \
          (const __attribute__((address_space(1))) void*)gB,                       \
          (__attribute__((address_space(3))) void*)(lds + (d) * 32768 + 16384 + (c << 13) + tid * 16), \
          16, 0, 0);                                                               \
    }                                                                              \
  }

// all 12 ds_reads at tile top into SEPARATE reg sets (a0/a1) -> no WAR hazard,
// mh=0 MFMAs cover a1 latency; waves desync so LDS port overlaps MFMA pipe.
#define KLOOPF8(NT, KB)                                                            \
  STGF8(0, (KB))                                                                   \
  STGF8(1, (KB) + 64)                                                              \
  for (int t = 0; t < (NT); ++t) {                                                 \
    const int d = t & 1;                                                           \
    const u8* Abuf = lds + d * 32768;                                              \
    const u8* Bbuf = Abuf + 16384;                                                 \
    SB();                                                                          \
    if (t + 1 < (NT)) { asm volatile("s_waitcnt vmcnt(4)"); }                      \
    else              { asm volatile("s_waitcnt vmcnt(0)"); }                      \
    BAR();                                                                         \
    _Pragma("unroll")                                                              \
    for (int nh = 0; nh < 2; ++nh)                                                 \
      _Pragma("unroll")                                                            \
      for (int nq = 0; nq < 2; ++nq) {                                             \
        const int row = (wc << 6) + (nh << 5) + (nq << 4) + fr;                    \
        i64x2 v = *(const i64x2*)(Bbuf + row * 64 + ((fq ^ ((row >> 1) & 3)) << 4)); \
        b[nh][nq][0] = v[0]; b[nh][nq][1] = v[1];                                  \
      }                                                                            \
    _Pragma("unroll")                                                              \
    for (int mq = 0; mq < 4; ++mq) {                                               \
      const int row = (wr << 7) + (mq << 4) + fr;                                  \
      i64x2 v = *(const i64x2*)(Abuf + row * 64 + ((fq ^ ((row >> 1) & 3)) << 4)); \
      a0[mq][0] = v[0]; a0[mq][1] = v[1];                                          \
    }                                                                              \
    _Pragma("unroll")                                                              \
    for (int mq = 0; mq < 4; ++mq) {                                               \
      const int row = (wr << 7) + 64 + (mq << 4) + fr;                             \
      i64x2 v = *(const i64x2*)(Abuf + row * 64 + ((fq ^ ((row >> 1) & 3)) << 4)); \
      a1[mq][0] = v[0]; a1[mq][1] = v[1];                                          \
    }                                                                              \
    __builtin_amdgcn_s_setprio(1);                                                 \
    _Pragma("unroll")                                                              \
    for (int mq = 0; mq < 4; ++mq)                                                 \
      _Pragma("unroll")                                                            \
      for (int nh = 0; nh < 2; ++nh)                                               \
        _Pragma("unroll")                                                          \
        for (int nq = 0; nq < 2; ++nq)                                             \
          _Pragma("unroll")                                                        \
          for (int ks = 0; ks < 2; ++ks)                                           \
            acc[mq][(nh << 1) + nq] =                                              \
                __builtin_amdgcn_mfma_f32_16x16x32_fp8_fp8(                        \
                    a0[mq][ks], b[nh][nq][ks], acc[mq][(nh << 1) + nq], 0, 0, 0);  \
    _Pragma("unroll")                                                              \
    for (int mq = 0; mq < 4; ++mq)                                                 \
      _Pragma("unroll")                                                            \
      for (int nh = 0; nh < 2; ++nh)                                               \
        _Pragma("unroll")                                                          \
        for (int nq = 0; nq < 2; ++nq)                                             \
          _Pragma("unroll")                                                        \
          for (int ks = 0; ks < 2; ++ks)                                           \
            acc[4 + mq][(nh << 1) + nq] =                                          \
                __builtin_amdgcn_mfma_f32_16x16x32_fp8_fp8(                        \
                    a1[mq][ks], b[nh][nq][ks], acc[4 + mq][(nh << 1) + nq], 0, 0, 0); \
    __builtin_amdgcn_s_setprio(0);                                                 \
    BAR();                                                                         \
    if (t + 2 < (NT)) STGF8(d, (KB) + ((t + 2) << 6))                              \
  }

// ---------------- fp8 exp-GEMM: P8 = e4m3(exp(acc/256)), fused rowsum ---------
__global__ __launch_bounds__(512, 2) void gemm256e8(const u8* __restrict__ A,
                                                    const u8* __restrict__ B,
                                                    u8* __restrict__ P,
                                                    float* __restrict__ dpart,
                                                    int Kb, int nTiles) {
  __shared__ __align__(16) u8 lds[65536];
  const int tid  = threadIdx.x;
  const int lane = tid & 63;
  const int wid  = tid >> 6;
  const int wr   = wid >> 2;
  const int wc   = wid & 3;

  const int nwg = (int)(gridDim.x * gridDim.y);
  int lin = blockIdx.y * gridDim.x + blockIdx.x;
  { const int cpx = nwg >> 3; lin = (lin & 7) * cpx + (lin >> 3); }
  const int row0 = (lin & 15) << 8;    // gridDim.x == 16
  const int cblk = lin >> 4;
  const int col0 = cblk << 8;

  const int fr = lane & 15;
  const int fq = lane >> 4;

  f32x4 acc[8][4];
  #pragma unroll
  for (int m = 0; m < 8; ++m)
    #pragma unroll
    for (int n = 0; n < 4; ++n) acc[m][n] = (f32x4){0.f, 0.f, 0.f, 0.f};

  i64t a0[4][2], a1[4][2], b[2][2][2];

  KLOOPF8(nTiles, 0)

  // epilogue: P8 = e4m3(exp(acc/256)) at K-permuted cols; fused row-sums
  const float inv256 = 1.0f / 256.0f;
  float rs[32];
  #pragma unroll
  for (int i = 0; i < 32; ++i) rs[i] = 0.f;
  #pragma unroll
  for (int m = 0; m < 8; ++m)
    #pragma unroll
    for (int n = 0; n < 4; ++n) {
      const int l6  = (n << 4) + fr;
      const int col = col0 + (wc << 6) + kperm(l6);
      #pragma unroll
      for (int j = 0; j < 4; ++j) {
        const int row = row0 + (wr << 7) + (m << 4) + (fq << 2) + j;
        float e = __expf(acc[m][n][j] * inv256);
        P[(size_t)row * VOCAB + col] = f2e4m3_exp(e);
        rs[(m << 2) + j] += e;
      }
    }
  #pragma unroll
  for (int i = 0; i < 32; ++i) {
    #pragma unroll
    for (int s = 8; s >= 1; s >>= 1) rs[i] += __shfl_xor(rs[i], s, 16);
  }
  __syncthreads();
  float* dsm = (float*)lds;
  if (fr == 0) {
    #pragma unroll
    for (int m = 0; m < 8; ++m)
      #pragma unroll
      for (int j = 0; j < 4; ++j)
        dsm[(wc << 8) + (wr << 7) + (m << 4) + (fq << 2) + j] = rs[(m << 2) + j];
  }
  __syncthreads();
  if (tid < 256)
    dpart[(size_t)(row0 + tid) * 256 + cblk] =
        dsm[tid] + dsm[256 + tid] + dsm[512 + tid] + dsm[768 + tid];
}

// ---------------- fp8 PV GEMM: parts[z] = P8 @ veT8ᵀ (uneven split-K=8) -------
__global__ __launch_bounds__(512, 2) void gemm256p8(const u8* __restrict__ A,
                                                    const u8* __restrict__ B,
                                                    float* __restrict__ Cout,
                                                    int Kb) {
  __shared__ __align__(16) u8 lds[65536];
  const int tid  = threadIdx.x;
  const int lane = tid & 63;
  const int wid  = tid >> 6;
  const int wr   = wid >> 2;
  const int wc   = wid & 3;

  const int nwg = (int)(gridDim.x * gridDim.y);
  int lin = blockIdx.y * gridDim.x + blockIdx.x;
  { const int cpx = nwg >> 3; lin = (lin & 7) * cpx + (lin >> 3); }
  const int row0 = (lin & 15) << 8;    // gridDim.x == 16
  const int col0 = (lin >> 4) << 8;

  const int z = blockIdx.z;            // 0..7 ; 500 tiles = 4x63 + 4x62
  const int nT = (z < 4) ? 63 : 62;
  const int kb = ((z * 62 + ((z < 4) ? z : 4)) << 6);

  const int fr = lane & 15;
  const int fq = lane >> 4;

  f32x4 acc[8][4];
  #pragma unroll
  for (int m = 0; m < 8; ++m)
    #pragma unroll
    for (int n = 0; n < 4; ++n) acc[m][n] = (f32x4){0.f, 0.f, 0.f, 0.f};

  i64t a0[4][2], a1[4][2], b[2][2][2];

  KLOOPF8(nT, kb)

  float* C = Cout + (size_t)z * NTOK * DIM;
  #pragma unroll
  for (int m = 0; m < 8; ++m)
    #pragma unroll
    for (int n = 0; n < 4; ++n) {
      const int col = col0 + (wc << 6) + (n << 4) + fr;
      #pragma unroll
      for (int j = 0; j < 4; ++j) {
        const int row = row0 + (wr << 7) + (m << 4) + (fq << 2) + j;
        C[(size_t)row * DIM + col] = acc[m][n][j];
      }
    }
}

// ---------------- bf16 128² exp-GEMM + bf16 256² PV (chunked fallback) --------
__global__ __launch_bounds__(256, 2) void gemm128e(const u16* __restrict__ A,
                                                   const u16* __restrict__ B,
                                                   u16* __restrict__ P,
                                                   float* __restrict__ dpart,
                                                   int K, int nTiles, int ldc, int cb0) {
  __shared__ __align__(16) u16 lds[32768];
  const int tid  = threadIdx.x;
  const int lane = tid & 63;
  const int wid  = tid >> 6;
  const int wr   = wid >> 1;
  const int wc   = wid & 1;

  const int nwg = (int)(gridDim.x * gridDim.y);
  int lin = blockIdx.y * gridDim.x + blockIdx.x;
  { const int cpx = nwg >> 3; lin = (lin & 7) * cpx + (lin >> 3); }
  const int row0 = (lin & 31) << 7;
  const int cblk = lin >> 5;
  const int col0 = cblk << 7;

  const int fr = lane & 15;
  const int fq = lane >> 4;
  const int rb = tid >> 3;
  const int ss = tid & 7;

#define STG128(d, kk)                                                              \
  {                                                                                \
    _Pragma("unroll")                                                              \
    for (int c = 0; c < 4; ++c) {                                                  \
      const int ra = (c << 5) + rb;                                                \
      const u16* gA = A + (size_t)(row0 + ra) * K + (kk) + ((ss ^ (ra & 7)) << 3); \
      __builtin_amdgcn_global_load_lds(                                            \
          (const __attribute__((address_space(1))) void*)gA,                       \
          (__attribute__((address_space(3))) void*)(lds + (d) * 16384 + (((c << 5) + (wid << 3)) << 6)), \
          16, 0, 0);                                                               \
    }                                                                              \
    _Pragma("unroll")                                                              \
    for (int c = 0; c < 4; ++c) {                                                  \
      const int rn = (c << 5) + rb;                                                \
      const u16* gB = B + (size_t)(col0 + rn) * K + (kk) + ((ss ^ (rn & 7)) << 3); \
      __builtin_amdgcn_global_load_lds(                                            \
          (const __attribute__((address_space(1))) void*)gB,                       \
          (__attribute__((address_space(3))) void*)(lds + (d) * 16384 + 8192 + (((c << 5) + (wid << 3)) << 6)), \
          16, 0, 0);                                                               \
    }                                                                              \
  }

  f32x4 acc[4][4];
  #pragma unroll
  for (int m = 0; m < 4; ++m)
    #pragma unroll
    for (int n = 0; n < 4; ++n) acc[m][n] = (f32x4){0.f, 0.f, 0.f, 0.f};

  STG128(0, 0)
  STG128(1, 64)

  bf16x8 a[4], b[4];

  for (int t = 0; t < nTiles; ++t) {
    const int d = t & 1;
    const u16* Abuf = lds + d * 16384;
    const u16* Bbuf = Abuf + 8192;
    SB();
    if (t + 1 < nTiles) { asm volatile("s_waitcnt vmcnt(8)"); }
    else                { asm volatile("s_waitcnt vmcnt(0)"); }
    BAR();

    #pragma unroll
    for (int ks = 0; ks < 2; ++ks) {
      #pragma unroll
      for (int mq = 0; mq < 4; ++mq) {
        const int row  = (wr << 6) + (mq << 4) + fr;
        const int slot = ((ks << 2) + fq) ^ (row & 7);
        a[mq] = *(const bf16x8*)(Abuf + (row << 6) + (slot << 3));
      }
      #pragma unroll
      for (int nq = 0; nq < 4; ++nq) {
        const int row  = (wc << 6) + (nq << 4) + fr;
        const int slot = ((ks << 2) + fq) ^ (row & 7);
        b[nq] = *(const bf16x8*)(Bbuf + (row << 6) + (slot << 3));
      }
      __builtin_amdgcn_s_setprio(1);
      #pragma unroll
      for (int mq = 0; mq < 4; ++mq)
        #pragma unroll
        for (int nq = 0; nq < 4; ++nq)
          acc[mq][nq] = __builtin_amdgcn_mfma_f32_16x16x32_bf16(
              a[mq], b[nq], acc[mq][nq], 0, 0, 0);
      __builtin_amdgcn_s_setprio(0);
    }
    BAR();
    if (t + 2 < nTiles) STG128(d, (t + 2) << 6)
  }
#undef STG128

  float rs[16];
  #pragma unroll
  for (int i = 0; i < 16; ++i) rs[i] = 0.f;
  #pragma unroll
  for (int mq = 0; mq < 4; ++mq)
    #pragma unroll
    for (int nq = 0; nq < 4; ++nq) {
      const int col = col0 + (wc << 6) + (nq << 4) + fr;
      #pragma unroll
      for (int j = 0; j < 4; ++j) {
        const int row = row0 + (wr << 6) + (mq << 4) + (fq << 2) + j;
        float e = __expf(acc[mq][nq][j]);
        P[(size_t)row * ldc + col] = f2bf(e);
        rs[(mq << 2) + j] += e;
      }
    }
  #pragma unroll
  for (int i = 0; i < 16; ++i) {
    #pragma unroll
    for (int s = 8; s >= 1; s >>= 1) rs[i] += __shfl_xor(rs[i], s, 16);
  }
  __syncthreads();
  float* dsm = (float*)lds;
  if (fr == 0) {
    #pragma unroll
    for (int mq = 0; mq < 4; ++mq)
      #pragma unroll
      for (int j = 0; j < 4; ++j)
        dsm[(wc << 7) + (wr << 6) + (mq << 4) + (fq << 2) + j] = rs[(mq << 2) + j];
  }
  __syncthreads();
  if (tid < 128)
    dpart[(size_t)(row0 + tid) * 256 + cb0 + cblk] = dsm[tid] + dsm[128 + tid];
}

#define STG256(d, kk)                                                              \
  {                                                                                \
    _Pragma("unroll")                                                              \
    for (int c = 0; c < 4; ++c) {                                                  \
      const int ra = (c << 6) + rb;                                                \
      const u16* gA = A + (size_t)(row0 + ra) * K + (kk) + ((ss ^ (ra & 7)) << 3); \
      __builtin_amdgcn_global_load_lds(                                            \
          (const __attribute__((address_space(1))) void*)gA,                       \
          (__attribute__((address_space(3))) void*)(lds + (d) * 32768 + (((c << 6) + (wid << 3)) << 6)), \
          16, 0, 0);                                                               \
    }                                                                              \
    _Pragma("unroll")                                                              \
    for (int c = 0; c < 4; ++c) {                                                  \
      const int rn = (c << 6) + rb;                                                \
      const u16* gB = B + (size_t)(col0 + rn) * K + (kk) + ((ss ^ (rn & 7)) << 3); \
      __builtin_amdgcn_global_load_lds(                                            \
          (const __attribute__((address_space(1))) void*)gB,                       \
          (__attribute__((address_space(3))) void*)(lds + (d) * 32768 + 16384 + (((c << 6) + (wid << 3)) << 6)), \
          16, 0, 0);                                                               \
    }                                                                              \
  }

// bf16 256² PV for fallback (+= into parts slice)
__global__ __launch_bounds__(512, 2) void gemm256acc(const u16* __restrict__ A,
                                                     const u16* __restrict__ B,
                                                     float* __restrict__ Cout,
                                                     int K, int nTiles, int ldc) {
  __shared__ __align__(16) u16 lds[65536];
  const int tid  = threadIdx.x;
  const int lane = tid & 63;
  const int wid  = tid >> 6;
  const int wr   = wid >> 2;
  const int wc   = wid & 3;

  const int nwg = (int)(gridDim.x * gridDim.y);
  int lin = blockIdx.y * gridDim.x + blockIdx.x;
  { const int cpx = nwg >> 3; lin = (lin & 7) * cpx + (lin >> 3); }
  const int row0 = (lin & 15) << 8;
  const int col0 = (lin >> 4) << 8;

  const int kbase = blockIdx.z * (nTiles << 6);
  const int fr = lane & 15;
  const int fq = lane >> 4;
  const int rb = tid >> 3;
  const int ss = tid & 7;

  f32x4 acc[8][4];
  #pragma unroll
  for (int m = 0; m < 8; ++m)
    #pragma unroll
    for (int n = 0; n < 4; ++n) acc[m][n] = (f32x4){0.f, 0.f, 0.f, 0.f};

  bf16x8 a[4][2], b[2][2][2];

  STG256(0, kbase)
  STG256(1, kbase + 64)
  for (int t = 0; t < nTiles; ++t) {
    const int d = t & 1;
    const u16* Abuf = lds + d * 32768;
    const u16* Bbuf = Abuf + 16384;
    SB();
    if (t + 1 < nTiles) { asm volatile("s_waitcnt vmcnt(8)"); }
    else                { asm volatile("s_waitcnt vmcnt(0)"); }
    BAR();
    #pragma unroll
    for (int nh = 0; nh < 2; ++nh)
      #pragma unroll
      for (int nq = 0; nq < 2; ++nq)
        #pragma unroll
        for (int ks = 0; ks < 2; ++ks) {
          const int row  = (wc << 6) + (nh << 5) + (nq << 4) + fr;
          const int slot = ((ks << 2) + fq) ^ (row & 7);
          b[nh][nq][ks] = *(const bf16x8*)(Bbuf + (row << 6) + (slot << 3));
        }
    #pragma unroll
    for (int mh = 0; mh < 2; ++mh) {
      #pragma unroll
      for (int mq = 0; mq < 4; ++mq)
        #pragma unroll
        for (int ks = 0; ks < 2; ++ks) {
          const int row  = (wr << 7) + (mh << 6) + (mq << 4) + fr;
          const int slot = ((ks << 2) + fq) ^ (row & 7);
          a[mq][ks] = *(const bf16x8*)(Abuf + (row << 6) + (slot << 3));
        }
      __builtin_amdgcn_s_setprio(1);
      #pragma unroll
      for (int mq = 0; mq < 4; ++mq)
        #pragma unroll
        for (int nh = 0; nh < 2; ++nh)
          #pragma unroll
          for (int nq = 0; nq < 2; ++nq)
            #pragma unroll
            for (int ks = 0; ks < 2; ++ks)
              acc[(mh << 2) + mq][(nh << 1) + nq] =
                  __builtin_amdgcn_mfma_f32_16x16x32_bf16(
                      a[mq][ks], b[nh][nq][ks], acc[(mh << 2) + mq][(nh << 1) + nq], 0, 0, 0);
      __builtin_amdgcn_s_setprio(0);
    }
    BAR();
    if (t + 2 < nTiles) STG256(d, kbase + ((t + 2) << 6))
  }

  float* C = Cout + (size_t)blockIdx.z * NTOK * DIM;
  #pragma unroll
  for (int m = 0; m < 8; ++m)
    #pragma unroll
    for (int n = 0; n < 4; ++n) {
      const int col = col0 + (wc << 6) + (n << 4) + fr;
      #pragma unroll
      for (int j = 0; j < 4; ++j) {
        const int row = row0 + (wr << 7) + (m << 4) + (fq << 2) + j;
        C[(size_t)row * ldc + col] += acc[m][n][j];
      }
    }
}

// ---------------- denom reduce ----------------
__global__ void denom_reduce(const float* __restrict__ dpart, float* __restrict__ denom,
                             int npart) {
  int row = blockIdx.x;
  int l = threadIdx.x;              // 64
  float s = 0.f;
  #pragma unroll
  for (int k = 0; k < 4; ++k) {
    int idx = l + (k << 6);
    if (idx < npart) s += dpart[(size_t)row * 256 + idx];
  }
  #pragma unroll
  for (int off = 32; off >= 1; off >>= 1) s += __shfl_down(s, off, 64);
  if (l == 0) denom[row] = s;
}

// ---------------- finalize ----------------
__global__ void finalize(const float* __restrict__ parts, const float* __restrict__ denom,
                         const float* __restrict__ ve, const int* __restrict__ batch,
                         float* __restrict__ out, int nks, float pvInv) {
  int row = blockIdx.x;
  int t = threadIdx.x;
  float inv = 0.5f * pvInv / denom[row];
  float4 a = *(const float4*)(ve + (size_t)batch[row] * DIM + (t << 2));
  float sx = 0.f, sy = 0.f, sz = 0.f, sw = 0.f;
  for (int ks = 0; ks < nks; ++ks) {
    float4 pv = *(const float4*)(parts + ((size_t)ks * NTOK + row) * DIM + (t << 2));
    sx += pv.x; sy += pv.y; sz += pv.z; sw += pv.w;
  }
  float4 o;
  o.x = 0.5f * a.x + inv * sx;
  o.y = 0.5f * a.y + inv * sy;
  o.z = 0.5f * a.z + inv * sz;
  o.w = 0.5f * a.w + inv * sw;
  *(float4*)(out + (size_t)row * DIM + (t << 2)) = o;
}

// ---------------- launch ----------------
extern "C" void kernel_launch(void* const* d_in, const int* in_sizes, int n_in,
                              void* d_out, int out_size, void* d_ws, size_t ws_size,
                              hipStream_t stream) {
  const int*   batch = (const int*)d_in[0];
  const float* lang  = (const float*)d_in[1];
  const float* key   = (const float*)d_in[2];
  const float* ve    = (const float*)d_in[3];
  const float* W     = (const float*)d_in[4];
  float* out = (float*)d_out;

  const size_t szWt    = (size_t)DIM * DIM * 2;
  const size_t szQb    = (size_t)NTOK * DIM * 2;
  const size_t szQW    = (size_t)NTOK * DIM * 2;
  const size_t szDpart = (size_t)NTOK * 256 * 4;
  const size_t szDenom = (size_t)NTOK * 4;
  const size_t base    = szWt + szQb + szQW + szDpart + szDenom;

  char* ws = (char*)d_ws;
  u16*   Wt    = (u16*)(ws);
  u16*   qb    = (u16*)(ws + szWt);
  u16*   qW    = (u16*)(ws + szWt + szQb);
  float* dpart = (float*)(ws + szWt + szQb + szQW);
  float* denom = (float*)(ws + szWt + szQb + szQW + szDpart);

  const int KSF = 8;
  const size_t szPartsF = (size_t)KSF * NTOK * DIM * 4;     // 134 MB
  const size_t szQW8    = (size_t)NTOK * DIM;               //   4 MB
  const size_t szKey8   = (size_t)VOCAB * DIM;              //  33 MB
  const size_t szVeT8   = (size_t)DIM * VOCAB;              //  33 MB
  const size_t szP8     = (size_t)NTOK * VOCAB;             // 131 MB
  const bool fullP = (base + szPartsF + szQW8 + szKey8 + szVeT8 + szP8) <= ws_size;

  transpose_cvt<<<dim3(DIM / 64, DIM / 64), 256, 0, stream>>>(W, Wt, DIM, DIM);
  gather_q<<<NTOK, 256, 0, stream>>>(batch, lang, qb);
  gemm_qw<<<dim3(NTOK / 128, DIM / 128), 256, 0, stream>>>(qb, Wt, qW, DIM, DIM / 32, DIM);

  if (fullP) {
    float* parts = (float*)(ws + base);
    u8*    qW8   = (u8*)(ws + base + szPartsF);
    u8*    key8  = (u8*)(ws + base + szPartsF + szQW8);
    u8*    veT8  = (u8*)(ws + base + szPartsF + szQW8 + szKey8);
    u8*    P8    = (u8*)(ws + base + szPartsF + szQW8 + szKey8 + szVeT8);

    cvt_qw_f8<<<NTOK * DIM / 8 / 256, 256, 0, stream>>>(qW, qW8);
    cvt_key_f8<<<VOCAB * DIM / 8 / 256, 256, 0, stream>>>(key, key8);
    transpose_cvt_f8<<<dim3(VOCAB / 64, DIM / 64), 256, 0, stream>>>(ve, veT8);

    // P8 = e4m3(exp(qW8 @ key8ᵀ / 256)), fused row-sum partials
    gemm256e8<<<dim3(NTOK / 256, VOCAB / 256), 512, 0, stream>>>(qW8, key8, P8, dpart,
                                                                 DIM, DIM / 64);
    denom_reduce<<<NTOK, 64, 0, stream>>>(dpart, denom, VOCAB / 256);
    // parts[z] = P8 @ veT8ᵀ (uneven split-K = 8, 512 blocks = 2/CU)
    gemm256p8<<<dim3(NTOK / 256, DIM / 256, KSF), 512, 0, stream>>>(P8, veT8, parts, VOCAB);
    finalize<<<NTOK, 256, 0, stream>>>(parts, denom, ve, batch, out, KSF, 1.0f / 16.0f);
  } else {
    // bf16 chunked fallback (proven path)
    const int KS = 2;
    const size_t szParts = (size_t)KS * NTOK * DIM * 4;
    int CHUNK = 1280;
    {
      const int copt[2] = {6400, 1280};
      for (int i = 0; i < 2; ++i) {
        size_t need = base + szParts + (size_t)copt[i] * (NTOK * 2 + DIM * 4);
        if (need <= ws_size) { CHUNK = copt[i]; break; }
      }
    }
    const int NCHUNK = VOCAB / CHUNK;
    float* parts = (float*)(ws + base);
    char*  dyn   = ws + base + szParts;
    u16*   keyc  = (u16*)(dyn);
    u16*   veTc  = (u16*)(dyn + (size_t)CHUNK * DIM * 2);
    u16*   Pc    = (u16*)(dyn + (size_t)CHUNK * DIM * 4);

    hipMemsetAsync(parts, 0, szParts, stream);
    for (int c = 0; c < NCHUNK; ++c) {
      const int v0 = c * CHUNK;
      cvt_f32_bf16<<<CHUNK * DIM / 1024, 256, 0, stream>>>(key + (size_t)v0 * DIM, keyc);
      transpose_cvt<<<dim3(CHUNK / 64, DIM / 64), 256, 0, stream>>>(ve + (size_t)v0 * DIM, veTc,
                                                                    DIM, CHUNK);
      gemm128e<<<dim3(NTOK / 128, CHUNK / 128), 256, 0, stream>>>(qW, keyc, Pc, dpart,
                                                                  DIM, DIM / 64, CHUNK, v0 >> 7);
      gemm256acc<<<dim3(NTOK / 256, DIM / 256, KS), 512, 0, stream>>>(Pc, veTc, parts,
                                                                      CHUNK, CHUNK / 64 / KS, DIM);
    }
    denom_reduce<<<NTOK, 64, 0, stream>>>(dpart, denom, 250);
    finalize<<<NTOK, 256, 0, stream>>>(parts, denom, ve, batch, out, KS, 1.0f);
  }
}

// Round 12
// 566.751 us; speedup vs baseline: 2.0730x; 1.0214x over previous
//
#include <hip/hip_runtime.h>

// out = 0.5*ve[batch] + 0.5 * softmax((lang[batch]@W) @ keyᵀ) @ ve
// Full-P dataflow in fp8 e4m3 (inputs scaled x16, scores /256 before exp):
//   P8 = e4m3(exp(qW8 @ key8ᵀ /256)), fused row-sums; parts = P8 @ veT8ᵀ.
// 256² pipelined GEMMs: 4-slot LDS rotation (128 KiB), ONE barrier per K-tile,
// counted vmcnt(12) (3 tiles in flight), pair-interleaved K storage,
// quad-spread XOR swizzle (conflict-free b128), split a0/a1 register sets.
// bf16 chunked fallback if ws_size too small.

#define DIM   1024
#define VOCAB 32000
#define NTOK  4096

typedef unsigned short u16;
typedef unsigned char  u8;
typedef long long      i64t;
typedef __attribute__((ext_vector_type(2))) long long i64x2;
typedef __attribute__((ext_vector_type(8))) __bf16 bf16x8;
typedef __attribute__((ext_vector_type(4))) float  f32x4;
typedef __attribute__((ext_vector_type(8))) u16    u16x8;
typedef __attribute__((ext_vector_type(4))) u16    u16x4;
typedef __attribute__((ext_vector_type(8))) u8     u8x8;

__device__ __forceinline__ u16 f2bf(float f) {  // round-to-nearest-even
  unsigned u = __float_as_uint(f);
  u += 0x7FFFu + ((u >> 16) & 1u);
  return (u16)(u >> 16);
}
__device__ __forceinline__ float bf2f(u16 s) {
  return __uint_as_float(((unsigned)s) << 16);
}
// f32 -> OCP e4m3 (RNE, general, for conversion kernels)
__device__ __forceinline__ u8 f2e4m3(float f) {
  unsigned u = __float_as_uint(f);
  unsigned s = (u >> 24) & 0x80u;
  int e = (int)((u >> 23) & 0xFF);
  unsigned m = u & 0x7FFFFF;
  int te = e - 127 + 7;
  if (te >= 1) {
    unsigned keep = m >> 20;
    unsigned rest = m & 0xFFFFF;
    keep += (rest > 0x80000u) || (rest == 0x80000u && (keep & 1));
    if (keep == 8) { keep = 0; te += 1; }
    return (u8)(s | ((unsigned)te << 3) | keep);
  } else {
    float q = fabsf(f) * 512.0f;
    int qi = (int)rintf(q);
    if (qi > 7) return (u8)(s | (1u << 3));
    return (u8)(s | (unsigned)qi);
  }
}
// fast e4m3 encode for e in (0.5, 2) — exp epilogue only
__device__ __forceinline__ u8 f2e4m3_exp(float e) {
  float sc = (e >= 1.0f) ? 8.0f : 16.0f;
  int   bo = (e >= 1.0f) ? 48 : 40;
  return (u8)(bo + (int)rintf(e * sc));
}
// K-storage permutation within a 64-block: orig k -> pos (pair-interleave)
__device__ __forceinline__ int kperm(int k) {
  return ((k >> 3) & 3) * 16 + ((k >> 5) << 3) + (k & 7);
}

#define SB() __builtin_amdgcn_sched_barrier(0)
#define BAR() { SB(); __builtin_amdgcn_s_barrier(); SB(); }

// ---------------- conversion / gather ----------------

__global__ void cvt_f32_bf16(const float* __restrict__ in, u16* __restrict__ out) {
  size_t i = (size_t)blockIdx.x * 256 + threadIdx.x;
  float4 v = ((const float4*)in)[i];
  u16x4 o; o[0]=f2bf(v.x); o[1]=f2bf(v.y); o[2]=f2bf(v.z); o[3]=f2bf(v.w);
  ((u16x4*)out)[i] = o;
}

__global__ void gather_q(const int* __restrict__ batch, const float* __restrict__ lang,
                         u16* __restrict__ q) {
  int row = blockIdx.x;
  int src = batch[row];
  int t = threadIdx.x;
  float4 v = *(const float4*)(lang + (size_t)src * DIM + (t << 2));
  u16x4 o; o[0]=f2bf(v.x); o[1]=f2bf(v.y); o[2]=f2bf(v.z); o[3]=f2bf(v.w);
  *(u16x4*)(q + (size_t)row * DIM + (t << 2)) = o;
}

// bf16 transpose (W prologue + fallback): out[c][r] = bf16(in[r][c])
__global__ void transpose_cvt(const float* __restrict__ in, u16* __restrict__ out,
                              int ldin, int ldout) {
  __shared__ u16 t[64][66];
  int r0 = blockIdx.x << 6;
  int c0 = blockIdx.y << 6;
  int tid = threadIdx.x;
  #pragma unroll
  for (int p = 0; p < 4; ++p) {
    int r = (p << 4) + (tid >> 4);
    int c = (tid & 15) << 2;
    float4 v = *(const float4*)(in + (size_t)(r0 + r) * ldin + c0 + c);
    t[c+0][r] = f2bf(v.x);
    t[c+1][r] = f2bf(v.y);
    t[c+2][r] = f2bf(v.z);
    t[c+3][r] = f2bf(v.w);
  }
  __syncthreads();
  #pragma unroll
  for (int qq = 0; qq < 2; ++qq) {
    int rr = tid >> 2;
    int cc = (((tid & 3) << 1) + qq) << 3;
    u16x8 w;
    #pragma unroll
    for (int j = 0; j < 8; ++j) w[j] = t[rr][cc + j];
    *(u16x8*)(out + (size_t)(c0 + rr) * ldout + r0 + cc) = w;
  }
}

// key f32 -> fp8 x16, K(DIM)-permuted. one thread = 8 output bytes (one group)
__global__ void cvt_key_f8(const float* __restrict__ in, u8* __restrict__ out) {
  size_t g = (size_t)blockIdx.x * 256 + threadIdx.x;
  size_t row = g >> 7;               // DIM/8 = 128 groups per row
  int gg = (int)(g & 127);
  int b = gg >> 3, G = gg & 7;
  int O = ((G & 1) << 2) + (G >> 1); // inverse group perm
  const float* src = in + row * DIM + (b << 6) + (O << 3);
  float4 v0 = *(const float4*)src;
  float4 v1 = *(const float4*)(src + 4);
  u8x8 o;
  o[0]=f2e4m3(16.f*v0.x); o[1]=f2e4m3(16.f*v0.y); o[2]=f2e4m3(16.f*v0.z); o[3]=f2e4m3(16.f*v0.w);
  o[4]=f2e4m3(16.f*v1.x); o[5]=f2e4m3(16.f*v1.y); o[6]=f2e4m3(16.f*v1.z); o[7]=f2e4m3(16.f*v1.w);
  *(u8x8*)(out + row * DIM + (b << 6) + (G << 3)) = o;
}

// qW bf16 -> fp8 x16, K(DIM)-permuted
__global__ void cvt_qw_f8(const u16* __restrict__ in, u8* __restrict__ out) {
  size_t g = (size_t)blockIdx.x * 256 + threadIdx.x;
  size_t row = g >> 7;
  int gg = (int)(g & 127);
  int b = gg >> 3, G = gg & 7;
  int O = ((G & 1) << 2) + (G >> 1);
  u16x8 v = *(const u16x8*)(in + row * DIM + (b << 6) + (O << 3));
  u8x8 o;
  #pragma unroll
  for (int j = 0; j < 8; ++j) o[j] = f2e4m3(16.f * bf2f(v[j]));
  *(u8x8*)(out + row * DIM + (b << 6) + (G << 3)) = o;
}

// ve f32 [VOCAB][DIM] -> veT8 fp8 x16 [DIM][VOCAB], K(VOCAB)-permuted
__global__ void transpose_cvt_f8(const float* __restrict__ in, u8* __restrict__ out) {
  __shared__ float t[64][65];
  int r0 = blockIdx.x << 6;          // vocab base
  int c0 = blockIdx.y << 6;          // dim base
  int tid = threadIdx.x;
  #pragma unroll
  for (int p = 0; p < 4; ++p) {
    int r = (p << 4) + (tid >> 4);
    int c = (tid & 15) << 2;
    float4 v = *(const float4*)(in + (size_t)(r0 + r) * DIM + c0 + c);
    t[c+0][r] = v.x; t[c+1][r] = v.y; t[c+2][r] = v.z; t[c+3][r] = v.w;
  }
  __syncthreads();
  #pragma unroll
  for (int qq = 0; qq < 2; ++qq) {
    int rr = tid >> 2;                          // dim-local
    int O  = ((tid & 3) << 1) + qq;             // orig vocab group 0..7
    int cc = O << 3;
    int Gp = ((O & 3) << 1) + (O >> 2);         // stored group
    u8x8 w;
    #pragma unroll
    for (int j = 0; j < 8; ++j) w[j] = f2e4m3(16.f * t[rr][cc + j]);
    *(u8x8*)(out + (size_t)(c0 + rr) * VOCAB + r0 + (Gp << 3)) = w;
  }
}

// ---------------- small GEMM for qW: C[M,N]=A@B^T, 128x128 tile (bf16 out) ----
__global__ void gemm_qw(const u16* __restrict__ A, const u16* __restrict__ B,
                        u16* __restrict__ C, int K, int kSteps, int ldc) {
  __shared__ u16 As[128 * 32];
  __shared__ u16 Bs[128 * 32];
  const int tid  = threadIdx.x;
  const int lane = tid & 63;
  const int wid  = tid >> 6;
  const int wr   = wid >> 1, wc = wid & 1;
  const int row0 = blockIdx.x << 7;
  const int col0 = blockIdx.y << 7;

  f32x4 acc[4][4];
  #pragma unroll
  for (int m = 0; m < 4; ++m)
    #pragma unroll
    for (int n = 0; n < 4; ++n) acc[m][n] = (f32x4){0.f,0.f,0.f,0.f};

  const int sr = lane >> 2;
  const int sc = (lane & 3) << 3;

  for (int ks = 0; ks < kSteps; ++ks) {
    const int kk = ks << 5;
    #pragma unroll
    for (int t = 0; t < 2; ++t) {
      const int i = wid * 2 + t;
      const u16* gA = A + (size_t)(row0 + (i << 4) + sr) * K + kk + sc;
      const u16* gB = B + (size_t)(col0 + (i << 4) + sr) * K + kk + sc;
      __builtin_amdgcn_global_load_lds((const __attribute__((address_space(1))) void*)gA,
                                       (__attribute__((address_space(3))) void*)(As + i * 512),
                                       16, 0, 0);
      __builtin_amdgcn_global_load_lds((const __attribute__((address_space(1))) void*)gB,
                                       (__attribute__((address_space(3))) void*)(Bs + i * 512),
                                       16, 0, 0);
    }
    __syncthreads();
    bf16x8 a[4], b[4];
    #pragma unroll
    for (int m = 0; m < 4; ++m)
      a[m] = *(const bf16x8*)(As + ((wr << 6) + (m << 4) + (lane & 15)) * 32 + ((lane >> 4) << 3));
    #pragma unroll
    for (int n = 0; n < 4; ++n)
      b[n] = *(const bf16x8*)(Bs + ((wc << 6) + (n << 4) + (lane & 15)) * 32 + ((lane >> 4) << 3));
    #pragma unroll
    for (int m = 0; m < 4; ++m)
      #pragma unroll
      for (int n = 0; n < 4; ++n)
        acc[m][n] = __builtin_amdgcn_mfma_f32_16x16x32_bf16(a[m], b[n], acc[m][n], 0, 0, 0);
    __syncthreads();
  }

  const int r0 = row0 + (wr << 6);
  const int c0 = col0 + (wc << 6);
  const int fq = (lane >> 4) << 2;
  const int fr = lane & 15;
  #pragma unroll
  for (int m = 0; m < 4; ++m)
    #pragma unroll
    for (int n = 0; n < 4; ++n) {
      int col = c0 + (n << 4) + fr;
      #pragma unroll
      for (int j = 0; j < 4; ++j) {
        int row = r0 + (m << 4) + fq + j;
        C[(size_t)row * ldc + col] = f2bf(acc[m][n][j]);
      }
    }
}

// ---------------- fp8 256² K-loop: 4-slot rotation, 1 barrier/tile -----------
// quad-spread swizzle: phys slot of fragment j in row r = j ^ ((r>>1)&3)
#define STGF8(s, kk)                                                               \
  {                                                                                \
    _Pragma("unroll")                                                              \
    for (int c = 0; c < 2; ++c) {                                                  \
      const int ra = (tid >> 2) + (c << 7);                                        \
      const u8* gA = A + (size_t)(row0 + ra) * Kb + (kk) +                         \
                     (((tid & 3) ^ ((ra >> 1) & 3)) << 4);                         \
      __builtin_amdgcn_global_load_lds(                                            \
          (const __attribute__((address_space(1))) void*)gA,                       \
          (__attribute__((address_space(3))) void*)(lds + (s) * 32768 + (c << 13) + tid * 16), \
          16, 0, 0);                                                               \
    }                                                                              \
    _Pragma("unroll")                                                              \
    for (int c = 0; c < 2; ++c) {                                                  \
      const int rn = (tid >> 2) + (c << 7);                                        \
      const u8* gB = B + (size_t)(col0 + rn) * Kb + (kk) +                         \
                     (((tid & 3) ^ ((rn >> 1) & 3)) << 4);                         \
      __builtin_amdgcn_global_load_lds(                                            \
          (const __attribute__((address_space(1))) void*)gB,                       \
          (__attribute__((address_space(3))) void*)(lds + (s) * 32768 + 16384 + (c << 13) + tid * 16), \
          16, 0, 0);                                                               \
    }                                                                              \
  }

// per tile: {barrier (all waves done with t-1)} -> restage (t+3) into t-1's
// slot -> vmcnt(12) (tile t's loads done; 3 tiles stay in flight) -> reads+MFMA.
#define KLOOPF8(NT, KB)                                                            \
  STGF8(0, (KB))                                                                   \
  if ((NT) > 1) STGF8(1, (KB) + 64)                                                \
  if ((NT) > 2) STGF8(2, (KB) + 128)                                               \
  for (int t = 0; t < (NT); ++t) {                                                 \
    const u8* Abuf = lds + (t & 3) * 32768;                                        \
    const u8* Bbuf = Abuf + 16384;                                                 \
    BAR();                                                                         \
    if (t + 3 < (NT)) STGF8((t + 3) & 3, (KB) + ((t + 3) << 6))                    \
    const int rem = (NT) - 1 - t;                                                  \
    SB();                                                                          \
    if (rem >= 3)      { asm volatile("s_waitcnt vmcnt(12)"); }                    \
    else if (rem == 2) { asm volatile("s_waitcnt vmcnt(8)"); }                     \
    else if (rem == 1) { asm volatile("s_waitcnt vmcnt(4)"); }                     \
    else               { asm volatile("s_waitcnt vmcnt(0)"); }                     \
    SB();                                                                          \
    _Pragma("unroll")                                                              \
    for (int nh = 0; nh < 2; ++nh)                                                 \
      _Pragma("unroll")                                                            \
      for (int nq = 0; nq < 2; ++nq) {                                             \
        const int row = (wc << 6) + (nh << 5) + (nq << 4) + fr;                    \
        i64x2 v = *(const i64x2*)(Bbuf + row * 64 + ((fq ^ ((row >> 1) & 3)) << 4)); \
        b[nh][nq][0] = v[0]; b[nh][nq][1] = v[1];                                  \
      }                                                                            \
    _Pragma("unroll")                                                              \
    for (int mq = 0; mq < 4; ++mq) {                                               \
      const int row = (wr << 7) + (mq << 4) + fr;                                  \
      i64x2 v = *(const i64x2*)(Abuf + row * 64 + ((fq ^ ((row >> 1) & 3)) << 4)); \
      a0[mq][0] = v[0]; a0[mq][1] = v[1];                                          \
    }                                                                              \
    _Pragma("unroll")                                                              \
    for (int mq = 0; mq < 4; ++mq) {                                               \
      const int row = (wr << 7) + 64 + (mq << 4) + fr;                             \
      i64x2 v = *(const i64x2*)(Abuf + row * 64 + ((fq ^ ((row >> 1) & 3)) << 4)); \
      a1[mq][0] = v[0]; a1[mq][1] = v[1];                                          \
    }                                                                              \
    __builtin_amdgcn_s_setprio(1);                                                 \
    _Pragma("unroll")                                                              \
    for (int mq = 0; mq < 4; ++mq)                                                 \
      _Pragma("unroll")                                                            \
      for (int nh = 0; nh < 2; ++nh)                                               \
        _Pragma("unroll")                                                          \
        for (int nq = 0; nq < 2; ++nq)                                             \
          _Pragma("unroll")                                                        \
          for (int ks = 0; ks < 2; ++ks)                                           \
            acc[mq][(nh << 1) + nq] =                                              \
                __builtin_amdgcn_mfma_f32_16x16x32_fp8_fp8(                        \
                    a0[mq][ks], b[nh][nq][ks], acc[mq][(nh << 1) + nq], 0, 0, 0);  \
    _Pragma("unroll")                                                              \
    for (int mq = 0; mq < 4; ++mq)                                                 \
      _Pragma("unroll")                                                            \
      for (int nh = 0; nh < 2; ++nh)                                               \
        _Pragma("unroll")                                                          \
        for (int nq = 0; nq < 2; ++nq)                                             \
          _Pragma("unroll")                                                        \
          for (int ks = 0; ks < 2; ++ks)                                           \
            acc[4 + mq][(nh << 1) + nq] =                                          \
                __builtin_amdgcn_mfma_f32_16x16x32_fp8_fp8(                        \
                    a1[mq][ks], b[nh][nq][ks], acc[4 + mq][(nh << 1) + nq], 0, 0, 0); \
    __builtin_amdgcn_s_setprio(0);                                                 \
  }

// ---------------- fp8 exp-GEMM: P8 = e4m3(exp(acc/256)), fused rowsum ---------
__global__ __launch_bounds__(512, 2) void gemm256e8(const u8* __restrict__ A,
                                                    const u8* __restrict__ B,
                                                    u8* __restrict__ P,
                                                    float* __restrict__ dpart,
                                                    int Kb, int nTiles) {
  __shared__ __align__(16) u8 lds[131072];   // 4 slots x 32 KiB
  const int tid  = threadIdx.x;
  const int lane = tid & 63;
  const int wid  = tid >> 6;
  const int wr   = wid >> 2;
  const int wc   = wid & 3;

  const int nwg = (int)(gridDim.x * gridDim.y);
  int lin = blockIdx.y * gridDim.x + blockIdx.x;
  { const int cpx = nwg >> 3; lin = (lin & 7) * cpx + (lin >> 3); }
  const int row0 = (lin & 15) << 8;    // gridDim.x == 16
  const int cblk = lin >> 4;
  const int col0 = cblk << 8;

  const int fr = lane & 15;
  const int fq = lane >> 4;

  f32x4 acc[8][4];
  #pragma unroll
  for (int m = 0; m < 8; ++m)
    #pragma unroll
    for (int n = 0; n < 4; ++n) acc[m][n] = (f32x4){0.f, 0.f, 0.f, 0.f};

  i64t a0[4][2], a1[4][2], b[2][2][2];

  KLOOPF8(nTiles, 0)

  // epilogue: P8 = e4m3(exp(acc/256)) at K-permuted cols; fused row-sums
  const float inv256 = 1.0f / 256.0f;
  float rs[32];
  #pragma unroll
  for (int i = 0; i < 32; ++i) rs[i] = 0.f;
  #pragma unroll
  for (int m = 0; m < 8; ++m)
    #pragma unroll
    for (int n = 0; n < 4; ++n) {
      const int l6  = (n << 4) + fr;
      const int col = col0 + (wc << 6) + kperm(l6);
      #pragma unroll
      for (int j = 0; j < 4; ++j) {
        const int row = row0 + (wr << 7) + (m << 4) + (fq << 2) + j;
        float e = __expf(acc[m][n][j] * inv256);
        P[(size_t)row * VOCAB + col] = f2e4m3_exp(e);
        rs[(m << 2) + j] += e;
      }
    }
  #pragma unroll
  for (int i = 0; i < 32; ++i) {
    #pragma unroll
    for (int s = 8; s >= 1; s >>= 1) rs[i] += __shfl_xor(rs[i], s, 16);
  }
  __syncthreads();
  float* dsm = (float*)lds;
  if (fr == 0) {
    #pragma unroll
    for (int m = 0; m < 8; ++m)
      #pragma unroll
      for (int j = 0; j < 4; ++j)
        dsm[(wc << 8) + (wr << 7) + (m << 4) + (fq << 2) + j] = rs[(m << 2) + j];
  }
  __syncthreads();
  if (tid < 256)
    dpart[(size_t)(row0 + tid) * 256 + cblk] =
        dsm[tid] + dsm[256 + tid] + dsm[512 + tid] + dsm[768 + tid];
}

// ---------------- fp8 PV GEMM: parts[z] = P8 @ veT8ᵀ (uneven split-K=8) -------
__global__ __launch_bounds__(512, 2) void gemm256p8(const u8* __restrict__ A,
                                                    const u8* __restrict__ B,
                                                    float* __restrict__ Cout,
                                                    int Kb) {
  __shared__ __align__(16) u8 lds[131072];   // 4 slots x 32 KiB
  const int tid  = threadIdx.x;
  const int lane = tid & 63;
  const int wid  = tid >> 6;
  const int wr   = wid >> 2;
  const int wc   = wid & 3;

  const int nwg = (int)(gridDim.x * gridDim.y);
  int lin = blockIdx.y * gridDim.x + blockIdx.x;
  { const int cpx = nwg >> 3; lin = (lin & 7) * cpx + (lin >> 3); }
  const int row0 = (lin & 15) << 8;    // gridDim.x == 16
  const int col0 = (lin >> 4) << 8;

  const int z = blockIdx.z;            // 0..7 ; 500 tiles = 4x63 + 4x62
  const int nT = (z < 4) ? 63 : 62;
  const int kb = ((z * 62 + ((z < 4) ? z : 4)) << 6);

  const int fr = lane & 15;
  const int fq = lane >> 4;

  f32x4 acc[8][4];
  #pragma unroll
  for (int m = 0; m < 8; ++m)
    #pragma unroll
    for (int n = 0; n < 4; ++n) acc[m][n] = (f32x4){0.f, 0.f, 0.f, 0.f};

  i64t a0[4][2], a1[4][2], b[2][2][2];

  KLOOPF8(nT, kb)

  float* C = Cout + (size_t)z * NTOK * DIM;
  #pragma unroll
  for (int m = 0; m < 8; ++m)
    #pragma unroll
    for (int n = 0; n < 4; ++n) {
      const int col = col0 + (wc << 6) + (n << 4) + fr;
      #pragma unroll
      for (int j = 0; j < 4; ++j) {
        const int row = row0 + (wr << 7) + (m << 4) + (fq << 2) + j;
        C[(size_t)row * DIM + col] = acc[m][n][j];
      }
    }
}

// ---------------- bf16 128² exp-GEMM + bf16 256² PV (chunked fallback) --------
__global__ __launch_bounds__(256, 2) void gemm128e(const u16* __restrict__ A,
                                                   const u16* __restrict__ B,
                                                   u16* __restrict__ P,
                                                   float* __restrict__ dpart,
                                                   int K, int nTiles, int ldc, int cb0) {
  __shared__ __align__(16) u16 lds[32768];
  const int tid  = threadIdx.x;
  const int lane = tid & 63;
  const int wid  = tid >> 6;
  const int wr   = wid >> 1;
  const int wc   = wid & 1;

  const int nwg = (int)(gridDim.x * gridDim.y);
  int lin = blockIdx.y * gridDim.x + blockIdx.x;
  { const int cpx = nwg >> 3; lin = (lin & 7) * cpx + (lin >> 3); }
  const int row0 = (lin & 31) << 7;
  const int cblk = lin >> 5;
  const int col0 = cblk << 7;

  const int fr = lane & 15;
  const int fq = lane >> 4;
  const int rb = tid >> 3;
  const int ss = tid & 7;

#define STG128(d, kk)                                                              \
  {                                                                                \
    _Pragma("unroll")                                                              \
    for (int c = 0; c < 4; ++c) {                                                  \
      const int ra = (c << 5) + rb;                                                \
      const u16* gA = A + (size_t)(row0 + ra) * K + (kk) + ((ss ^ (ra & 7)) << 3); \
      __builtin_amdgcn_global_load_lds(                                            \
          (const __attribute__((address_space(1))) void*)gA,                       \
          (__attribute__((address_space(3))) void*)(lds + (d) * 16384 + (((c << 5) + (wid << 3)) << 6)), \
          16, 0, 0);                                                               \
    }                                                                              \
    _Pragma("unroll")                                                              \
    for (int c = 0; c < 4; ++c) {                                                  \
      const int rn = (c << 5) + rb;                                                \
      const u16* gB = B + (size_t)(col0 + rn) * K + (kk) + ((ss ^ (rn & 7)) << 3); \
      __builtin_amdgcn_global_load_lds(                                            \
          (const __attribute__((address_space(1))) void*)gB,                       \
          (__attribute__((address_space(3))) void*)(lds + (d) * 16384 + 8192 + (((c << 5) + (wid << 3)) << 6)), \
          16, 0, 0);                                                               \
    }                                                                              \
  }

  f32x4 acc[4][4];
  #pragma unroll
  for (int m = 0; m < 4; ++m)
    #pragma unroll
    for (int n = 0; n < 4; ++n) acc[m][n] = (f32x4){0.f, 0.f, 0.f, 0.f};

  STG128(0, 0)
  STG128(1, 64)

  bf16x8 a[4], b[4];

  for (int t = 0; t < nTiles; ++t) {
    const int d = t & 1;
    const u16* Abuf = lds + d * 16384;
    const u16* Bbuf = Abuf + 8192;
    SB();
    if (t + 1 < nTiles) { asm volatile("s_waitcnt vmcnt(8)"); }
    else                { asm volatile("s_waitcnt vmcnt(0)"); }
    BAR();

    #pragma unroll
    for (int ks = 0; ks < 2; ++ks) {
      #pragma unroll
      for (int mq = 0; mq < 4; ++mq) {
        const int row  = (wr << 6) + (mq << 4) + fr;
        const int slot = ((ks << 2) + fq) ^ (row & 7);
        a[mq] = *(const bf16x8*)(Abuf + (row << 6) + (slot << 3));
      }
      #pragma unroll
      for (int nq = 0; nq < 4; ++nq) {
        const int row  = (wc << 6) + (nq << 4) + fr;
        const int slot = ((ks << 2) + fq) ^ (row & 7);
        b[nq] = *(const bf16x8*)(Bbuf + (row << 6) + (slot << 3));
      }
      __builtin_amdgcn_s_setprio(1);
      #pragma unroll
      for (int mq = 0; mq < 4; ++mq)
        #pragma unroll
        for (int nq = 0; nq < 4; ++nq)
          acc[mq][nq] = __builtin_amdgcn_mfma_f32_16x16x32_bf16(
              a[mq], b[nq], acc[mq][nq], 0, 0, 0);
      __builtin_amdgcn_s_setprio(0);
    }
    BAR();
    if (t + 2 < nTiles) STG128(d, (t + 2) << 6)
  }
#undef STG128

  float rs[16];
  #pragma unroll
  for (int i = 0; i < 16; ++i) rs[i] = 0.f;
  #pragma unroll
  for (int mq = 0; mq < 4; ++mq)
    #pragma unroll
    for (int nq = 0; nq < 4; ++nq) {
      const int col = col0 + (wc << 6) + (nq << 4) + fr;
      #pragma unroll
      for (int j = 0; j < 4; ++j) {
        const int row = row0 + (wr << 6) + (mq << 4) + (fq << 2) + j;
        float e = __expf(acc[mq][nq][j]);
        P[(size_t)row * ldc + col] = f2bf(e);
        rs[(mq << 2) + j] += e;
      }
    }
  #pragma unroll
  for (int i = 0; i < 16; ++i) {
    #pragma unroll
    for (int s = 8; s >= 1; s >>= 1) rs[i] += __shfl_xor(rs[i], s, 16);
  }
  __syncthreads();
  float* dsm = (float*)lds;
  if (fr == 0) {
    #pragma unroll
    for (int mq = 0; mq < 4; ++mq)
      #pragma unroll
      for (int j = 0; j < 4; ++j)
        dsm[(wc << 7) + (wr << 6) + (mq << 4) + (fq << 2) + j] = rs[(mq << 2) + j];
  }
  __syncthreads();
  if (tid < 128)
    dpart[(size_t)(row0 + tid) * 256 + cb0 + cblk] = dsm[tid] + dsm[128 + tid];
}

#define STG256(d, kk)                                                              \
  {                                                                                \
    _Pragma("unroll")                                                              \
    for (int c = 0; c < 4; ++c) {                                                  \
      const int ra = (c << 6) + rb;                                                \
      const u16* gA = A + (size_t)(row0 + ra) * K + (kk) + ((ss ^ (ra & 7)) << 3); \
      __builtin_amdgcn_global_load_lds(                                            \
          (const __attribute__((address_space(1))) void*)gA,                       \
          (__attribute__((address_space(3))) void*)(lds + (d) * 32768 + (((c << 6) + (wid << 3)) << 6)), \
          16, 0, 0);                                                               \
    }                                                                              \
    _Pragma("unroll")                                                              \
    for (int c = 0; c < 4; ++c) {                                                  \
      const int rn = (c << 6) + rb;                                                \
      const u16* gB = B + (size_t)(col0 + rn) * K + (kk) + ((ss ^ (rn & 7)) << 3); \
      __builtin_amdgcn_global_load_lds(                                            \
          (const __attribute__((address_space(1))) void*)gB,                       \
          (__attribute__((address_space(3))) void*)(lds + (d) * 32768 + 16384 + (((c << 6) + (wid << 3)) << 6)), \
          16, 0, 0);                                                               \
    }                                                                              \
  }

// bf16 256² PV for fallback (+= into parts slice)
__global__ __launch_bounds__(512, 2) void gemm256acc(const u16* __restrict__ A,
                                                     const u16* __restrict__ B,
                                                     float* __restrict__ Cout,
                                                     int K, int nTiles, int ldc) {
  __shared__ __align__(16) u16 lds[65536];
  const int tid  = threadIdx.x;
  const int lane = tid & 63;
  const int wid  = tid >> 6;
  const int wr   = wid >> 2;
  const int wc   = wid & 3;

  const int nwg = (int)(gridDim.x * gridDim.y);
  int lin = blockIdx.y * gridDim.x + blockIdx.x;
  { const int cpx = nwg >> 3; lin = (lin & 7) * cpx + (lin >> 3); }
  const int row0 = (lin & 15) << 8;
  const int col0 = (lin >> 4) << 8;

  const int kbase = blockIdx.z * (nTiles << 6);
  const int fr = lane & 15;
  const int fq = lane >> 4;
  const int rb = tid >> 3;
  const int ss = tid & 7;

  f32x4 acc[8][4];
  #pragma unroll
  for (int m = 0; m < 8; ++m)
    #pragma unroll
    for (int n = 0; n < 4; ++n) acc[m][n] = (f32x4){0.f, 0.f, 0.f, 0.f};

  bf16x8 a[4][2], b[2][2][2];

  STG256(0, kbase)
  STG256(1, kbase + 64)
  for (int t = 0; t < nTiles; ++t) {
    const int d = t & 1;
    const u16* Abuf = lds + d * 32768;
    const u16* Bbuf = Abuf + 16384;
    SB();
    if (t + 1 < nTiles) { asm volatile("s_waitcnt vmcnt(8)"); }
    else                { asm volatile("s_waitcnt vmcnt(0)"); }
    BAR();
    #pragma unroll
    for (int nh = 0; nh < 2; ++nh)
      #pragma unroll
      for (int nq = 0; nq < 2; ++nq)
        #pragma unroll
        for (int ks = 0; ks < 2; ++ks) {
          const int row  = (wc << 6) + (nh << 5) + (nq << 4) + fr;
          const int slot = ((ks << 2) + fq) ^ (row & 7);
          b[nh][nq][ks] = *(const bf16x8*)(Bbuf + (row << 6) + (slot << 3));
        }
    #pragma unroll
    for (int mh = 0; mh < 2; ++mh) {
      #pragma unroll
      for (int mq = 0; mq < 4; ++mq)
        #pragma unroll
        for (int ks = 0; ks < 2; ++ks) {
          const int row  = (wr << 7) + (mh << 6) + (mq << 4) + fr;
          const int slot = ((ks << 2) + fq) ^ (row & 7);
          a[mq][ks] = *(const bf16x8*)(Abuf + (row << 6) + (slot << 3));
        }
      __builtin_amdgcn_s_setprio(1);
      #pragma unroll
      for (int mq = 0; mq < 4; ++mq)
        #pragma unroll
        for (int nh = 0; nh < 2; ++nh)
          #pragma unroll
          for (int nq = 0; nq < 2; ++nq)
            #pragma unroll
            for (int ks = 0; ks < 2; ++ks)
              acc[(mh << 2) + mq][(nh << 1) + nq] =
                  __builtin_amdgcn_mfma_f32_16x16x32_bf16(
                      a[mq][ks], b[nh][nq][ks], acc[(mh << 2) + mq][(nh << 1) + nq], 0, 0, 0);
      __builtin_amdgcn_s_setprio(0);
    }
    BAR();
    if (t + 2 < nTiles) STG256(d, kbase + ((t + 2) << 6))
  }

  float* C = Cout + (size_t)blockIdx.z * NTOK * DIM;
  #pragma unroll
  for (int m = 0; m < 8; ++m)
    #pragma unroll
    for (int n = 0; n < 4; ++n) {
      const int col = col0 + (wc << 6) + (n << 4) + fr;
      #pragma unroll
      for (int j = 0; j < 4; ++j) {
        const int row = row0 + (wr << 7) + (m << 4) + (fq << 2) + j;
        C[(size_t)row * ldc + col] += acc[m][n][j];
      }
    }
}

// ---------------- denom reduce ----------------
__global__ void denom_reduce(const float* __restrict__ dpart, float* __restrict__ denom,
                             int npart) {
  int row = blockIdx.x;
  int l = threadIdx.x;              // 64
  float s = 0.f;
  #pragma unroll
  for (int k = 0; k < 4; ++k) {
    int idx = l + (k << 6);
    if (idx < npart) s += dpart[(size_t)row * 256 + idx];
  }
  #pragma unroll
  for (int off = 32; off >= 1; off >>= 1) s += __shfl_down(s, off, 64);
  if (l == 0) denom[row] = s;
}

// ---------------- finalize ----------------
__global__ void finalize(const float* __restrict__ parts, const float* __restrict__ denom,
                         const float* __restrict__ ve, const int* __restrict__ batch,
                         float* __restrict__ out, int nks, float pvInv) {
  int row = blockIdx.x;
  int t = threadIdx.x;
  float inv = 0.5f * pvInv / denom[row];
  float4 a = *(const float4*)(ve + (size_t)batch[row] * DIM + (t << 2));
  float sx = 0.f, sy = 0.f, sz = 0.f, sw = 0.f;
  for (int ks = 0; ks < nks; ++ks) {
    float4 pv = *(const float4*)(parts + ((size_t)ks * NTOK + row) * DIM + (t << 2));
    sx += pv.x; sy += pv.y; sz += pv.z; sw += pv.w;
  }
  float4 o;
  o.x = 0.5f * a.x + inv * sx;
  o.y = 0.5f * a.y + inv * sy;
  o.z = 0.5f * a.z + inv * sz;
  o.w = 0.5f * a.w + inv * sw;
  *(float4*)(out + (size_t)row * DIM + (t << 2)) = o;
}

// ---------------- launch ----------------
extern "C" void kernel_launch(void* const* d_in, const int* in_sizes, int n_in,
                              void* d_out, int out_size, void* d_ws, size_t ws_size,
                              hipStream_t stream) {
  const int*   batch = (const int*)d_in[0];
  const float* lang  = (const float*)d_in[1];
  const float* key   = (const float*)d_in[2];
  const float* ve    = (const float*)d_in[3];
  const float* W     = (const float*)d_in[4];
  float* out = (float*)d_out;

  const size_t szWt    = (size_t)DIM * DIM * 2;
  const size_t szQb    = (size_t)NTOK * DIM * 2;
  const size_t szQW    = (size_t)NTOK * DIM * 2;
  const size_t szDpart = (size_t)NTOK * 256 * 4;
  const size_t szDenom = (size_t)NTOK * 4;
  const size_t base    = szWt + szQb + szQW + szDpart + szDenom;

  char* ws = (char*)d_ws;
  u16*   Wt    = (u16*)(ws);
  u16*   qb    = (u16*)(ws + szWt);
  u16*   qW    = (u16*)(ws + szWt + szQb);
  float* dpart = (float*)(ws + szWt + szQb + szQW);
  float* denom = (float*)(ws + szWt + szQb + szQW + szDpart);

  const int KSF = 8;
  const size_t szPartsF = (size_t)KSF * NTOK * DIM * 4;     // 134 MB
  const size_t szQW8    = (size_t)NTOK * DIM;               //   4 MB
  const size_t szKey8   = (size_t)VOCAB * DIM;              //  33 MB
  const size_t szVeT8   = (size_t)DIM * VOCAB;              //  33 MB
  const size_t szP8     = (size_t)NTOK * VOCAB;             // 131 MB
  const bool fullP = (base + szPartsF + szQW8 + szKey8 + szVeT8 + szP8) <= ws_size;

  transpose_cvt<<<dim3(DIM / 64, DIM / 64), 256, 0, stream>>>(W, Wt, DIM, DIM);
  gather_q<<<NTOK, 256, 0, stream>>>(batch, lang, qb);
  gemm_qw<<<dim3(NTOK / 128, DIM / 128), 256, 0, stream>>>(qb, Wt, qW, DIM, DIM / 32, DIM);

  if (fullP) {
    float* parts = (float*)(ws + base);
    u8*    qW8   = (u8*)(ws + base + szPartsF);
    u8*    key8  = (u8*)(ws + base + szPartsF + szQW8);
    u8*    veT8  = (u8*)(ws + base + szPartsF + szQW8 + szKey8);
    u8*    P8    = (u8*)(ws + base + szPartsF + szQW8 + szKey8 + szVeT8);

    cvt_qw_f8<<<NTOK * DIM / 8 / 256, 256, 0, stream>>>(qW, qW8);
    cvt_key_f8<<<VOCAB * DIM / 8 / 256, 256, 0, stream>>>(key, key8);
    transpose_cvt_f8<<<dim3(VOCAB / 64, DIM / 64), 256, 0, stream>>>(ve, veT8);

    // P8 = e4m3(exp(qW8 @ key8ᵀ / 256)), fused row-sum partials
    gemm256e8<<<dim3(NTOK / 256, VOCAB / 256), 512, 0, stream>>>(qW8, key8, P8, dpart,
                                                                 DIM, DIM / 64);
    denom_reduce<<<NTOK, 64, 0, stream>>>(dpart, denom, VOCAB / 256);
    // parts[z] = P8 @ veT8ᵀ (uneven split-K = 8)
    gemm256p8<<<dim3(NTOK / 256, DIM / 256, KSF), 512, 0, stream>>>(P8, veT8, parts, VOCAB);
    finalize<<<NTOK, 256, 0, stream>>>(parts, denom, ve, batch, out, KSF, 1.0f / 16.0f);
  } else {
    // bf16 chunked fallback (proven path)
    const int KS = 2;
    const size_t szParts = (size_t)KS * NTOK * DIM * 4;
    int CHUNK = 1280;
    {
      const int copt[2] = {6400, 1280};
      for (int i = 0; i < 2; ++i) {
        size_t need = base + szParts + (size_t)copt[i] * (NTOK * 2 + DIM * 4);
        if (need <= ws_size) { CHUNK = copt[i]; break; }
      }
    }
    const int NCHUNK = VOCAB / CHUNK;
    float* parts = (float*)(ws + base);
    char*  dyn   = ws + base + szParts;
    u16*   keyc  = (u16*)(dyn);
    u16*   veTc  = (u16*)(dyn + (size_t)CHUNK * DIM * 2);
    u16*   Pc    = (u16*)(dyn + (size_t)CHUNK * DIM * 4);

    hipMemsetAsync(parts, 0, szParts, stream);
    for (int c = 0; c < NCHUNK; ++c) {
      const int v0 = c * CHUNK;
      cvt_f32_bf16<<<CHUNK * DIM / 1024, 256, 0, stream>>>(key + (size_t)v0 * DIM, keyc);
      transpose_cvt<<<dim3(CHUNK / 64, DIM / 64), 256, 0, stream>>>(ve + (size_t)v0 * DIM, veTc,
                                                                    DIM, CHUNK);
      gemm128e<<<dim3(NTOK / 128, CHUNK / 128), 256, 0, stream>>>(qW, keyc, Pc, dpart,
                                                                  DIM, DIM / 64, CHUNK, v0 >> 7);
      gemm256acc<<<dim3(NTOK / 256, DIM / 256, KS), 512, 0, stream>>>(Pc, veTc, parts,
                                                                      CHUNK, CHUNK / 64 / KS, DIM);
    }
    denom_reduce<<<NTOK, 64, 0, stream>>>(dpart, denom, 250);
    finalize<<<NTOK, 256, 0, stream>>>(parts, denom, ve, batch, out, KS, 1.0f);
  }
}